// Round 1
// baseline (1012.302 us; speedup 1.0000x reference)
//
#include <hip/hip_runtime.h>
#include <hip/hip_bf16.h>

#define B_    16
#define L_    1024
#define DM    384
#define DIP   1676
#define DI    768
#define CONVD 896
#define NH    12
#define HD    64
#define DS    64
#define NCH   4
#define CH    256
#define EPS_  1e-5f

// ---------------- K1: in_proj GEMM (useq @ W^T), fused transpose + split + softplus ----------------
// A[m,k] = u[b, k, l] (m = b*1024 + l), Bmat[n,k] = in_proj_w[n,k]
__global__ __launch_bounds__(256) void k_inproj(
    const float* __restrict__ u, const float* __restrict__ W,
    const float* __restrict__ dt_bias,
    float* __restrict__ z, float* __restrict__ xBC, float* __restrict__ dt)
{
  __shared__ float As[16][65];
  __shared__ float Bs[16][65];
  const int m0 = blockIdx.x * 64;
  const int n0 = blockIdx.y * 64;
  const int b  = m0 >> 10;
  const int l0 = m0 & 1023;
  const int t  = threadIdx.x;
  const int tx = t & 15, ty = t >> 4;
  float acc[4][4] = {};
  const float* ub = u + (size_t)b * DM * L_ + l0;
  for (int k0 = 0; k0 < DM; k0 += 16) {
#pragma unroll
    for (int r = 0; r < 4; ++r) {
      int idx = r * 256 + t;
      int kk = idx >> 6, mm = idx & 63;
      As[kk][mm] = ub[(size_t)(k0 + kk) * L_ + mm];  // coalesced along l
    }
    {
      int n = t >> 2, kq = (t & 3) * 4;
      int gn = n0 + n;
      float4 v = make_float4(0.f, 0.f, 0.f, 0.f);
      if (gn < DIP) v = *(const float4*)&W[(size_t)gn * DM + k0 + kq];
      Bs[kq + 0][n] = v.x; Bs[kq + 1][n] = v.y;
      Bs[kq + 2][n] = v.z; Bs[kq + 3][n] = v.w;
    }
    __syncthreads();
#pragma unroll
    for (int k = 0; k < 16; ++k) {
      float a[4], bb[4];
#pragma unroll
      for (int i = 0; i < 4; ++i) a[i] = As[k][ty * 4 + i];
#pragma unroll
      for (int j = 0; j < 4; ++j) bb[j] = Bs[k][tx * 4 + j];
#pragma unroll
      for (int i = 0; i < 4; ++i)
#pragma unroll
        for (int j = 0; j < 4; ++j)
          acc[i][j] = fmaf(a[i], bb[j], acc[i][j]);
    }
    __syncthreads();
  }
#pragma unroll
  for (int i = 0; i < 4; ++i) {
    size_t m = (size_t)m0 + ty * 4 + i;
#pragma unroll
    for (int j = 0; j < 4; ++j) {
      int n = n0 + tx * 4 + j;
      if (n >= DIP) continue;
      float v = acc[i][j];
      if (n < DI) z[m * DI + n] = v;
      else if (n < DI + CONVD) xBC[m * CONVD + (n - DI)] = v;
      else {
        int hh = n - (DI + CONVD);
        float xv = v + dt_bias[hh];
        dt[m * NH + hh] = (xv > 20.f) ? xv : log1pf(expf(xv));  // softplus
      }
    }
  }
}

// ---------------- K2: depthwise 3x3 conv SAME + bias + SiLU + split ----------------
__global__ __launch_bounds__(256) void k_conv(
    const float* __restrict__ xBC, const float* __restrict__ cw,
    const float* __restrict__ cb,
    float* __restrict__ x, float* __restrict__ Bm, float* __restrict__ Cm)
{
  int tid = blockIdx.x * 256 + threadIdx.x;     // B_*L_*224 total
  int c4  = tid % 224;
  int rem = tid / 224;
  int l   = rem & 1023;
  int b   = rem >> 10;
  if (b >= B_) return;
  int h = l >> 5, w = l & 31;
  int c = c4 * 4;
  float acc[4];
#pragma unroll
  for (int j = 0; j < 4; ++j) acc[j] = cb[c + j];
#pragma unroll
  for (int dh = -1; dh <= 1; ++dh) {
    int hh = h + dh;
    if (hh < 0 || hh >= 32) continue;
#pragma unroll
    for (int dw = -1; dw <= 1; ++dw) {
      int ww = w + dw;
      if (ww < 0 || ww >= 32) continue;
      const float4 v = *(const float4*)&xBC[((size_t)(b * 1024 + hh * 32 + ww)) * CONVD + c];
      int kb = (dh + 1) * 3 + (dw + 1);
      acc[0] = fmaf(v.x, cw[(c + 0) * 9 + kb], acc[0]);
      acc[1] = fmaf(v.y, cw[(c + 1) * 9 + kb], acc[1]);
      acc[2] = fmaf(v.z, cw[(c + 2) * 9 + kb], acc[2]);
      acc[3] = fmaf(v.w, cw[(c + 3) * 9 + kb], acc[3]);
    }
  }
  size_t row = (size_t)b * 1024 + l;
#pragma unroll
  for (int j = 0; j < 4; ++j) {
    float v = acc[j];
    float s = v / (1.f + expf(-v));               // silu
    int cc = c + j;
    if (cc < DI) x[row * DI + cc] = s;
    else if (cc < DI + DS) Bm[row * DS + (cc - DI)] = s;
    else Cm[row * DS + (cc - DI - DS)] = s;
  }
}

// ---------------- K3: dA = dt*A, inclusive cumsum per chunk, chunk decay ----------------
__global__ __launch_bounds__(256) void k_dtcum(
    const float* __restrict__ dt, const float* __restrict__ A_log,
    float* __restrict__ dAcs, float* __restrict__ cdecay)
{
  __shared__ float s[256];
  const int bc = blockIdx.x;          // b*4 + c
  const int i  = threadIdx.x;
  const size_t row = (size_t)bc * 256 + i;
  for (int h = 0; h < NH; ++h) {
    float A = -expf(A_log[h]);
    float v = dt[row * NH + h] * A;
    s[i] = v;
    __syncthreads();
#pragma unroll
    for (int off = 1; off < 256; off <<= 1) {
      float add = (i >= off) ? s[i - off] : 0.f;
      __syncthreads();
      s[i] += add;
      __syncthreads();
    }
    float cs = s[i];
    dAcs[row * NH + h] = cs;
    if (i == 255) cdecay[bc * NH + h] = expf(cs);
    __syncthreads();
  }
}

// ---------------- K4: G[i,j] = C_i . B_j per chunk (head-independent, NGROUPS=1) ----------------
__global__ __launch_bounds__(256) void k_G(
    const float* __restrict__ Bm, const float* __restrict__ Cm,
    float* __restrict__ G)
{
  __shared__ float Cs[64 * 65];   // [n][i]
  __shared__ float Bs[64 * 65];   // [n][j]
  const int bc = blockIdx.x;      // 0..63
  const int it = blockIdx.y;      // 0..3
  const int t  = threadIdx.x;
  const int tx = t & 15, ty = t >> 4;
  const int i0 = it * 64;
  const size_t base = (size_t)bc * 256;
#pragma unroll
  for (int r = 0; r < 4; ++r) {
    int idx = r * 256 + t;
    int a = idx >> 4, q = (idx & 15) * 4;
    float4 v = *(const float4*)&Cm[(base + i0 + a) * DS + q];
    Cs[(q + 0) * 65 + a] = v.x; Cs[(q + 1) * 65 + a] = v.y;
    Cs[(q + 2) * 65 + a] = v.z; Cs[(q + 3) * 65 + a] = v.w;
  }
  for (int jt = 0; jt < 4; ++jt) {
    __syncthreads();
    int j0 = jt * 64;
#pragma unroll
    for (int r = 0; r < 4; ++r) {
      int idx = r * 256 + t;
      int a = idx >> 4, q = (idx & 15) * 4;
      float4 v = *(const float4*)&Bm[(base + j0 + a) * DS + q];
      Bs[(q + 0) * 65 + a] = v.x; Bs[(q + 1) * 65 + a] = v.y;
      Bs[(q + 2) * 65 + a] = v.z; Bs[(q + 3) * 65 + a] = v.w;
    }
    __syncthreads();
    float acc[4][4] = {};
    for (int n = 0; n < 64; ++n) {
      float a[4], bb[4];
#pragma unroll
      for (int i = 0; i < 4; ++i) a[i] = Cs[n * 65 + ty * 4 + i];
#pragma unroll
      for (int j = 0; j < 4; ++j) bb[j] = Bs[n * 65 + tx * 4 + j];
#pragma unroll
      for (int i = 0; i < 4; ++i)
#pragma unroll
        for (int j = 0; j < 4; ++j)
          acc[i][j] = fmaf(a[i], bb[j], acc[i][j]);
    }
#pragma unroll
    for (int i = 0; i < 4; ++i) {
      float4 o = make_float4(acc[i][0], acc[i][1], acc[i][2], acc[i][3]);
      *(float4*)&G[((size_t)bc << 16) + (size_t)(i0 + ty * 4 + i) * 256 + j0 + tx * 4] = o;
    }
  }
}

// ---------------- K5: chunk states[p,n] = sum_j w_j * x[j,p] * B[j,n] ----------------
__global__ __launch_bounds__(256) void k_states(
    const float* __restrict__ x, const float* __restrict__ Bm,
    const float* __restrict__ dt, const float* __restrict__ dAcs,
    float* __restrict__ states)
{
  __shared__ float xs[64 * 65];   // [j][p]
  __shared__ float Bs[64 * 65];   // [j][n]
  __shared__ float wj[64];
  const int bc = blockIdx.x;
  const int hh = blockIdx.y;
  const int t  = threadIdx.x;
  const int tx = t & 15, ty = t >> 4;
  const size_t base = (size_t)bc * 256;
  const float last = dAcs[(base + 255) * NH + hh];
  float acc[4][4] = {};
  for (int j0 = 0; j0 < 256; j0 += 64) {
#pragma unroll
    for (int r = 0; r < 4; ++r) {
      int idx = r * 256 + t;
      int j = idx >> 4, pq = (idx & 15) * 4;
      float4 v = *(const float4*)&x[(base + j0 + j) * DI + hh * HD + pq];
      xs[j * 65 + pq + 0] = v.x; xs[j * 65 + pq + 1] = v.y;
      xs[j * 65 + pq + 2] = v.z; xs[j * 65 + pq + 3] = v.w;
      float4 u2 = *(const float4*)&Bm[(base + j0 + j) * DS + pq];
      Bs[j * 65 + pq + 0] = u2.x; Bs[j * 65 + pq + 1] = u2.y;
      Bs[j * 65 + pq + 2] = u2.z; Bs[j * 65 + pq + 3] = u2.w;
    }
    if (t < 64) {
      size_t r2 = base + j0 + t;
      wj[t] = expf(last - dAcs[r2 * NH + hh]) * dt[r2 * NH + hh];
    }
    __syncthreads();
    for (int j = 0; j < 64; ++j) {
      float w = wj[j];
      float xv[4], bv[4];
#pragma unroll
      for (int i = 0; i < 4; ++i) xv[i] = xs[j * 65 + ty * 4 + i] * w;
#pragma unroll
      for (int jj = 0; jj < 4; ++jj) bv[jj] = Bs[j * 65 + tx * 4 + jj];
#pragma unroll
      for (int i = 0; i < 4; ++i)
#pragma unroll
        for (int jj = 0; jj < 4; ++jj)
          acc[i][jj] = fmaf(xv[i], bv[jj], acc[i][jj]);
    }
    __syncthreads();
  }
  const size_t sb = ((size_t)(bc * NH + hh)) << 12;
#pragma unroll
  for (int i = 0; i < 4; ++i) {
    float4 o = make_float4(acc[i][0], acc[i][1], acc[i][2], acc[i][3]);
    *(float4*)&states[sb + (size_t)(ty * 4 + i) * 64 + tx * 4] = o;
  }
}

// ---------------- K6: sequential inter-chunk state scan (4 chunks) ----------------
__global__ __launch_bounds__(256) void k_scanc(
    const float* __restrict__ states, const float* __restrict__ cdecay,
    float* __restrict__ prev)
{
  int tid = blockIdx.x * 256 + threadIdx.x;   // B_*NH*4096
  int pn  = tid & 4095;
  int rem = tid >> 12;
  int hh  = rem % NH;
  int b   = rem / NH;
  float carry = 0.f;
#pragma unroll
  for (int c = 0; c < 4; ++c) {
    size_t idx = ((size_t)((b * 4 + c) * NH + hh) << 12) + pn;
    prev[idx] = carry;
    carry = carry * cdecay[(b * 4 + c) * NH + hh] + states[idx];
  }
}

// ---------------- K7: y = intra + inter + D*x per (chunk, head, i-tile) ----------------
__global__ __launch_bounds__(256) void k_y(
    const float* __restrict__ x, const float* __restrict__ Cm,
    const float* __restrict__ dtp, const float* __restrict__ dAcs,
    const float* __restrict__ G, const float* __restrict__ prev,
    const float* __restrict__ Dp, float* __restrict__ y)
{
  __shared__ float l1[64 * 65];   // Cs[n][i] then atts[j][i]
  __shared__ float l2[64 * 65];   // Ps[n][p] then xs[j][p]
  __shared__ float dAi[64], dAj[64], dtj[64];
  const int bc = blockIdx.x;
  const int hh = blockIdx.y;
  const int it = blockIdx.z;
  const int t  = threadIdx.x;
  const int tx = t & 15, ty = t >> 4;
  const int i0 = it * 64;
  const size_t base = (size_t)bc * 256;
  if (t < 64) dAi[t] = dAcs[(base + i0 + t) * NH + hh];
  // phase 1: y_inter_raw = C . prev^T
#pragma unroll
  for (int r = 0; r < 4; ++r) {
    int idx = r * 256 + t;
    int a = idx >> 4, q = (idx & 15) * 4;
    float4 v = *(const float4*)&Cm[(base + i0 + a) * DS + q];
    l1[(q + 0) * 65 + a] = v.x; l1[(q + 1) * 65 + a] = v.y;
    l1[(q + 2) * 65 + a] = v.z; l1[(q + 3) * 65 + a] = v.w;
    float4 u2 = *(const float4*)&prev[((size_t)(bc * NH + hh) << 12) + (size_t)a * 64 + q];
    l2[(q + 0) * 65 + a] = u2.x; l2[(q + 1) * 65 + a] = u2.y;
    l2[(q + 2) * 65 + a] = u2.z; l2[(q + 3) * 65 + a] = u2.w;
  }
  __syncthreads();
  float acc[4][4] = {};
  for (int n = 0; n < 64; ++n) {
    float a[4], bb[4];
#pragma unroll
    for (int i = 0; i < 4; ++i) a[i] = l1[n * 65 + ty * 4 + i];
#pragma unroll
    for (int p = 0; p < 4; ++p) bb[p] = l2[n * 65 + tx * 4 + p];
#pragma unroll
    for (int i = 0; i < 4; ++i)
#pragma unroll
      for (int p = 0; p < 4; ++p)
        acc[i][p] = fmaf(a[i], bb[p], acc[i][p]);
  }
  __syncthreads();
#pragma unroll
  for (int i = 0; i < 4; ++i) {
    float e = expf(dAi[ty * 4 + i]);
#pragma unroll
    for (int p = 0; p < 4; ++p) acc[i][p] *= e;
  }
  // phase 2: causal intra-chunk attention tiles
  for (int jt = 0; jt <= it; ++jt) {
    int j0 = jt * 64;
    if (t < 64) {
      size_t r2 = base + j0 + t;
      dAj[t] = dAcs[r2 * NH + hh];
      dtj[t] = dtp[r2 * NH + hh];
    }
#pragma unroll
    for (int r = 0; r < 4; ++r) {
      int idx = r * 256 + t;
      int j = idx >> 4, pq = (idx & 15) * 4;
      float4 v = *(const float4*)&x[(base + j0 + j) * DI + hh * HD + pq];
      l2[j * 65 + pq + 0] = v.x; l2[j * 65 + pq + 1] = v.y;
      l2[j * 65 + pq + 2] = v.z; l2[j * 65 + pq + 3] = v.w;
    }
    __syncthreads();
#pragma unroll
    for (int r = 0; r < 16; ++r) {
      int idx = r * 256 + t;
      int i = idx >> 6, j = idx & 63;
      float av = 0.f;
      if (jt < it || j <= i) {
        float g = G[((size_t)bc << 16) + (size_t)(i0 + i) * 256 + j0 + j];
        av = g * expf(dAi[i] - dAj[j]) * dtj[j];
      }
      l1[j * 65 + i] = av;
    }
    __syncthreads();
    for (int j = 0; j < 64; ++j) {
      float a[4], xv[4];
#pragma unroll
      for (int i = 0; i < 4; ++i) a[i] = l1[j * 65 + ty * 4 + i];
#pragma unroll
      for (int p = 0; p < 4; ++p) xv[p] = l2[j * 65 + tx * 4 + p];
#pragma unroll
      for (int i = 0; i < 4; ++i)
#pragma unroll
        for (int p = 0; p < 4; ++p)
          acc[i][p] = fmaf(a[i], xv[p], acc[i][p]);
    }
    __syncthreads();
  }
  // phase 3: + D*x, store
  const float Dh = Dp[hh];
#pragma unroll
  for (int i = 0; i < 4; ++i) {
    size_t row = base + i0 + ty * 4 + i;
    const float4 xv = *(const float4*)&x[row * DI + hh * HD + tx * 4];
    float4 o;
    o.x = acc[i][0] + Dh * xv.x;
    o.y = acc[i][1] + Dh * xv.y;
    o.z = acc[i][2] + Dh * xv.z;
    o.w = acc[i][3] + Dh * xv.w;
    *(float4*)&y[row * DI + hh * HD + tx * 4] = o;
  }
}

// ---------------- K8: LayerNorm over 768 + multiply z (in place on y) ----------------
__global__ __launch_bounds__(256) void k_norm(
    const float* __restrict__ z, const float* __restrict__ nw,
    const float* __restrict__ nb, float* __restrict__ y)
{
  __shared__ float rs[4], rq[4];
  const size_t row = blockIdx.x;
  const int t = threadIdx.x;
  float v[3];
  float s = 0.f, sq = 0.f;
#pragma unroll
  for (int r = 0; r < 3; ++r) {
    v[r] = y[row * DI + r * 256 + t];
    s += v[r];
    sq = fmaf(v[r], v[r], sq);
  }
#pragma unroll
  for (int off = 32; off > 0; off >>= 1) {
    s  += __shfl_down(s, off, 64);
    sq += __shfl_down(sq, off, 64);
  }
  const int wid = t >> 6, lane = t & 63;
  if (lane == 0) { rs[wid] = s; rq[wid] = sq; }
  __syncthreads();
  if (t == 0) {
    rs[0] = rs[0] + rs[1] + rs[2] + rs[3];
    rq[0] = rq[0] + rq[1] + rq[2] + rq[3];
  }
  __syncthreads();
  const float mu   = rs[0] * (1.f / DI);
  const float var  = rq[0] * (1.f / DI) - mu * mu;
  const float rstd = 1.f / sqrtf(var + EPS_);
#pragma unroll
  for (int r = 0; r < 3; ++r) {
    int d = r * 256 + t;
    float o = (v[r] - mu) * rstd * nw[d] + nb[d];
    y[row * DI + d] = o * z[row * DI + d];
  }
}

// ---------------- K9: out_proj GEMM + fused output transpose ----------------
__global__ __launch_bounds__(256) void k_outproj(
    const float* __restrict__ y, const float* __restrict__ W,
    float* __restrict__ out)
{
  __shared__ float As[16][65];
  __shared__ float Bs[16][65];
  const int m0 = blockIdx.x * 64;
  const int n0 = blockIdx.y * 64;
  const int t  = threadIdx.x;
  const int tx = t & 15, ty = t >> 4;
  float acc[4][4] = {};
  for (int k0 = 0; k0 < DI; k0 += 16) {
    {
      int m = t >> 2, kq = (t & 3) * 4;
      float4 v = *(const float4*)&y[(size_t)(m0 + m) * DI + k0 + kq];
      As[kq + 0][m] = v.x; As[kq + 1][m] = v.y;
      As[kq + 2][m] = v.z; As[kq + 3][m] = v.w;
      float4 w2 = *(const float4*)&W[(size_t)(n0 + m) * DI + k0 + kq];
      Bs[kq + 0][m] = w2.x; Bs[kq + 1][m] = w2.y;
      Bs[kq + 2][m] = w2.z; Bs[kq + 3][m] = w2.w;
    }
    __syncthreads();
#pragma unroll
    for (int k = 0; k < 16; ++k) {
      float a[4], bb[4];
#pragma unroll
      for (int i = 0; i < 4; ++i) a[i] = As[k][ty * 4 + i];
#pragma unroll
      for (int j = 0; j < 4; ++j) bb[j] = Bs[k][tx * 4 + j];
#pragma unroll
      for (int i = 0; i < 4; ++i)
#pragma unroll
        for (int j = 0; j < 4; ++j)
          acc[i][j] = fmaf(a[i], bb[j], acc[i][j]);
    }
    __syncthreads();
  }
  const int b = m0 >> 10, l0 = m0 & 1023;
#pragma unroll
  for (int i = 0; i < 4; ++i) {
#pragma unroll
    for (int j = 0; j < 4; ++j) {
      int n = n0 + tx * 4 + j;
      out[(size_t)b * DM * L_ + (size_t)n * L_ + l0 + ty * 4 + i] = acc[i][j];
    }
  }
}

extern "C" void kernel_launch(void* const* d_in, const int* in_sizes, int n_in,
                              void* d_out, int out_size, void* d_ws, size_t ws_size,
                              hipStream_t stream)
{
  const float* u    = (const float*)d_in[0];
  const float* ipw  = (const float*)d_in[1];
  const float* cw   = (const float*)d_in[2];
  const float* cb   = (const float*)d_in[3];
  const float* dtb  = (const float*)d_in[4];
  const float* Alog = (const float*)d_in[5];
  const float* Dp   = (const float*)d_in[6];
  const float* nw   = (const float*)d_in[7];
  const float* nb   = (const float*)d_in[8];
  const float* opw  = (const float*)d_in[9];
  float* out = (float*)d_out;

  float* ws = (float*)d_ws;
  size_t off = 0;
  float* z_buf   = ws + off; off += (size_t)B_ * L_ * DI;       // 12.58M
  float* xBC_buf = ws + off; off += (size_t)B_ * L_ * CONVD;    // 14.68M
  float* y_buf   = xBC_buf;  // alias: xBC dead after conv, y written later
  float* dt_buf  = ws + off; off += (size_t)B_ * L_ * NH;
  float* x_buf   = ws + off; off += (size_t)B_ * L_ * DI;
  float* Bm_buf  = ws + off; off += (size_t)B_ * L_ * DS;
  float* Cm_buf  = ws + off; off += (size_t)B_ * L_ * DS;
  float* dAcs    = ws + off; off += (size_t)B_ * L_ * NH;
  float* cdec    = ws + off; off += (size_t)B_ * NCH * NH;
  float* G_buf   = ws + off; off += (size_t)B_ * NCH * CH * CH;
  float* st_buf  = ws + off; off += (size_t)B_ * NCH * NH * HD * DS;
  float* pv_buf  = ws + off; off += (size_t)B_ * NCH * NH * HD * DS;

  hipLaunchKernelGGL(k_inproj,  dim3(256, 27), dim3(256), 0, stream, u, ipw, dtb, z_buf, xBC_buf, dt_buf);
  hipLaunchKernelGGL(k_conv,    dim3(14336),   dim3(256), 0, stream, xBC_buf, cw, cb, x_buf, Bm_buf, Cm_buf);
  hipLaunchKernelGGL(k_dtcum,   dim3(64),      dim3(256), 0, stream, dt_buf, Alog, dAcs, cdec);
  hipLaunchKernelGGL(k_G,       dim3(64, 4),   dim3(256), 0, stream, Bm_buf, Cm_buf, G_buf);
  hipLaunchKernelGGL(k_states,  dim3(64, 12),  dim3(256), 0, stream, x_buf, Bm_buf, dt_buf, dAcs, st_buf);
  hipLaunchKernelGGL(k_scanc,   dim3(3072),    dim3(256), 0, stream, st_buf, cdec, pv_buf);
  hipLaunchKernelGGL(k_y,       dim3(64, 12, 4), dim3(256), 0, stream, x_buf, Cm_buf, dt_buf, dAcs, G_buf, pv_buf, Dp, y_buf);
  hipLaunchKernelGGL(k_norm,    dim3(16384),   dim3(256), 0, stream, z_buf, nw, nb, y_buf);
  hipLaunchKernelGGL(k_outproj, dim3(256, 6),  dim3(256), 0, stream, y_buf, opw, out);
}

// Round 2
// 568.314 us; speedup vs baseline: 1.7812x; 1.7812x over previous
//
#include <hip/hip_runtime.h>
#include <hip/hip_bf16.h>

#define B_    16
#define L_    1024
#define DM    384
#define DIP   1676
#define NP1   1792
#define DI    768
#define CONVD 896
#define NH    12
#define HD    64
#define DS    64
#define NCH   4
#define CH    256
#define EPS_  1e-5f

typedef unsigned short u16;
typedef unsigned int   u32;
typedef __attribute__((ext_vector_type(8))) short bf16x8;
typedef __attribute__((ext_vector_type(4))) float f32x4;

// bf16 round-to-nearest-even split helpers (bit ops, no header type issues)
__device__ __forceinline__ u16 f2b(float v) {
  u32 u = __float_as_uint(v);
  u32 r = (u + 0x7FFFu + ((u >> 16) & 1u)) >> 16;
  return (u16)r;
}
__device__ __forceinline__ float b2f(u16 h) { return __uint_as_float(((u32)h) << 16); }
__device__ __forceinline__ void bsplit(float v, u16& h, u16& l) {
  u16 hh = f2b(v);
  l = f2b(v - b2f(hh));
  h = hh;
}

// ---------------- converters ----------------
// u[b, k, l] -> Ah/Al[m=b*1024+l][k]  (transpose via LDS, split to bf16 hi/lo)
__global__ __launch_bounds__(256) void k_cvtA(const float* __restrict__ u,
                                              u16* __restrict__ Ah, u16* __restrict__ Al)
{
  __shared__ float Ls[32][129];
  const int t  = threadIdx.x;
  const int l0 = blockIdx.x * 128;
  const int k0 = blockIdx.y * 32;
  const int b  = blockIdx.z;
#pragma unroll
  for (int r = 0; r < 4; ++r) {
    int idx = r * 256 + t;
    int kk = idx >> 5, q = idx & 31;
    float4 v = *(const float4*)&u[((size_t)(b * DM + k0 + kk)) * L_ + l0 + q * 4];
    Ls[kk][q * 4 + 0] = v.x; Ls[kk][q * 4 + 1] = v.y;
    Ls[kk][q * 4 + 2] = v.z; Ls[kk][q * 4 + 3] = v.w;
  }
  __syncthreads();
#pragma unroll
  for (int it = 0; it < 2; ++it) {
    int task = it * 256 + t;
    int l = task >> 2, kq = (task & 3) * 8;
    u32 hw[4], lw[4];
#pragma unroll
    for (int j = 0; j < 4; ++j) {
      u16 h0, l0v, h1, l1v;
      bsplit(Ls[kq + 2 * j + 0][l], h0, l0v);
      bsplit(Ls[kq + 2 * j + 1][l], h1, l1v);
      hw[j] = (u32)h0 | ((u32)h1 << 16);
      lw[j] = (u32)l0v | ((u32)l1v << 16);
    }
    size_t off = ((size_t)(b * L_ + l0 + l)) * DM + k0 + kq;
    *(uint4*)&Ah[off] = make_uint4(hw[0], hw[1], hw[2], hw[3]);
    *(uint4*)&Al[off] = make_uint4(lw[0], lw[1], lw[2], lw[3]);
  }
}

// row-major [n][K] fp32 -> bf16 hi/lo pair, zero-padding rows >= nsrc
__global__ __launch_bounds__(256) void k_cvtW(const float* __restrict__ W,
    u16* __restrict__ Wh, u16* __restrict__ Wl, int nsrc, int K, int total4)
{
  int i = blockIdx.x * 256 + threadIdx.x;
  if (i >= total4) return;
  int e = i * 4;
  int row = e / K;
  float4 v = make_float4(0.f, 0.f, 0.f, 0.f);
  if (row < nsrc) v = *(const float4*)&W[e];
  u16 h[4], l[4];
  bsplit(v.x, h[0], l[0]); bsplit(v.y, h[1], l[1]);
  bsplit(v.z, h[2], l[2]); bsplit(v.w, h[3], l[3]);
  *(uint2*)&Wh[e] = make_uint2((u32)h[0] | ((u32)h[1] << 16), (u32)h[2] | ((u32)h[3] << 16));
  *(uint2*)&Wl[e] = make_uint2((u32)l[0] | ((u32)l[1] << 16), (u32)l[2] | ((u32)l[3] << 16));
}

// ---------------- bf16x3 MFMA GEMM: in_proj ----------------
// C[m,n] = sum_k A[m,k]W[n,k]; M=16384, Npad=1792, K=384.
// 128x128 tile, BK=32, 4 waves each 64x64 (4x4 frags of 16x16x32).
// LDS layout swizzle: 16B slot s = g ^ ((m>>1)&3) -> even 8-access/bank ds_read_b128.
__global__ __launch_bounds__(256) void k_gemm1(
    const u16* __restrict__ Ah, const u16* __restrict__ Al,
    const u16* __restrict__ Bh, const u16* __restrict__ Bl,
    const float* __restrict__ dt_bias,
    float* __restrict__ z, float* __restrict__ xBC, float* __restrict__ dt)
{
  __shared__ u16 lds[16384];   // [Ah 4096][Al 4096][Bh 4096][Bl 4096] u16
  const int t = threadIdx.x;
  const int lane = t & 63, wid = t >> 6;
  const int wr = wid >> 1, wc = wid & 1;
  const int gg = lane >> 4, mlo = lane & 15;
  const int m0 = blockIdx.x * 128, n0 = blockIdx.y * 128;
  f32x4 acc[4][4];
#pragma unroll
  for (int i = 0; i < 4; ++i)
#pragma unroll
    for (int j = 0; j < 4; ++j) acc[i][j] = (f32x4){0.f, 0.f, 0.f, 0.f};
  const u16* g0 = Ah + (size_t)m0 * DM;
  const u16* g1 = Al + (size_t)m0 * DM;
  const u16* g2 = Bh + (size_t)n0 * DM;
  const u16* g3 = Bl + (size_t)n0 * DM;
  const char* ldsb = (const char*)lds;
  for (int k0 = 0; k0 < DM; k0 += 32) {
#pragma unroll
    for (int i = 0; i < 2; ++i) {
      int S = i * 256 + t;
      int m = S >> 2;
      int g = (S ^ (m >> 1)) & 3;
      size_t goff = (size_t)m * DM + k0 + g * 8;
      __builtin_amdgcn_global_load_lds((const __attribute__((address_space(1))) u32*)(g0 + goff),
          (__attribute__((address_space(3))) u32*)(lds + S * 8), 16, 0, 0);
      __builtin_amdgcn_global_load_lds((const __attribute__((address_space(1))) u32*)(g1 + goff),
          (__attribute__((address_space(3))) u32*)(lds + 4096 + S * 8), 16, 0, 0);
      __builtin_amdgcn_global_load_lds((const __attribute__((address_space(1))) u32*)(g2 + goff),
          (__attribute__((address_space(3))) u32*)(lds + 8192 + S * 8), 16, 0, 0);
      __builtin_amdgcn_global_load_lds((const __attribute__((address_space(1))) u32*)(g3 + goff),
          (__attribute__((address_space(3))) u32*)(lds + 12288 + S * 8), 16, 0, 0);
    }
    __syncthreads();
    bf16x8 fa[4], fal[4], fb[4], fbl[4];
#pragma unroll
    for (int mf = 0; mf < 4; ++mf) {
      int m = wr * 64 + mf * 16 + mlo;
      int off = m * 64 + (((gg ^ (m >> 1)) & 3) << 4);
      fa[mf]  = *(const bf16x8*)(ldsb + off);
      fal[mf] = *(const bf16x8*)(ldsb + 8192 + off);
    }
#pragma unroll
    for (int nf = 0; nf < 4; ++nf) {
      int n = wc * 64 + nf * 16 + mlo;
      int off = n * 64 + (((gg ^ (n >> 1)) & 3) << 4);
      fb[nf]  = *(const bf16x8*)(ldsb + 16384 + off);
      fbl[nf] = *(const bf16x8*)(ldsb + 24576 + off);
    }
#pragma unroll
    for (int mf = 0; mf < 4; ++mf)
#pragma unroll
      for (int nf = 0; nf < 4; ++nf) {
        acc[mf][nf] = __builtin_amdgcn_mfma_f32_16x16x32_bf16(fa[mf],  fb[nf],  acc[mf][nf], 0, 0, 0);
        acc[mf][nf] = __builtin_amdgcn_mfma_f32_16x16x32_bf16(fa[mf],  fbl[nf], acc[mf][nf], 0, 0, 0);
        acc[mf][nf] = __builtin_amdgcn_mfma_f32_16x16x32_bf16(fal[mf], fb[nf],  acc[mf][nf], 0, 0, 0);
      }
    __syncthreads();
  }
  const int rb = m0 + wr * 64 + (lane >> 4) * 4;
  const int cb = n0 + wc * 64 + mlo;
#pragma unroll
  for (int mf = 0; mf < 4; ++mf)
#pragma unroll
    for (int nf = 0; nf < 4; ++nf) {
      int col = cb + nf * 16;
#pragma unroll
      for (int r = 0; r < 4; ++r) {
        int row = rb + mf * 16 + r;
        float v = acc[mf][nf][r];
        if (col < DI) z[(size_t)row * DI + col] = v;
        else if (col < DI + CONVD) xBC[(size_t)row * CONVD + (col - DI)] = v;
        else if (col < DIP) {
          int hh = col - (DI + CONVD);
          float xv = v + dt_bias[hh];
          dt[(size_t)row * NH + hh] = (xv > 20.f) ? xv : log1pf(expf(xv));
        }
      }
    }
}

// ---------------- bf16x3 MFMA GEMM: out_proj (+fused output transpose) ----------------
// M=16384, N=384, K=768
__global__ __launch_bounds__(256) void k_gemm2(
    const u16* __restrict__ Ah, const u16* __restrict__ Al,
    const u16* __restrict__ Bh, const u16* __restrict__ Bl,
    float* __restrict__ out)
{
  __shared__ u16 lds[16384];
  const int t = threadIdx.x;
  const int lane = t & 63, wid = t >> 6;
  const int wr = wid >> 1, wc = wid & 1;
  const int gg = lane >> 4, mlo = lane & 15;
  const int m0 = blockIdx.x * 128, n0 = blockIdx.y * 128;
  f32x4 acc[4][4];
#pragma unroll
  for (int i = 0; i < 4; ++i)
#pragma unroll
    for (int j = 0; j < 4; ++j) acc[i][j] = (f32x4){0.f, 0.f, 0.f, 0.f};
  const u16* g0 = Ah + (size_t)m0 * DI;
  const u16* g1 = Al + (size_t)m0 * DI;
  const u16* g2 = Bh + (size_t)n0 * DI;
  const u16* g3 = Bl + (size_t)n0 * DI;
  const char* ldsb = (const char*)lds;
  for (int k0 = 0; k0 < DI; k0 += 32) {
#pragma unroll
    for (int i = 0; i < 2; ++i) {
      int S = i * 256 + t;
      int m = S >> 2;
      int g = (S ^ (m >> 1)) & 3;
      size_t goff = (size_t)m * DI + k0 + g * 8;
      __builtin_amdgcn_global_load_lds((const __attribute__((address_space(1))) u32*)(g0 + goff),
          (__attribute__((address_space(3))) u32*)(lds + S * 8), 16, 0, 0);
      __builtin_amdgcn_global_load_lds((const __attribute__((address_space(1))) u32*)(g1 + goff),
          (__attribute__((address_space(3))) u32*)(lds + 4096 + S * 8), 16, 0, 0);
      __builtin_amdgcn_global_load_lds((const __attribute__((address_space(1))) u32*)(g2 + goff),
          (__attribute__((address_space(3))) u32*)(lds + 8192 + S * 8), 16, 0, 0);
      __builtin_amdgcn_global_load_lds((const __attribute__((address_space(1))) u32*)(g3 + goff),
          (__attribute__((address_space(3))) u32*)(lds + 12288 + S * 8), 16, 0, 0);
    }
    __syncthreads();
    bf16x8 fa[4], fal[4], fb[4], fbl[4];
#pragma unroll
    for (int mf = 0; mf < 4; ++mf) {
      int m = wr * 64 + mf * 16 + mlo;
      int off = m * 64 + (((gg ^ (m >> 1)) & 3) << 4);
      fa[mf]  = *(const bf16x8*)(ldsb + off);
      fal[mf] = *(const bf16x8*)(ldsb + 8192 + off);
    }
#pragma unroll
    for (int nf = 0; nf < 4; ++nf) {
      int n = wc * 64 + nf * 16 + mlo;
      int off = n * 64 + (((gg ^ (n >> 1)) & 3) << 4);
      fb[nf]  = *(const bf16x8*)(ldsb + 16384 + off);
      fbl[nf] = *(const bf16x8*)(ldsb + 24576 + off);
    }
#pragma unroll
    for (int mf = 0; mf < 4; ++mf)
#pragma unroll
      for (int nf = 0; nf < 4; ++nf) {
        acc[mf][nf] = __builtin_amdgcn_mfma_f32_16x16x32_bf16(fa[mf],  fb[nf],  acc[mf][nf], 0, 0, 0);
        acc[mf][nf] = __builtin_amdgcn_mfma_f32_16x16x32_bf16(fa[mf],  fbl[nf], acc[mf][nf], 0, 0, 0);
        acc[mf][nf] = __builtin_amdgcn_mfma_f32_16x16x32_bf16(fal[mf], fb[nf],  acc[mf][nf], 0, 0, 0);
      }
    __syncthreads();
  }
  const int rb = m0 + wr * 64 + (lane >> 4) * 4;
  const int cb = n0 + wc * 64 + mlo;
#pragma unroll
  for (int mf = 0; mf < 4; ++mf)
#pragma unroll
    for (int nf = 0; nf < 4; ++nf) {
      int col = cb + nf * 16;       // < 384 always (N=384, 3 col-tiles)
#pragma unroll
      for (int r = 0; r < 4; ++r) {
        int row = rb + mf * 16 + r;
        int b = row >> 10, l = row & 1023;
        out[((size_t)(b * DM + col)) * L_ + l] = acc[mf][nf][r];
      }
    }
}

// ---------------- K2: depthwise 3x3 conv SAME + bias + SiLU + split ----------------
__global__ __launch_bounds__(256) void k_conv(
    const float* __restrict__ xBC, const float* __restrict__ cw,
    const float* __restrict__ cb,
    float* __restrict__ x, float* __restrict__ Bm, float* __restrict__ Cm)
{
  int tid = blockIdx.x * 256 + threadIdx.x;
  int c4  = tid % 224;
  int rem = tid / 224;
  int l   = rem & 1023;
  int b   = rem >> 10;
  if (b >= B_) return;
  int h = l >> 5, w = l & 31;
  int c = c4 * 4;
  float acc[4];
#pragma unroll
  for (int j = 0; j < 4; ++j) acc[j] = cb[c + j];
#pragma unroll
  for (int dh = -1; dh <= 1; ++dh) {
    int hh = h + dh;
    if (hh < 0 || hh >= 32) continue;
#pragma unroll
    for (int dw = -1; dw <= 1; ++dw) {
      int ww = w + dw;
      if (ww < 0 || ww >= 32) continue;
      const float4 v = *(const float4*)&xBC[((size_t)(b * 1024 + hh * 32 + ww)) * CONVD + c];
      int kb = (dh + 1) * 3 + (dw + 1);
      acc[0] = fmaf(v.x, cw[(c + 0) * 9 + kb], acc[0]);
      acc[1] = fmaf(v.y, cw[(c + 1) * 9 + kb], acc[1]);
      acc[2] = fmaf(v.z, cw[(c + 2) * 9 + kb], acc[2]);
      acc[3] = fmaf(v.w, cw[(c + 3) * 9 + kb], acc[3]);
    }
  }
  size_t row = (size_t)b * 1024 + l;
#pragma unroll
  for (int j = 0; j < 4; ++j) {
    float v = acc[j];
    float s = v / (1.f + expf(-v));
    int cc = c + j;
    if (cc < DI) x[row * DI + cc] = s;
    else if (cc < DI + DS) Bm[row * DS + (cc - DI)] = s;
    else Cm[row * DS + (cc - DI - DS)] = s;
  }
}

// ---------------- K3: dt*A cumsum per chunk ----------------
__global__ __launch_bounds__(256) void k_dtcum(
    const float* __restrict__ dt, const float* __restrict__ A_log,
    float* __restrict__ dAcs, float* __restrict__ cdecay)
{
  __shared__ float s[256];
  const int bc = blockIdx.x;
  const int i  = threadIdx.x;
  const size_t row = (size_t)bc * 256 + i;
  for (int h = 0; h < NH; ++h) {
    float A = -expf(A_log[h]);
    float v = dt[row * NH + h] * A;
    s[i] = v;
    __syncthreads();
#pragma unroll
    for (int off = 1; off < 256; off <<= 1) {
      float add = (i >= off) ? s[i - off] : 0.f;
      __syncthreads();
      s[i] += add;
      __syncthreads();
    }
    float cs = s[i];
    dAcs[row * NH + h] = cs;
    if (i == 255) cdecay[bc * NH + h] = expf(cs);
    __syncthreads();
  }
}

// ---------------- K4: G[i,j] = C_i . B_j per chunk ----------------
__global__ __launch_bounds__(256) void k_G(
    const float* __restrict__ Bm, const float* __restrict__ Cm,
    float* __restrict__ G)
{
  __shared__ float Cs[64 * 65];
  __shared__ float Bs[64 * 65];
  const int bc = blockIdx.x;
  const int it = blockIdx.y;
  const int t  = threadIdx.x;
  const int tx = t & 15, ty = t >> 4;
  const int i0 = it * 64;
  const size_t base = (size_t)bc * 256;
#pragma unroll
  for (int r = 0; r < 4; ++r) {
    int idx = r * 256 + t;
    int a = idx >> 4, q = (idx & 15) * 4;
    float4 v = *(const float4*)&Cm[(base + i0 + a) * DS + q];
    Cs[(q + 0) * 65 + a] = v.x; Cs[(q + 1) * 65 + a] = v.y;
    Cs[(q + 2) * 65 + a] = v.z; Cs[(q + 3) * 65 + a] = v.w;
  }
  for (int jt = 0; jt < 4; ++jt) {
    __syncthreads();
    int j0 = jt * 64;
#pragma unroll
    for (int r = 0; r < 4; ++r) {
      int idx = r * 256 + t;
      int a = idx >> 4, q = (idx & 15) * 4;
      float4 v = *(const float4*)&Bm[(base + j0 + a) * DS + q];
      Bs[(q + 0) * 65 + a] = v.x; Bs[(q + 1) * 65 + a] = v.y;
      Bs[(q + 2) * 65 + a] = v.z; Bs[(q + 3) * 65 + a] = v.w;
    }
    __syncthreads();
    float acc[4][4] = {};
    for (int n = 0; n < 64; ++n) {
      float a[4], bb[4];
#pragma unroll
      for (int i = 0; i < 4; ++i) a[i] = Cs[n * 65 + ty * 4 + i];
#pragma unroll
      for (int j = 0; j < 4; ++j) bb[j] = Bs[n * 65 + tx * 4 + j];
#pragma unroll
      for (int i = 0; i < 4; ++i)
#pragma unroll
        for (int j = 0; j < 4; ++j)
          acc[i][j] = fmaf(a[i], bb[j], acc[i][j]);
    }
#pragma unroll
    for (int i = 0; i < 4; ++i) {
      float4 o = make_float4(acc[i][0], acc[i][1], acc[i][2], acc[i][3]);
      *(float4*)&G[((size_t)bc << 16) + (size_t)(i0 + ty * 4 + i) * 256 + j0 + tx * 4] = o;
    }
  }
}

// ---------------- K5: chunk states ----------------
__global__ __launch_bounds__(256) void k_states(
    const float* __restrict__ x, const float* __restrict__ Bm,
    const float* __restrict__ dt, const float* __restrict__ dAcs,
    float* __restrict__ states)
{
  __shared__ float xs[64 * 65];
  __shared__ float Bs[64 * 65];
  __shared__ float wj[64];
  const int bc = blockIdx.x;
  const int hh = blockIdx.y;
  const int t  = threadIdx.x;
  const int tx = t & 15, ty = t >> 4;
  const size_t base = (size_t)bc * 256;
  const float last = dAcs[(base + 255) * NH + hh];
  float acc[4][4] = {};
  for (int j0 = 0; j0 < 256; j0 += 64) {
#pragma unroll
    for (int r = 0; r < 4; ++r) {
      int idx = r * 256 + t;
      int j = idx >> 4, pq = (idx & 15) * 4;
      float4 v = *(const float4*)&x[(base + j0 + j) * DI + hh * HD + pq];
      xs[j * 65 + pq + 0] = v.x; xs[j * 65 + pq + 1] = v.y;
      xs[j * 65 + pq + 2] = v.z; xs[j * 65 + pq + 3] = v.w;
      float4 u2 = *(const float4*)&Bm[(base + j0 + j) * DS + pq];
      Bs[j * 65 + pq + 0] = u2.x; Bs[j * 65 + pq + 1] = u2.y;
      Bs[j * 65 + pq + 2] = u2.z; Bs[j * 65 + pq + 3] = u2.w;
    }
    if (t < 64) {
      size_t r2 = base + j0 + t;
      wj[t] = expf(last - dAcs[r2 * NH + hh]) * dt[r2 * NH + hh];
    }
    __syncthreads();
    for (int j = 0; j < 64; ++j) {
      float w = wj[j];
      float xv[4], bv[4];
#pragma unroll
      for (int i = 0; i < 4; ++i) xv[i] = xs[j * 65 + ty * 4 + i] * w;
#pragma unroll
      for (int jj = 0; jj < 4; ++jj) bv[jj] = Bs[j * 65 + tx * 4 + jj];
#pragma unroll
      for (int i = 0; i < 4; ++i)
#pragma unroll
        for (int jj = 0; jj < 4; ++jj)
          acc[i][jj] = fmaf(xv[i], bv[jj], acc[i][jj]);
    }
    __syncthreads();
  }
  const size_t sb = ((size_t)(bc * NH + hh)) << 12;
#pragma unroll
  for (int i = 0; i < 4; ++i) {
    float4 o = make_float4(acc[i][0], acc[i][1], acc[i][2], acc[i][3]);
    *(float4*)&states[sb + (size_t)(ty * 4 + i) * 64 + tx * 4] = o;
  }
}

// ---------------- K6: inter-chunk scan ----------------
__global__ __launch_bounds__(256) void k_scanc(
    const float* __restrict__ states, const float* __restrict__ cdecay,
    float* __restrict__ prev)
{
  int tid = blockIdx.x * 256 + threadIdx.x;
  int pn  = tid & 4095;
  int rem = tid >> 12;
  int hh  = rem % NH;
  int b   = rem / NH;
  float carry = 0.f;
#pragma unroll
  for (int c = 0; c < 4; ++c) {
    size_t idx = ((size_t)((b * 4 + c) * NH + hh) << 12) + pn;
    prev[idx] = carry;
    carry = carry * cdecay[(b * 4 + c) * NH + hh] + states[idx];
  }
}

// ---------------- K7: y = intra + inter + D*x ----------------
__global__ __launch_bounds__(256) void k_y(
    const float* __restrict__ x, const float* __restrict__ Cm,
    const float* __restrict__ dtp, const float* __restrict__ dAcs,
    const float* __restrict__ G, const float* __restrict__ prev,
    const float* __restrict__ Dp, float* __restrict__ y)
{
  __shared__ float l1[64 * 65];
  __shared__ float l2[64 * 65];
  __shared__ float dAi[64], dAj[64], dtj[64];
  const int bc = blockIdx.x;
  const int hh = blockIdx.y;
  const int it = blockIdx.z;
  const int t  = threadIdx.x;
  const int tx = t & 15, ty = t >> 4;
  const int i0 = it * 64;
  const size_t base = (size_t)bc * 256;
  if (t < 64) dAi[t] = dAcs[(base + i0 + t) * NH + hh];
#pragma unroll
  for (int r = 0; r < 4; ++r) {
    int idx = r * 256 + t;
    int a = idx >> 4, q = (idx & 15) * 4;
    float4 v = *(const float4*)&Cm[(base + i0 + a) * DS + q];
    l1[(q + 0) * 65 + a] = v.x; l1[(q + 1) * 65 + a] = v.y;
    l1[(q + 2) * 65 + a] = v.z; l1[(q + 3) * 65 + a] = v.w;
    float4 u2 = *(const float4*)&prev[((size_t)(bc * NH + hh) << 12) + (size_t)a * 64 + q];
    l2[(q + 0) * 65 + a] = u2.x; l2[(q + 1) * 65 + a] = u2.y;
    l2[(q + 2) * 65 + a] = u2.z; l2[(q + 3) * 65 + a] = u2.w;
  }
  __syncthreads();
  float acc[4][4] = {};
  for (int n = 0; n < 64; ++n) {
    float a[4], bb[4];
#pragma unroll
    for (int i = 0; i < 4; ++i) a[i] = l1[n * 65 + ty * 4 + i];
#pragma unroll
    for (int p = 0; p < 4; ++p) bb[p] = l2[n * 65 + tx * 4 + p];
#pragma unroll
    for (int i = 0; i < 4; ++i)
#pragma unroll
      for (int p = 0; p < 4; ++p)
        acc[i][p] = fmaf(a[i], bb[p], acc[i][p]);
  }
  __syncthreads();
#pragma unroll
  for (int i = 0; i < 4; ++i) {
    float e = expf(dAi[ty * 4 + i]);
#pragma unroll
    for (int p = 0; p < 4; ++p) acc[i][p] *= e;
  }
  for (int jt = 0; jt <= it; ++jt) {
    int j0 = jt * 64;
    if (t < 64) {
      size_t r2 = base + j0 + t;
      dAj[t] = dAcs[r2 * NH + hh];
      dtj[t] = dtp[r2 * NH + hh];
    }
#pragma unroll
    for (int r = 0; r < 4; ++r) {
      int idx = r * 256 + t;
      int j = idx >> 4, pq = (idx & 15) * 4;
      float4 v = *(const float4*)&x[(base + j0 + j) * DI + hh * HD + pq];
      l2[j * 65 + pq + 0] = v.x; l2[j * 65 + pq + 1] = v.y;
      l2[j * 65 + pq + 2] = v.z; l2[j * 65 + pq + 3] = v.w;
    }
    __syncthreads();
#pragma unroll
    for (int r = 0; r < 16; ++r) {
      int idx = r * 256 + t;
      int i = idx >> 6, j = idx & 63;
      float av = 0.f;
      if (jt < it || j <= i) {
        float g = G[((size_t)bc << 16) + (size_t)(i0 + i) * 256 + j0 + j];
        av = g * expf(dAi[i] - dAj[j]) * dtj[j];
      }
      l1[j * 65 + i] = av;
    }
    __syncthreads();
    for (int j = 0; j < 64; ++j) {
      float a[4], xv[4];
#pragma unroll
      for (int i = 0; i < 4; ++i) a[i] = l1[j * 65 + ty * 4 + i];
#pragma unroll
      for (int p = 0; p < 4; ++p) xv[p] = l2[j * 65 + tx * 4 + p];
#pragma unroll
      for (int i = 0; i < 4; ++i)
#pragma unroll
        for (int p = 0; p < 4; ++p)
          acc[i][p] = fmaf(a[i], xv[p], acc[i][p]);
    }
    __syncthreads();
  }
  const float Dh = Dp[hh];
#pragma unroll
  for (int i = 0; i < 4; ++i) {
    size_t row = base + i0 + ty * 4 + i;
    const float4 xv = *(const float4*)&x[row * DI + hh * HD + tx * 4];
    float4 o;
    o.x = acc[i][0] + Dh * xv.x;
    o.y = acc[i][1] + Dh * xv.y;
    o.z = acc[i][2] + Dh * xv.z;
    o.w = acc[i][3] + Dh * xv.w;
    *(float4*)&y[row * DI + hh * HD + tx * 4] = o;
  }
}

// ---------------- K8: LayerNorm * z -> bf16 hi/lo pair for out_proj ----------------
__global__ __launch_bounds__(256) void k_norm(
    const float* __restrict__ z, const float* __restrict__ nw,
    const float* __restrict__ nb, const float* __restrict__ y,
    u16* __restrict__ yh, u16* __restrict__ yl)
{
  __shared__ float rs[4], rq[4];
  const size_t row = blockIdx.x;
  const int t = threadIdx.x;
  float v[3];
  float s = 0.f, sq = 0.f;
#pragma unroll
  for (int r = 0; r < 3; ++r) {
    v[r] = y[row * DI + r * 256 + t];
    s += v[r];
    sq = fmaf(v[r], v[r], sq);
  }
#pragma unroll
  for (int off = 32; off > 0; off >>= 1) {
    s  += __shfl_down(s, off, 64);
    sq += __shfl_down(sq, off, 64);
  }
  const int wid = t >> 6, lane = t & 63;
  if (lane == 0) { rs[wid] = s; rq[wid] = sq; }
  __syncthreads();
  if (t == 0) {
    rs[0] = rs[0] + rs[1] + rs[2] + rs[3];
    rq[0] = rq[0] + rq[1] + rq[2] + rq[3];
  }
  __syncthreads();
  const float mu   = rs[0] * (1.f / DI);
  const float var  = rq[0] * (1.f / DI) - mu * mu;
  const float rstd = 1.f / sqrtf(var + EPS_);
#pragma unroll
  for (int r = 0; r < 3; ++r) {
    int d = r * 256 + t;
    float o = (v[r] - mu) * rstd * nw[d] + nb[d];
    float p = o * z[row * DI + d];
    u16 h, l;
    bsplit(p, h, l);
    yh[row * DI + d] = h;
    yl[row * DI + d] = l;
  }
}

extern "C" void kernel_launch(void* const* d_in, const int* in_sizes, int n_in,
                              void* d_out, int out_size, void* d_ws, size_t ws_size,
                              hipStream_t stream)
{
  const float* u    = (const float*)d_in[0];
  const float* ipw  = (const float*)d_in[1];
  const float* cw   = (const float*)d_in[2];
  const float* cb   = (const float*)d_in[3];
  const float* dtb  = (const float*)d_in[4];
  const float* Alog = (const float*)d_in[5];
  const float* Dp   = (const float*)d_in[6];
  const float* nw   = (const float*)d_in[7];
  const float* nb   = (const float*)d_in[8];
  const float* opw  = (const float*)d_in[9];
  float* out = (float*)d_out;

  float* ws = (float*)d_ws;
  size_t off = 0;
  float* z_buf   = ws + off; off += (size_t)B_ * L_ * DI;
  float* xBC_buf = ws + off; off += (size_t)B_ * L_ * CONVD;
  float* y_buf   = xBC_buf;                       // alias: xBC dead after conv
  float* dt_buf  = ws + off; off += (size_t)B_ * L_ * NH;
  float* x_buf   = ws + off; off += (size_t)B_ * L_ * DI;
  float* Bm_buf  = ws + off; off += (size_t)B_ * L_ * DS;
  float* Cm_buf  = ws + off; off += (size_t)B_ * L_ * DS;
  float* dAcs    = ws + off; off += (size_t)B_ * L_ * NH;
  float* cdec    = ws + off; off += (size_t)B_ * NCH * NH;
  float* G_buf   = ws + off; off += (size_t)B_ * NCH * CH * CH;
  float* st_buf  = ws + off; off += (size_t)B_ * NCH * NH * HD * DS;
  float* pv_buf  = ws + off; off += (size_t)B_ * NCH * NH * HD * DS;
  u16*   Woh     = (u16*)(ws + off); off += (size_t)DM * DI / 2;
  u16*   Wol     = (u16*)(ws + off); off += (size_t)DM * DI / 2;

  // aliases inside x_buf (x written by k_conv AFTER gemm1 consumes Ah/Al/Wh/Wl;
  // yh/yl written by k_norm AFTER k_y consumes x)
  u16* Ah = (u16*)x_buf;                             // 16384*384
  u16* Al = Ah + (size_t)B_ * L_ * DM;
  u16* Wh = Al + (size_t)B_ * L_ * DM;               // 1792*384 (padded)
  u16* Wl = Wh + (size_t)NP1 * DM;
  u16* yh = (u16*)x_buf;                             // 16384*768
  u16* yl = yh + (size_t)B_ * L_ * DI;

  hipLaunchKernelGGL(k_cvtA, dim3(8, 12, 16), dim3(256), 0, stream, u, Ah, Al);
  hipLaunchKernelGGL(k_cvtW, dim3((NP1 * DM / 4 + 255) / 256), dim3(256), 0, stream,
                     ipw, Wh, Wl, DIP, DM, NP1 * DM / 4);
  hipLaunchKernelGGL(k_cvtW, dim3((DM * DI / 4 + 255) / 256), dim3(256), 0, stream,
                     opw, Woh, Wol, DM, DI, DM * DI / 4);
  hipLaunchKernelGGL(k_gemm1, dim3(128, 14), dim3(256), 0, stream,
                     Ah, Al, Wh, Wl, dtb, z_buf, xBC_buf, dt_buf);
  hipLaunchKernelGGL(k_conv,   dim3(14336), dim3(256), 0, stream, xBC_buf, cw, cb, x_buf, Bm_buf, Cm_buf);
  hipLaunchKernelGGL(k_dtcum,  dim3(64),    dim3(256), 0, stream, dt_buf, Alog, dAcs, cdec);
  hipLaunchKernelGGL(k_G,      dim3(64, 4), dim3(256), 0, stream, Bm_buf, Cm_buf, G_buf);
  hipLaunchKernelGGL(k_states, dim3(64, 12), dim3(256), 0, stream, x_buf, Bm_buf, dt_buf, dAcs, st_buf);
  hipLaunchKernelGGL(k_scanc,  dim3(3072),  dim3(256), 0, stream, st_buf, cdec, pv_buf);
  hipLaunchKernelGGL(k_y,      dim3(64, 12, 4), dim3(256), 0, stream,
                     x_buf, Cm_buf, dt_buf, dAcs, G_buf, pv_buf, Dp, y_buf);
  hipLaunchKernelGGL(k_norm,   dim3(16384), dim3(256), 0, stream, z_buf, nw, nb, y_buf, yh, yl);
  hipLaunchKernelGGL(k_gemm2,  dim3(128, 3), dim3(256), 0, stream, yh, yl, Woh, Wol, out);
}

// Round 3
// 426.930 us; speedup vs baseline: 2.3711x; 1.3312x over previous
//
#include <hip/hip_runtime.h>
#include <hip/hip_bf16.h>

#define B_    16
#define L_    1024
#define DM    384
#define DIP   1676
#define NP1   1792
#define DI    768
#define CONVD 896
#define NH    12
#define HD    64
#define DS    64
#define NCH   4
#define CH    256
#define EPS_  1e-5f

typedef unsigned short u16;
typedef unsigned int   u32;
typedef __attribute__((ext_vector_type(8))) short bf16x8;
typedef __attribute__((ext_vector_type(4))) float f32x4;

// bf16 round-to-nearest-even split helpers
__device__ __forceinline__ u16 f2b(float v) {
  u32 u = __float_as_uint(v);
  u32 r = (u + 0x7FFFu + ((u >> 16) & 1u)) >> 16;
  return (u16)r;
}
__device__ __forceinline__ float b2f(u16 h) { return __uint_as_float(((u32)h) << 16); }
__device__ __forceinline__ void bsplit(float v, u16& h, u16& l) {
  u16 hh = f2b(v);
  l = f2b(v - b2f(hh));
  h = hh;
}

// ---------------- converters ----------------
__global__ __launch_bounds__(256) void k_cvtA(const float* __restrict__ u,
                                              u16* __restrict__ Ah, u16* __restrict__ Al)
{
  __shared__ float Ls[32][129];
  const int t  = threadIdx.x;
  const int l0 = blockIdx.x * 128;
  const int k0 = blockIdx.y * 32;
  const int b  = blockIdx.z;
#pragma unroll
  for (int r = 0; r < 4; ++r) {
    int idx = r * 256 + t;
    int kk = idx >> 5, q = idx & 31;
    float4 v = *(const float4*)&u[((size_t)(b * DM + k0 + kk)) * L_ + l0 + q * 4];
    Ls[kk][q * 4 + 0] = v.x; Ls[kk][q * 4 + 1] = v.y;
    Ls[kk][q * 4 + 2] = v.z; Ls[kk][q * 4 + 3] = v.w;
  }
  __syncthreads();
#pragma unroll
  for (int it = 0; it < 2; ++it) {
    int task = it * 256 + t;
    int l = task >> 2, kq = (task & 3) * 8;
    u32 hw[4], lw[4];
#pragma unroll
    for (int j = 0; j < 4; ++j) {
      u16 h0, l0v, h1, l1v;
      bsplit(Ls[kq + 2 * j + 0][l], h0, l0v);
      bsplit(Ls[kq + 2 * j + 1][l], h1, l1v);
      hw[j] = (u32)h0 | ((u32)h1 << 16);
      lw[j] = (u32)l0v | ((u32)l1v << 16);
    }
    size_t off = ((size_t)(b * L_ + l0 + l)) * DM + k0 + kq;
    *(uint4*)&Ah[off] = make_uint4(hw[0], hw[1], hw[2], hw[3]);
    *(uint4*)&Al[off] = make_uint4(lw[0], lw[1], lw[2], lw[3]);
  }
}

__global__ __launch_bounds__(256) void k_cvtW(const float* __restrict__ W,
    u16* __restrict__ Wh, u16* __restrict__ Wl, int nsrc, int K, int total4)
{
  int i = blockIdx.x * 256 + threadIdx.x;
  if (i >= total4) return;
  int e = i * 4;
  int row = e / K;
  float4 v = make_float4(0.f, 0.f, 0.f, 0.f);
  if (row < nsrc) v = *(const float4*)&W[e];
  u16 h[4], l[4];
  bsplit(v.x, h[0], l[0]); bsplit(v.y, h[1], l[1]);
  bsplit(v.z, h[2], l[2]); bsplit(v.w, h[3], l[3]);
  *(uint2*)&Wh[e] = make_uint2((u32)h[0] | ((u32)h[1] << 16), (u32)h[2] | ((u32)h[3] << 16));
  *(uint2*)&Wl[e] = make_uint2((u32)l[0] | ((u32)l[1] << 16), (u32)l[2] | ((u32)l[3] << 16));
}

// ---------------- bf16x3 MFMA GEMM: in_proj ----------------
__global__ __launch_bounds__(256) void k_gemm1(
    const u16* __restrict__ Ah, const u16* __restrict__ Al,
    const u16* __restrict__ Bh, const u16* __restrict__ Bl,
    const float* __restrict__ dt_bias,
    float* __restrict__ z, float* __restrict__ xBC, float* __restrict__ dt)
{
  __shared__ u16 lds[16384];
  const int t = threadIdx.x;
  const int lane = t & 63, wid = t >> 6;
  const int wr = wid >> 1, wc = wid & 1;
  const int gg = lane >> 4, mlo = lane & 15;
  const int m0 = blockIdx.x * 128, n0 = blockIdx.y * 128;
  f32x4 acc[4][4];
#pragma unroll
  for (int i = 0; i < 4; ++i)
#pragma unroll
    for (int j = 0; j < 4; ++j) acc[i][j] = (f32x4){0.f, 0.f, 0.f, 0.f};
  const u16* g0 = Ah + (size_t)m0 * DM;
  const u16* g1 = Al + (size_t)m0 * DM;
  const u16* g2 = Bh + (size_t)n0 * DM;
  const u16* g3 = Bl + (size_t)n0 * DM;
  const char* ldsb = (const char*)lds;
  for (int k0 = 0; k0 < DM; k0 += 32) {
#pragma unroll
    for (int i = 0; i < 2; ++i) {
      int S = i * 256 + t;
      int m = S >> 2;
      int g = (S ^ (m >> 1)) & 3;
      size_t goff = (size_t)m * DM + k0 + g * 8;
      __builtin_amdgcn_global_load_lds((const __attribute__((address_space(1))) u32*)(g0 + goff),
          (__attribute__((address_space(3))) u32*)(lds + S * 8), 16, 0, 0);
      __builtin_amdgcn_global_load_lds((const __attribute__((address_space(1))) u32*)(g1 + goff),
          (__attribute__((address_space(3))) u32*)(lds + 4096 + S * 8), 16, 0, 0);
      __builtin_amdgcn_global_load_lds((const __attribute__((address_space(1))) u32*)(g2 + goff),
          (__attribute__((address_space(3))) u32*)(lds + 8192 + S * 8), 16, 0, 0);
      __builtin_amdgcn_global_load_lds((const __attribute__((address_space(1))) u32*)(g3 + goff),
          (__attribute__((address_space(3))) u32*)(lds + 12288 + S * 8), 16, 0, 0);
    }
    __syncthreads();
    bf16x8 fa[4], fal[4], fb[4], fbl[4];
#pragma unroll
    for (int mf = 0; mf < 4; ++mf) {
      int m = wr * 64 + mf * 16 + mlo;
      int off = m * 64 + (((gg ^ (m >> 1)) & 3) << 4);
      fa[mf]  = *(const bf16x8*)(ldsb + off);
      fal[mf] = *(const bf16x8*)(ldsb + 8192 + off);
    }
#pragma unroll
    for (int nf = 0; nf < 4; ++nf) {
      int n = wc * 64 + nf * 16 + mlo;
      int off = n * 64 + (((gg ^ (n >> 1)) & 3) << 4);
      fb[nf]  = *(const bf16x8*)(ldsb + 16384 + off);
      fbl[nf] = *(const bf16x8*)(ldsb + 24576 + off);
    }
#pragma unroll
    for (int mf = 0; mf < 4; ++mf)
#pragma unroll
      for (int nf = 0; nf < 4; ++nf) {
        acc[mf][nf] = __builtin_amdgcn_mfma_f32_16x16x32_bf16(fa[mf],  fb[nf],  acc[mf][nf], 0, 0, 0);
        acc[mf][nf] = __builtin_amdgcn_mfma_f32_16x16x32_bf16(fa[mf],  fbl[nf], acc[mf][nf], 0, 0, 0);
        acc[mf][nf] = __builtin_amdgcn_mfma_f32_16x16x32_bf16(fal[mf], fb[nf],  acc[mf][nf], 0, 0, 0);
      }
    __syncthreads();
  }
  const int rb = m0 + wr * 64 + (lane >> 4) * 4;
  const int cb = n0 + wc * 64 + mlo;
#pragma unroll
  for (int mf = 0; mf < 4; ++mf)
#pragma unroll
    for (int nf = 0; nf < 4; ++nf) {
      int col = cb + nf * 16;
#pragma unroll
      for (int r = 0; r < 4; ++r) {
        int row = rb + mf * 16 + r;
        float v = acc[mf][nf][r];
        if (col < DI) z[(size_t)row * DI + col] = v;
        else if (col < DI + CONVD) xBC[(size_t)row * CONVD + (col - DI)] = v;
        else if (col < DIP) {
          int hh = col - (DI + CONVD);
          float xv = v + dt_bias[hh];
          dt[(size_t)row * NH + hh] = (xv > 20.f) ? xv : log1pf(expf(xv));
        }
      }
    }
}

// ---------------- bf16x3 MFMA GEMM: out_proj ----------------
__global__ __launch_bounds__(256) void k_gemm2(
    const u16* __restrict__ Ah, const u16* __restrict__ Al,
    const u16* __restrict__ Bh, const u16* __restrict__ Bl,
    float* __restrict__ out)
{
  __shared__ u16 lds[16384];
  const int t = threadIdx.x;
  const int lane = t & 63, wid = t >> 6;
  const int wr = wid >> 1, wc = wid & 1;
  const int gg = lane >> 4, mlo = lane & 15;
  const int m0 = blockIdx.x * 128, n0 = blockIdx.y * 128;
  f32x4 acc[4][4];
#pragma unroll
  for (int i = 0; i < 4; ++i)
#pragma unroll
    for (int j = 0; j < 4; ++j) acc[i][j] = (f32x4){0.f, 0.f, 0.f, 0.f};
  const u16* g0 = Ah + (size_t)m0 * DI;
  const u16* g1 = Al + (size_t)m0 * DI;
  const u16* g2 = Bh + (size_t)n0 * DI;
  const u16* g3 = Bl + (size_t)n0 * DI;
  const char* ldsb = (const char*)lds;
  for (int k0 = 0; k0 < DI; k0 += 32) {
#pragma unroll
    for (int i = 0; i < 2; ++i) {
      int S = i * 256 + t;
      int m = S >> 2;
      int g = (S ^ (m >> 1)) & 3;
      size_t goff = (size_t)m * DI + k0 + g * 8;
      __builtin_amdgcn_global_load_lds((const __attribute__((address_space(1))) u32*)(g0 + goff),
          (__attribute__((address_space(3))) u32*)(lds + S * 8), 16, 0, 0);
      __builtin_amdgcn_global_load_lds((const __attribute__((address_space(1))) u32*)(g1 + goff),
          (__attribute__((address_space(3))) u32*)(lds + 4096 + S * 8), 16, 0, 0);
      __builtin_amdgcn_global_load_lds((const __attribute__((address_space(1))) u32*)(g2 + goff),
          (__attribute__((address_space(3))) u32*)(lds + 8192 + S * 8), 16, 0, 0);
      __builtin_amdgcn_global_load_lds((const __attribute__((address_space(1))) u32*)(g3 + goff),
          (__attribute__((address_space(3))) u32*)(lds + 12288 + S * 8), 16, 0, 0);
    }
    __syncthreads();
    bf16x8 fa[4], fal[4], fb[4], fbl[4];
#pragma unroll
    for (int mf = 0; mf < 4; ++mf) {
      int m = wr * 64 + mf * 16 + mlo;
      int off = m * 64 + (((gg ^ (m >> 1)) & 3) << 4);
      fa[mf]  = *(const bf16x8*)(ldsb + off);
      fal[mf] = *(const bf16x8*)(ldsb + 8192 + off);
    }
#pragma unroll
    for (int nf = 0; nf < 4; ++nf) {
      int n = wc * 64 + nf * 16 + mlo;
      int off = n * 64 + (((gg ^ (n >> 1)) & 3) << 4);
      fb[nf]  = *(const bf16x8*)(ldsb + 16384 + off);
      fbl[nf] = *(const bf16x8*)(ldsb + 24576 + off);
    }
#pragma unroll
    for (int mf = 0; mf < 4; ++mf)
#pragma unroll
      for (int nf = 0; nf < 4; ++nf) {
        acc[mf][nf] = __builtin_amdgcn_mfma_f32_16x16x32_bf16(fa[mf],  fb[nf],  acc[mf][nf], 0, 0, 0);
        acc[mf][nf] = __builtin_amdgcn_mfma_f32_16x16x32_bf16(fa[mf],  fbl[nf], acc[mf][nf], 0, 0, 0);
        acc[mf][nf] = __builtin_amdgcn_mfma_f32_16x16x32_bf16(fal[mf], fb[nf],  acc[mf][nf], 0, 0, 0);
      }
    __syncthreads();
  }
  const int rb = m0 + wr * 64 + (lane >> 4) * 4;
  const int cb = n0 + wc * 64 + mlo;
#pragma unroll
  for (int mf = 0; mf < 4; ++mf)
#pragma unroll
    for (int nf = 0; nf < 4; ++nf) {
      int col = cb + nf * 16;
#pragma unroll
      for (int r = 0; r < 4; ++r) {
        int row = rb + mf * 16 + r;
        int b = row >> 10, l = row & 1023;
        out[((size_t)(b * DM + col)) * L_ + l] = acc[mf][nf][r];
      }
    }
}

// ---------------- K2: LDS-tiled depthwise 3x3 conv + bias + SiLU + split ----------------
// block = (c-chunk of 16, h-half of 16 rows, b). Stage 18x32x16 with h-halo in LDS.
#define CC 16
__global__ __launch_bounds__(256) void k_conv(
    const float* __restrict__ xBC, const float* __restrict__ cw,
    const float* __restrict__ cb,
    float* __restrict__ x, float* __restrict__ Bm, float* __restrict__ Cm)
{
  __shared__ float Ls[18][32][CC];   // 36.9 KB
  const int t  = threadIdx.x;
  const int c0 = blockIdx.x * CC;
  const int h0 = blockIdx.y * 16;
  const int b  = blockIdx.z;
  // stage 18 rows (h0-1 .. h0+16) x 32 w x 16 c
#pragma unroll
  for (int k = 0; k < 9; ++k) {
    int f = k * 256 + t;               // 0..2303
    int fc4 = f & 3, fw = (f >> 2) & 31, fr = f >> 7;   // fr: 0..17
    int h = h0 + fr - 1;
    float4 v = make_float4(0.f, 0.f, 0.f, 0.f);
    if (h >= 0 && h < 32)
      v = *(const float4*)&xBC[((size_t)(b * 1024 + h * 32 + fw)) * CONVD + c0 + fc4 * 4];
    *(float4*)&Ls[fr][fw][fc4 * 4] = v;
  }
  // per-thread weights (4 channels x 9 taps) + bias in regs
  const int c4 = t & 3;
  const int w  = (t >> 2) & 31;
  const int hb = t >> 7;               // 0..1
  float wt[4][9];
  float bias[4];
#pragma unroll
  for (int j = 0; j < 4; ++j) {
    int c = c0 + c4 * 4 + j;
    bias[j] = cb[c];
#pragma unroll
    for (int kb = 0; kb < 9; ++kb) wt[j][kb] = cw[c * 9 + kb];
  }
  __syncthreads();
#pragma unroll
  for (int k = 0; k < 8; ++k) {
    int h = hb * 8 + k;                // local row 0..15
    float acc[4] = {bias[0], bias[1], bias[2], bias[3]};
#pragma unroll
    for (int dh = 0; dh < 3; ++dh) {
#pragma unroll
      for (int dw = -1; dw <= 1; ++dw) {
        int ww = w + dw;
        if (ww < 0 || ww > 31) continue;
        const float* p = &Ls[h + dh][ww][c4 * 4];
        int kb = dh * 3 + (dw + 1);
#pragma unroll
        for (int j = 0; j < 4; ++j) acc[j] = fmaf(p[j], wt[j][kb], acc[j]);
      }
    }
    float4 o;
    float* po = (float*)&o;
#pragma unroll
    for (int j = 0; j < 4; ++j) { float v = acc[j]; po[j] = v / (1.f + expf(-v)); }
    size_t row = (size_t)b * 1024 + (h0 + h) * 32 + w;
    int c = c0 + c4 * 4;
    if (c < DI)           *(float4*)&x[row * DI + c] = o;
    else if (c < DI + DS) *(float4*)&Bm[row * DS + (c - DI)] = o;
    else                  *(float4*)&Cm[row * DS + (c - DI - DS)] = o;
  }
}

// ---------------- K3: dt*A cumsum per chunk ----------------
__global__ __launch_bounds__(256) void k_dtcum(
    const float* __restrict__ dt, const float* __restrict__ A_log,
    float* __restrict__ dAcs, float* __restrict__ cdecay)
{
  __shared__ float s[256];
  const int bc = blockIdx.x;
  const int i  = threadIdx.x;
  const size_t row = (size_t)bc * 256 + i;
  for (int h = 0; h < NH; ++h) {
    float A = -expf(A_log[h]);
    float v = dt[row * NH + h] * A;
    s[i] = v;
    __syncthreads();
#pragma unroll
    for (int off = 1; off < 256; off <<= 1) {
      float add = (i >= off) ? s[i - off] : 0.f;
      __syncthreads();
      s[i] += add;
      __syncthreads();
    }
    float cs = s[i];
    dAcs[row * NH + h] = cs;
    if (i == 255) cdecay[bc * NH + h] = expf(cs);
    __syncthreads();
  }
}

// ---------------- K4: G[i,j] = C_i . B_j per chunk ----------------
__global__ __launch_bounds__(256) void k_G(
    const float* __restrict__ Bm, const float* __restrict__ Cm,
    float* __restrict__ G)
{
  __shared__ float Cs[64 * 65];
  __shared__ float Bs[64 * 65];
  const int bc = blockIdx.x;
  const int it = blockIdx.y;
  const int t  = threadIdx.x;
  const int tx = t & 15, ty = t >> 4;
  const int i0 = it * 64;
  const size_t base = (size_t)bc * 256;
#pragma unroll
  for (int r = 0; r < 4; ++r) {
    int idx = r * 256 + t;
    int a = idx >> 4, q = (idx & 15) * 4;
    float4 v = *(const float4*)&Cm[(base + i0 + a) * DS + q];
    Cs[(q + 0) * 65 + a] = v.x; Cs[(q + 1) * 65 + a] = v.y;
    Cs[(q + 2) * 65 + a] = v.z; Cs[(q + 3) * 65 + a] = v.w;
  }
  for (int jt = 0; jt < 4; ++jt) {
    __syncthreads();
    int j0 = jt * 64;
#pragma unroll
    for (int r = 0; r < 4; ++r) {
      int idx = r * 256 + t;
      int a = idx >> 4, q = (idx & 15) * 4;
      float4 v = *(const float4*)&Bm[(base + j0 + a) * DS + q];
      Bs[(q + 0) * 65 + a] = v.x; Bs[(q + 1) * 65 + a] = v.y;
      Bs[(q + 2) * 65 + a] = v.z; Bs[(q + 3) * 65 + a] = v.w;
    }
    __syncthreads();
    float acc[4][4] = {};
    for (int n = 0; n < 64; ++n) {
      float a[4], bb[4];
#pragma unroll
      for (int i = 0; i < 4; ++i) a[i] = Cs[n * 65 + ty * 4 + i];
#pragma unroll
      for (int j = 0; j < 4; ++j) bb[j] = Bs[n * 65 + tx * 4 + j];
#pragma unroll
      for (int i = 0; i < 4; ++i)
#pragma unroll
        for (int j = 0; j < 4; ++j)
          acc[i][j] = fmaf(a[i], bb[j], acc[i][j]);
    }
#pragma unroll
    for (int i = 0; i < 4; ++i) {
      float4 o = make_float4(acc[i][0], acc[i][1], acc[i][2], acc[i][3]);
      *(float4*)&G[((size_t)bc << 16) + (size_t)(i0 + ty * 4 + i) * 256 + j0 + tx * 4] = o;
    }
  }
}

// ---------------- K5: chunk states ----------------
__global__ __launch_bounds__(256) void k_states(
    const float* __restrict__ x, const float* __restrict__ Bm,
    const float* __restrict__ dt, const float* __restrict__ dAcs,
    float* __restrict__ states)
{
  __shared__ float xs[64 * 65];
  __shared__ float Bs[64 * 65];
  __shared__ float wj[64];
  const int bc = blockIdx.x;
  const int hh = blockIdx.y;
  const int t  = threadIdx.x;
  const int tx = t & 15, ty = t >> 4;
  const size_t base = (size_t)bc * 256;
  const float last = dAcs[(base + 255) * NH + hh];
  float acc[4][4] = {};
  for (int j0 = 0; j0 < 256; j0 += 64) {
#pragma unroll
    for (int r = 0; r < 4; ++r) {
      int idx = r * 256 + t;
      int j = idx >> 4, pq = (idx & 15) * 4;
      float4 v = *(const float4*)&x[(base + j0 + j) * DI + hh * HD + pq];
      xs[j * 65 + pq + 0] = v.x; xs[j * 65 + pq + 1] = v.y;
      xs[j * 65 + pq + 2] = v.z; xs[j * 65 + pq + 3] = v.w;
      float4 u2 = *(const float4*)&Bm[(base + j0 + j) * DS + pq];
      Bs[j * 65 + pq + 0] = u2.x; Bs[j * 65 + pq + 1] = u2.y;
      Bs[j * 65 + pq + 2] = u2.z; Bs[j * 65 + pq + 3] = u2.w;
    }
    if (t < 64) {
      size_t r2 = base + j0 + t;
      wj[t] = expf(last - dAcs[r2 * NH + hh]) * dt[r2 * NH + hh];
    }
    __syncthreads();
    for (int j = 0; j < 64; ++j) {
      float w = wj[j];
      float xv[4], bv[4];
#pragma unroll
      for (int i = 0; i < 4; ++i) xv[i] = xs[j * 65 + ty * 4 + i] * w;
#pragma unroll
      for (int jj = 0; jj < 4; ++jj) bv[jj] = Bs[j * 65 + tx * 4 + jj];
#pragma unroll
      for (int i = 0; i < 4; ++i)
#pragma unroll
        for (int jj = 0; jj < 4; ++jj)
          acc[i][jj] = fmaf(xv[i], bv[jj], acc[i][jj]);
    }
    __syncthreads();
  }
  const size_t sb = ((size_t)(bc * NH + hh)) << 12;
#pragma unroll
  for (int i = 0; i < 4; ++i) {
    float4 o = make_float4(acc[i][0], acc[i][1], acc[i][2], acc[i][3]);
    *(float4*)&states[sb + (size_t)(ty * 4 + i) * 64 + tx * 4] = o;
  }
}

// ---------------- K6: inter-chunk scan ----------------
__global__ __launch_bounds__(256) void k_scanc(
    const float* __restrict__ states, const float* __restrict__ cdecay,
    float* __restrict__ prev)
{
  int tid = blockIdx.x * 256 + threadIdx.x;
  int pn  = tid & 4095;
  int rem = tid >> 12;
  int hh  = rem % NH;
  int b   = rem / NH;
  float carry = 0.f;
#pragma unroll
  for (int c = 0; c < 4; ++c) {
    size_t idx = ((size_t)((b * 4 + c) * NH + hh) << 12) + pn;
    prev[idx] = carry;
    carry = carry * cdecay[(b * 4 + c) * NH + hh] + states[idx];
  }
}

// ---------------- K7: y = intra + inter + D*x ----------------
__global__ __launch_bounds__(256) void k_y(
    const float* __restrict__ x, const float* __restrict__ Cm,
    const float* __restrict__ dtp, const float* __restrict__ dAcs,
    const float* __restrict__ G, const float* __restrict__ prev,
    const float* __restrict__ Dp, float* __restrict__ y)
{
  __shared__ float l1[64 * 65];
  __shared__ float l2[64 * 65];
  __shared__ float dAi[64], dAj[64], dtj[64];
  const int bc = blockIdx.x;
  const int hh = blockIdx.y;
  const int it = blockIdx.z;
  const int t  = threadIdx.x;
  const int tx = t & 15, ty = t >> 4;
  const int i0 = it * 64;
  const size_t base = (size_t)bc * 256;
  if (t < 64) dAi[t] = dAcs[(base + i0 + t) * NH + hh];
#pragma unroll
  for (int r = 0; r < 4; ++r) {
    int idx = r * 256 + t;
    int a = idx >> 4, q = (idx & 15) * 4;
    float4 v = *(const float4*)&Cm[(base + i0 + a) * DS + q];
    l1[(q + 0) * 65 + a] = v.x; l1[(q + 1) * 65 + a] = v.y;
    l1[(q + 2) * 65 + a] = v.z; l1[(q + 3) * 65 + a] = v.w;
    float4 u2 = *(const float4*)&prev[((size_t)(bc * NH + hh) << 12) + (size_t)a * 64 + q];
    l2[(q + 0) * 65 + a] = u2.x; l2[(q + 1) * 65 + a] = u2.y;
    l2[(q + 2) * 65 + a] = u2.z; l2[(q + 3) * 65 + a] = u2.w;
  }
  __syncthreads();
  float acc[4][4] = {};
  for (int n = 0; n < 64; ++n) {
    float a[4], bb[4];
#pragma unroll
    for (int i = 0; i < 4; ++i) a[i] = l1[n * 65 + ty * 4 + i];
#pragma unroll
    for (int p = 0; p < 4; ++p) bb[p] = l2[n * 65 + tx * 4 + p];
#pragma unroll
    for (int i = 0; i < 4; ++i)
#pragma unroll
      for (int p = 0; p < 4; ++p)
        acc[i][p] = fmaf(a[i], bb[p], acc[i][p]);
  }
  __syncthreads();
#pragma unroll
  for (int i = 0; i < 4; ++i) {
    float e = expf(dAi[ty * 4 + i]);
#pragma unroll
    for (int p = 0; p < 4; ++p) acc[i][p] *= e;
  }
  for (int jt = 0; jt <= it; ++jt) {
    int j0 = jt * 64;
    if (t < 64) {
      size_t r2 = base + j0 + t;
      dAj[t] = dAcs[r2 * NH + hh];
      dtj[t] = dtp[r2 * NH + hh];
    }
#pragma unroll
    for (int r = 0; r < 4; ++r) {
      int idx = r * 256 + t;
      int j = idx >> 4, pq = (idx & 15) * 4;
      float4 v = *(const float4*)&x[(base + j0 + j) * DI + hh * HD + pq];
      l2[j * 65 + pq + 0] = v.x; l2[j * 65 + pq + 1] = v.y;
      l2[j * 65 + pq + 2] = v.z; l2[j * 65 + pq + 3] = v.w;
    }
    __syncthreads();
#pragma unroll
    for (int r = 0; r < 16; ++r) {
      int idx = r * 256 + t;
      int i = idx >> 6, j = idx & 63;
      float av = 0.f;
      if (jt < it || j <= i) {
        float g = G[((size_t)bc << 16) + (size_t)(i0 + i) * 256 + j0 + j];
        av = g * expf(dAi[i] - dAj[j]) * dtj[j];
      }
      l1[j * 65 + i] = av;
    }
    __syncthreads();
    for (int j = 0; j < 64; ++j) {
      float a[4], xv[4];
#pragma unroll
      for (int i = 0; i < 4; ++i) a[i] = l1[j * 65 + ty * 4 + i];
#pragma unroll
      for (int p = 0; p < 4; ++p) xv[p] = l2[j * 65 + tx * 4 + p];
#pragma unroll
      for (int i = 0; i < 4; ++i)
#pragma unroll
        for (int p = 0; p < 4; ++p)
          acc[i][p] = fmaf(a[i], xv[p], acc[i][p]);
    }
    __syncthreads();
  }
  const float Dh = Dp[hh];
#pragma unroll
  for (int i = 0; i < 4; ++i) {
    size_t row = base + i0 + ty * 4 + i;
    const float4 xv = *(const float4*)&x[row * DI + hh * HD + tx * 4];
    float4 o;
    o.x = acc[i][0] + Dh * xv.x;
    o.y = acc[i][1] + Dh * xv.y;
    o.z = acc[i][2] + Dh * xv.z;
    o.w = acc[i][3] + Dh * xv.w;
    *(float4*)&y[row * DI + hh * HD + tx * 4] = o;
  }
}

// ---------------- K8: LayerNorm * z -> bf16 hi/lo pair ----------------
__global__ __launch_bounds__(256) void k_norm(
    const float* __restrict__ z, const float* __restrict__ nw,
    const float* __restrict__ nb, const float* __restrict__ y,
    u16* __restrict__ yh, u16* __restrict__ yl)
{
  __shared__ float rs[4], rq[4];
  const size_t row = blockIdx.x;
  const int t = threadIdx.x;
  float v[3];
  float s = 0.f, sq = 0.f;
#pragma unroll
  for (int r = 0; r < 3; ++r) {
    v[r] = y[row * DI + r * 256 + t];
    s += v[r];
    sq = fmaf(v[r], v[r], sq);
  }
#pragma unroll
  for (int off = 32; off > 0; off >>= 1) {
    s  += __shfl_down(s, off, 64);
    sq += __shfl_down(sq, off, 64);
  }
  const int wid = t >> 6, lane = t & 63;
  if (lane == 0) { rs[wid] = s; rq[wid] = sq; }
  __syncthreads();
  if (t == 0) {
    rs[0] = rs[0] + rs[1] + rs[2] + rs[3];
    rq[0] = rq[0] + rq[1] + rq[2] + rq[3];
  }
  __syncthreads();
  const float mu   = rs[0] * (1.f / DI);
  const float var  = rq[0] * (1.f / DI) - mu * mu;
  const float rstd = 1.f / sqrtf(var + EPS_);
#pragma unroll
  for (int r = 0; r < 3; ++r) {
    int d = r * 256 + t;
    float o = (v[r] - mu) * rstd * nw[d] + nb[d];
    float p = o * z[row * DI + d];
    u16 h, l;
    bsplit(p, h, l);
    yh[row * DI + d] = h;
    yl[row * DI + d] = l;
  }
}

extern "C" void kernel_launch(void* const* d_in, const int* in_sizes, int n_in,
                              void* d_out, int out_size, void* d_ws, size_t ws_size,
                              hipStream_t stream)
{
  const float* u    = (const float*)d_in[0];
  const float* ipw  = (const float*)d_in[1];
  const float* cw   = (const float*)d_in[2];
  const float* cb   = (const float*)d_in[3];
  const float* dtb  = (const float*)d_in[4];
  const float* Alog = (const float*)d_in[5];
  const float* Dp   = (const float*)d_in[6];
  const float* nw   = (const float*)d_in[7];
  const float* nb   = (const float*)d_in[8];
  const float* opw  = (const float*)d_in[9];
  float* out = (float*)d_out;

  float* ws = (float*)d_ws;
  size_t off = 0;
  float* z_buf   = ws + off; off += (size_t)B_ * L_ * DI;
  float* xBC_buf = ws + off; off += (size_t)B_ * L_ * CONVD;
  float* y_buf   = xBC_buf;                       // alias: xBC dead after conv
  float* dt_buf  = ws + off; off += (size_t)B_ * L_ * NH;
  float* x_buf   = ws + off; off += (size_t)B_ * L_ * DI;
  float* Bm_buf  = ws + off; off += (size_t)B_ * L_ * DS;
  float* Cm_buf  = ws + off; off += (size_t)B_ * L_ * DS;
  float* dAcs    = ws + off; off += (size_t)B_ * L_ * NH;
  float* cdec    = ws + off; off += (size_t)B_ * NCH * NH;
  float* G_buf   = ws + off; off += (size_t)B_ * NCH * CH * CH;
  float* st_buf  = ws + off; off += (size_t)B_ * NCH * NH * HD * DS;
  float* pv_buf  = ws + off; off += (size_t)B_ * NCH * NH * HD * DS;
  u16*   Woh     = (u16*)(ws + off); off += (size_t)DM * DI / 2;
  u16*   Wol     = (u16*)(ws + off); off += (size_t)DM * DI / 2;

  u16* Ah = (u16*)x_buf;
  u16* Al = Ah + (size_t)B_ * L_ * DM;
  u16* Wh = Al + (size_t)B_ * L_ * DM;
  u16* Wl = Wh + (size_t)NP1 * DM;
  u16* yh = (u16*)x_buf;
  u16* yl = yh + (size_t)B_ * L_ * DI;

  hipLaunchKernelGGL(k_cvtA, dim3(8, 12, 16), dim3(256), 0, stream, u, Ah, Al);
  hipLaunchKernelGGL(k_cvtW, dim3((NP1 * DM / 4 + 255) / 256), dim3(256), 0, stream,
                     ipw, Wh, Wl, DIP, DM, NP1 * DM / 4);
  hipLaunchKernelGGL(k_cvtW, dim3((DM * DI / 4 + 255) / 256), dim3(256), 0, stream,
                     opw, Woh, Wol, DM, DI, DM * DI / 4);
  hipLaunchKernelGGL(k_gemm1, dim3(128, 14), dim3(256), 0, stream,
                     Ah, Al, Wh, Wl, dtb, z_buf, xBC_buf, dt_buf);
  hipLaunchKernelGGL(k_conv,   dim3(56, 2, 16), dim3(256), 0, stream, xBC_buf, cw, cb, x_buf, Bm_buf, Cm_buf);
  hipLaunchKernelGGL(k_dtcum,  dim3(64),    dim3(256), 0, stream, dt_buf, Alog, dAcs, cdec);
  hipLaunchKernelGGL(k_G,      dim3(64, 4), dim3(256), 0, stream, Bm_buf, Cm_buf, G_buf);
  hipLaunchKernelGGL(k_states, dim3(64, 12), dim3(256), 0, stream, x_buf, Bm_buf, dt_buf, dAcs, st_buf);
  hipLaunchKernelGGL(k_scanc,  dim3(3072),  dim3(256), 0, stream, st_buf, cdec, pv_buf);
  hipLaunchKernelGGL(k_y,      dim3(64, 12, 4), dim3(256), 0, stream,
                     x_buf, Cm_buf, dt_buf, dAcs, G_buf, pv_buf, Dp, y_buf);
  hipLaunchKernelGGL(k_norm,   dim3(16384), dim3(256), 0, stream, z_buf, nw, nb, y_buf, yh, yl);
  hipLaunchKernelGGL(k_gemm2,  dim3(128, 3), dim3(256), 0, stream, yh, yl, Woh, Wol, out);
}

// Round 4
// 331.823 us; speedup vs baseline: 3.0507x; 1.2866x over previous
//
#include <hip/hip_runtime.h>
#include <hip/hip_bf16.h>

#define B_    16
#define L_    1024
#define DM    384
#define DIP   1676
#define NP1   1792
#define DI    768
#define CONVD 896
#define NH    12
#define HD    64
#define DS    64
#define NCH   4
#define CH    256
#define EPS_  1e-5f

typedef unsigned short u16;
typedef unsigned int   u32;
typedef __attribute__((ext_vector_type(8))) short bf16x8;
typedef __attribute__((ext_vector_type(4))) float f32x4;

union U4 { uint4 v; u16 s[8]; };

// byte offset of 16B slot `slot` in row `row` of a [64][64]-bf16 LDS tile (128B rows, XOR swizzle)
#define SWZ(row, slot) (((row) << 7) + ((((slot) ^ ((row) & 7)) & 7) << 4))

// bf16 round-to-nearest-even split helpers
__device__ __forceinline__ u16 f2b(float v) {
  u32 u = __float_as_uint(v);
  u32 r = (u + 0x7FFFu + ((u >> 16) & 1u)) >> 16;
  return (u16)r;
}
__device__ __forceinline__ float b2f(u16 h) { return __uint_as_float(((u32)h) << 16); }
__device__ __forceinline__ void bsplit(float v, u16& h, u16& l) {
  u16 hh = f2b(v);
  l = f2b(v - b2f(hh));
  h = hh;
}

// ---------------- converters ----------------
__global__ __launch_bounds__(256) void k_cvtA(const float* __restrict__ u,
                                              u16* __restrict__ Ah, u16* __restrict__ Al)
{
  __shared__ float Ls[32][129];
  const int t  = threadIdx.x;
  const int l0 = blockIdx.x * 128;
  const int k0 = blockIdx.y * 32;
  const int b  = blockIdx.z;
#pragma unroll
  for (int r = 0; r < 4; ++r) {
    int idx = r * 256 + t;
    int kk = idx >> 5, q = idx & 31;
    float4 v = *(const float4*)&u[((size_t)(b * DM + k0 + kk)) * L_ + l0 + q * 4];
    Ls[kk][q * 4 + 0] = v.x; Ls[kk][q * 4 + 1] = v.y;
    Ls[kk][q * 4 + 2] = v.z; Ls[kk][q * 4 + 3] = v.w;
  }
  __syncthreads();
#pragma unroll
  for (int it = 0; it < 2; ++it) {
    int task = it * 256 + t;
    int l = task >> 2, kq = (task & 3) * 8;
    u32 hw[4], lw[4];
#pragma unroll
    for (int j = 0; j < 4; ++j) {
      u16 h0, l0v, h1, l1v;
      bsplit(Ls[kq + 2 * j + 0][l], h0, l0v);
      bsplit(Ls[kq + 2 * j + 1][l], h1, l1v);
      hw[j] = (u32)h0 | ((u32)h1 << 16);
      lw[j] = (u32)l0v | ((u32)l1v << 16);
    }
    size_t off = ((size_t)(b * L_ + l0 + l)) * DM + k0 + kq;
    *(uint4*)&Ah[off] = make_uint4(hw[0], hw[1], hw[2], hw[3]);
    *(uint4*)&Al[off] = make_uint4(lw[0], lw[1], lw[2], lw[3]);
  }
}

__global__ __launch_bounds__(256) void k_cvtW(const float* __restrict__ W,
    u16* __restrict__ Wh, u16* __restrict__ Wl, int nsrc, int K, int total4)
{
  int i = blockIdx.x * 256 + threadIdx.x;
  if (i >= total4) return;
  int e = i * 4;
  int row = e / K;
  float4 v = make_float4(0.f, 0.f, 0.f, 0.f);
  if (row < nsrc) v = *(const float4*)&W[e];
  u16 h[4], l[4];
  bsplit(v.x, h[0], l[0]); bsplit(v.y, h[1], l[1]);
  bsplit(v.z, h[2], l[2]); bsplit(v.w, h[3], l[3]);
  *(uint2*)&Wh[e] = make_uint2((u32)h[0] | ((u32)h[1] << 16), (u32)h[2] | ((u32)h[3] << 16));
  *(uint2*)&Wl[e] = make_uint2((u32)l[0] | ((u32)l[1] << 16), (u32)l[2] | ((u32)l[3] << 16));
}

// ---------------- bf16x3 MFMA GEMM: in_proj ----------------
__global__ __launch_bounds__(256) void k_gemm1(
    const u16* __restrict__ Ah, const u16* __restrict__ Al,
    const u16* __restrict__ Bh, const u16* __restrict__ Bl,
    const float* __restrict__ dt_bias,
    float* __restrict__ z, float* __restrict__ xBC, float* __restrict__ dt)
{
  __shared__ u16 lds[16384];
  const int t = threadIdx.x;
  const int lane = t & 63, wid = t >> 6;
  const int wr = wid >> 1, wc = wid & 1;
  const int gg = lane >> 4, mlo = lane & 15;
  const int m0 = blockIdx.x * 128, n0 = blockIdx.y * 128;
  f32x4 acc[4][4];
#pragma unroll
  for (int i = 0; i < 4; ++i)
#pragma unroll
    for (int j = 0; j < 4; ++j) acc[i][j] = (f32x4){0.f, 0.f, 0.f, 0.f};
  const u16* g0 = Ah + (size_t)m0 * DM;
  const u16* g1 = Al + (size_t)m0 * DM;
  const u16* g2 = Bh + (size_t)n0 * DM;
  const u16* g3 = Bl + (size_t)n0 * DM;
  const char* ldsb = (const char*)lds;
  for (int k0 = 0; k0 < DM; k0 += 32) {
#pragma unroll
    for (int i = 0; i < 2; ++i) {
      int S = i * 256 + t;
      int m = S >> 2;
      int g = (S ^ (m >> 1)) & 3;
      size_t goff = (size_t)m * DM + k0 + g * 8;
      __builtin_amdgcn_global_load_lds((const __attribute__((address_space(1))) u32*)(g0 + goff),
          (__attribute__((address_space(3))) u32*)(lds + S * 8), 16, 0, 0);
      __builtin_amdgcn_global_load_lds((const __attribute__((address_space(1))) u32*)(g1 + goff),
          (__attribute__((address_space(3))) u32*)(lds + 4096 + S * 8), 16, 0, 0);
      __builtin_amdgcn_global_load_lds((const __attribute__((address_space(1))) u32*)(g2 + goff),
          (__attribute__((address_space(3))) u32*)(lds + 8192 + S * 8), 16, 0, 0);
      __builtin_amdgcn_global_load_lds((const __attribute__((address_space(1))) u32*)(g3 + goff),
          (__attribute__((address_space(3))) u32*)(lds + 12288 + S * 8), 16, 0, 0);
    }
    __syncthreads();
    bf16x8 fa[4], fal[4], fb[4], fbl[4];
#pragma unroll
    for (int mf = 0; mf < 4; ++mf) {
      int m = wr * 64 + mf * 16 + mlo;
      int off = m * 64 + (((gg ^ (m >> 1)) & 3) << 4);
      fa[mf]  = *(const bf16x8*)(ldsb + off);
      fal[mf] = *(const bf16x8*)(ldsb + 8192 + off);
    }
#pragma unroll
    for (int nf = 0; nf < 4; ++nf) {
      int n = wc * 64 + nf * 16 + mlo;
      int off = n * 64 + (((gg ^ (n >> 1)) & 3) << 4);
      fb[nf]  = *(const bf16x8*)(ldsb + 16384 + off);
      fbl[nf] = *(const bf16x8*)(ldsb + 24576 + off);
    }
#pragma unroll
    for (int mf = 0; mf < 4; ++mf)
#pragma unroll
      for (int nf = 0; nf < 4; ++nf) {
        acc[mf][nf] = __builtin_amdgcn_mfma_f32_16x16x32_bf16(fa[mf],  fb[nf],  acc[mf][nf], 0, 0, 0);
        acc[mf][nf] = __builtin_amdgcn_mfma_f32_16x16x32_bf16(fa[mf],  fbl[nf], acc[mf][nf], 0, 0, 0);
        acc[mf][nf] = __builtin_amdgcn_mfma_f32_16x16x32_bf16(fal[mf], fb[nf],  acc[mf][nf], 0, 0, 0);
      }
    __syncthreads();
  }
  const int rb = m0 + wr * 64 + (lane >> 4) * 4;
  const int cb = n0 + wc * 64 + mlo;
#pragma unroll
  for (int mf = 0; mf < 4; ++mf)
#pragma unroll
    for (int nf = 0; nf < 4; ++nf) {
      int col = cb + nf * 16;
#pragma unroll
      for (int r = 0; r < 4; ++r) {
        int row = rb + mf * 16 + r;
        float v = acc[mf][nf][r];
        if (col < DI) z[(size_t)row * DI + col] = v;
        else if (col < DI + CONVD) xBC[(size_t)row * CONVD + (col - DI)] = v;
        else if (col < DIP) {
          int hh = col - (DI + CONVD);
          float xv = v + dt_bias[hh];
          dt[(size_t)row * NH + hh] = (xv > 20.f) ? xv : log1pf(expf(xv));
        }
      }
    }
}

// ---------------- bf16x3 MFMA GEMM: out_proj ----------------
__global__ __launch_bounds__(256) void k_gemm2(
    const u16* __restrict__ Ah, const u16* __restrict__ Al,
    const u16* __restrict__ Bh, const u16* __restrict__ Bl,
    float* __restrict__ out)
{
  __shared__ u16 lds[16384];
  const int t = threadIdx.x;
  const int lane = t & 63, wid = t >> 6;
  const int wr = wid >> 1, wc = wid & 1;
  const int gg = lane >> 4, mlo = lane & 15;
  const int m0 = blockIdx.x * 128, n0 = blockIdx.y * 128;
  f32x4 acc[4][4];
#pragma unroll
  for (int i = 0; i < 4; ++i)
#pragma unroll
    for (int j = 0; j < 4; ++j) acc[i][j] = (f32x4){0.f, 0.f, 0.f, 0.f};
  const u16* g0 = Ah + (size_t)m0 * DI;
  const u16* g1 = Al + (size_t)m0 * DI;
  const u16* g2 = Bh + (size_t)n0 * DI;
  const u16* g3 = Bl + (size_t)n0 * DI;
  const char* ldsb = (const char*)lds;
  for (int k0 = 0; k0 < DI; k0 += 32) {
#pragma unroll
    for (int i = 0; i < 2; ++i) {
      int S = i * 256 + t;
      int m = S >> 2;
      int g = (S ^ (m >> 1)) & 3;
      size_t goff = (size_t)m * DI + k0 + g * 8;
      __builtin_amdgcn_global_load_lds((const __attribute__((address_space(1))) u32*)(g0 + goff),
          (__attribute__((address_space(3))) u32*)(lds + S * 8), 16, 0, 0);
      __builtin_amdgcn_global_load_lds((const __attribute__((address_space(1))) u32*)(g1 + goff),
          (__attribute__((address_space(3))) u32*)(lds + 4096 + S * 8), 16, 0, 0);
      __builtin_amdgcn_global_load_lds((const __attribute__((address_space(1))) u32*)(g2 + goff),
          (__attribute__((address_space(3))) u32*)(lds + 8192 + S * 8), 16, 0, 0);
      __builtin_amdgcn_global_load_lds((const __attribute__((address_space(1))) u32*)(g3 + goff),
          (__attribute__((address_space(3))) u32*)(lds + 12288 + S * 8), 16, 0, 0);
    }
    __syncthreads();
    bf16x8 fa[4], fal[4], fb[4], fbl[4];
#pragma unroll
    for (int mf = 0; mf < 4; ++mf) {
      int m = wr * 64 + mf * 16 + mlo;
      int off = m * 64 + (((gg ^ (m >> 1)) & 3) << 4);
      fa[mf]  = *(const bf16x8*)(ldsb + off);
      fal[mf] = *(const bf16x8*)(ldsb + 8192 + off);
    }
#pragma unroll
    for (int nf = 0; nf < 4; ++nf) {
      int n = wc * 64 + nf * 16 + mlo;
      int off = n * 64 + (((gg ^ (n >> 1)) & 3) << 4);
      fb[nf]  = *(const bf16x8*)(ldsb + 16384 + off);
      fbl[nf] = *(const bf16x8*)(ldsb + 24576 + off);
    }
#pragma unroll
    for (int mf = 0; mf < 4; ++mf)
#pragma unroll
      for (int nf = 0; nf < 4; ++nf) {
        acc[mf][nf] = __builtin_amdgcn_mfma_f32_16x16x32_bf16(fa[mf],  fb[nf],  acc[mf][nf], 0, 0, 0);
        acc[mf][nf] = __builtin_amdgcn_mfma_f32_16x16x32_bf16(fa[mf],  fbl[nf], acc[mf][nf], 0, 0, 0);
        acc[mf][nf] = __builtin_amdgcn_mfma_f32_16x16x32_bf16(fal[mf], fb[nf],  acc[mf][nf], 0, 0, 0);
      }
    __syncthreads();
  }
  const int rb = m0 + wr * 64 + (lane >> 4) * 4;
  const int cb = n0 + wc * 64 + mlo;
#pragma unroll
  for (int mf = 0; mf < 4; ++mf)
#pragma unroll
    for (int nf = 0; nf < 4; ++nf) {
      int col = cb + nf * 16;
#pragma unroll
      for (int r = 0; r < 4; ++r) {
        int row = rb + mf * 16 + r;
        int b = row >> 10, l = row & 1023;
        out[((size_t)(b * DM + col)) * L_ + l] = acc[mf][nf][r];
      }
    }
}

// ---------------- K2: LDS-tiled depthwise 3x3 conv + bias + SiLU + split ----------------
// x channels -> fp32; B/C channels -> bf16 hi/lo pairs (natural layout)
#define CC 16
__global__ __launch_bounds__(256) void k_conv(
    const float* __restrict__ xBC, const float* __restrict__ cw,
    const float* __restrict__ cb,
    float* __restrict__ x,
    u16* __restrict__ Bh, u16* __restrict__ Bl,
    u16* __restrict__ Chh, u16* __restrict__ Cll)
{
  __shared__ float Ls[18][32][CC];
  const int t  = threadIdx.x;
  const int c0 = blockIdx.x * CC;
  const int h0 = blockIdx.y * 16;
  const int b  = blockIdx.z;
#pragma unroll
  for (int k = 0; k < 9; ++k) {
    int f = k * 256 + t;
    int fc4 = f & 3, fw = (f >> 2) & 31, fr = f >> 7;
    int h = h0 + fr - 1;
    float4 v = make_float4(0.f, 0.f, 0.f, 0.f);
    if (h >= 0 && h < 32)
      v = *(const float4*)&xBC[((size_t)(b * 1024 + h * 32 + fw)) * CONVD + c0 + fc4 * 4];
    *(float4*)&Ls[fr][fw][fc4 * 4] = v;
  }
  const int c4 = t & 3;
  const int w  = (t >> 2) & 31;
  const int hb = t >> 7;
  float wt[4][9];
  float bias[4];
#pragma unroll
  for (int j = 0; j < 4; ++j) {
    int c = c0 + c4 * 4 + j;
    bias[j] = cb[c];
#pragma unroll
    for (int kb = 0; kb < 9; ++kb) wt[j][kb] = cw[c * 9 + kb];
  }
  __syncthreads();
#pragma unroll
  for (int k = 0; k < 8; ++k) {
    int h = hb * 8 + k;
    float acc[4] = {bias[0], bias[1], bias[2], bias[3]};
#pragma unroll
    for (int dh = 0; dh < 3; ++dh) {
#pragma unroll
      for (int dw = -1; dw <= 1; ++dw) {
        int ww = w + dw;
        if (ww < 0 || ww > 31) continue;
        const float* p = &Ls[h + dh][ww][c4 * 4];
        int kb = dh * 3 + (dw + 1);
#pragma unroll
        for (int j = 0; j < 4; ++j) acc[j] = fmaf(p[j], wt[j][kb], acc[j]);
      }
    }
    float s4[4];
#pragma unroll
    for (int j = 0; j < 4; ++j) { float v = acc[j]; s4[j] = v / (1.f + expf(-v)); }
    size_t row = (size_t)b * 1024 + (h0 + h) * 32 + w;
    int c = c0 + c4 * 4;
    if (c < DI) {
      *(float4*)&x[row * DI + c] = make_float4(s4[0], s4[1], s4[2], s4[3]);
    } else {
      u16 hv[4], lv[4];
#pragma unroll
      for (int j = 0; j < 4; ++j) bsplit(s4[j], hv[j], lv[j]);
      uint2 hp = make_uint2((u32)hv[0] | ((u32)hv[1] << 16), (u32)hv[2] | ((u32)hv[3] << 16));
      uint2 lp = make_uint2((u32)lv[0] | ((u32)lv[1] << 16), (u32)lv[2] | ((u32)lv[3] << 16));
      if (c < DI + DS) {
        *(uint2*)&Bh[row * DS + (c - DI)] = hp;
        *(uint2*)&Bl[row * DS + (c - DI)] = lp;
      } else {
        *(uint2*)&Chh[row * DS + (c - DI - DS)] = hp;
        *(uint2*)&Cll[row * DS + (c - DI - DS)] = lp;
      }
    }
  }
}

// ---------------- K3: dt*A cumsum per chunk ----------------
__global__ __launch_bounds__(256) void k_dtcum(
    const float* __restrict__ dt, const float* __restrict__ A_log,
    float* __restrict__ dAcs, float* __restrict__ cdecay)
{
  __shared__ float s[256];
  const int bc = blockIdx.x;
  const int i  = threadIdx.x;
  const size_t row = (size_t)bc * 256 + i;
  for (int h = 0; h < NH; ++h) {
    float A = -expf(A_log[h]);
    float v = dt[row * NH + h] * A;
    s[i] = v;
    __syncthreads();
#pragma unroll
    for (int off = 1; off < 256; off <<= 1) {
      float add = (i >= off) ? s[i - off] : 0.f;
      __syncthreads();
      s[i] += add;
      __syncthreads();
    }
    float cs = s[i];
    dAcs[row * NH + h] = cs;
    if (i == 255) cdecay[bc * NH + h] = expf(cs);
    __syncthreads();
  }
}

// ---------------- K5: chunk states via MFMA (bf16x3) ----------------
// states[p,n] = sum_j (x[j,p]*w_j) * B[j,n], per (chunk, head)
__global__ __launch_bounds__(256) void k_states(
    const float* __restrict__ x,
    const u16* __restrict__ Bh, const u16* __restrict__ Bl,
    const float* __restrict__ dt, const float* __restrict__ dAcs,
    float* __restrict__ states)
{
  __shared__ float xf[64 * 65];
  __shared__ u32  bpack[64 * 65];
  __shared__ u16 BTh_t[4096], BTl_t[4096], Xh_t[4096], Xl_t[4096];
  __shared__ float wall[256];
  const int bc = blockIdx.x;
  const int hh = blockIdx.y;
  const int t  = threadIdx.x;
  const int lane = t & 63, w = t >> 6;
  const int mlo = lane & 15, gg = lane >> 4;
  const int r = t >> 2, q = (t & 3) * 16;
  const size_t base = (size_t)bc * 256;
  const float last = dAcs[(base + 255) * NH + hh];
  wall[t] = expf(last - dAcs[(base + t) * NH + hh]) * dt[(base + t) * NH + hh];
  f32x4 acc[4];
#pragma unroll
  for (int i = 0; i < 4; ++i) acc[i] = (f32x4){0.f, 0.f, 0.f, 0.f};
  for (int jt = 0; jt < 4; ++jt) {
    const int j0 = jt * 64;
    __syncthreads();
    // stage x tile [j][p] fp32 and B rows packed (hi<<16|lo)
    {
      const float* xp = &x[(size_t)(base + j0 + r) * DI + hh * HD + q];
#pragma unroll
      for (int k = 0; k < 4; ++k) {
        float4 v = *(const float4*)(xp + k * 4);
        xf[r * 65 + q + k * 4 + 0] = v.x; xf[r * 65 + q + k * 4 + 1] = v.y;
        xf[r * 65 + q + k * 4 + 2] = v.z; xf[r * 65 + q + k * 4 + 3] = v.w;
      }
      const u16* bhp = &Bh[(size_t)(base + j0 + r) * DS + q];
      const u16* blp = &Bl[(size_t)(base + j0 + r) * DS + q];
      U4 H0, H1, L0, L1;
      H0.v = *(const uint4*)bhp; H1.v = *(const uint4*)(bhp + 8);
      L0.v = *(const uint4*)blp; L1.v = *(const uint4*)(blp + 8);
#pragma unroll
      for (int k = 0; k < 8; ++k) {
        bpack[r * 65 + q + k]     = ((u32)H0.s[k] << 16) | L0.s[k];
        bpack[r * 65 + q + 8 + k] = ((u32)H1.s[k] << 16) | L1.s[k];
      }
    }
    __syncthreads();
    // transpose B -> BT tiles; transpose+scale+split x -> Xw tiles
#pragma unroll
    for (int c = 0; c < 2; ++c) {
      U4 BH, BL, XH, XL;
#pragma unroll
      for (int jj = 0; jj < 8; ++jj) {
        int j = q + c * 8 + jj;
        u32 vv = bpack[j * 65 + r];
        BH.s[jj] = (u16)(vv >> 16); BL.s[jj] = (u16)(vv & 0xffff);
        float xv = xf[j * 65 + r] * wall[j0 + j];
        u16 h, l; bsplit(xv, h, l);
        XH.s[jj] = h; XL.s[jj] = l;
      }
      int slot = (q >> 3) + c;
      *(uint4*)((char*)BTh_t + SWZ(r, slot)) = BH.v;
      *(uint4*)((char*)BTl_t + SWZ(r, slot)) = BL.v;
      *(uint4*)((char*)Xh_t  + SWZ(r, slot)) = XH.v;
      *(uint4*)((char*)Xl_t  + SWZ(r, slot)) = XL.v;
    }
    __syncthreads();
#pragma unroll
    for (int s = 0; s < 2; ++s) {
      bf16x8 fah = *(const bf16x8*)((const char*)Xh_t + SWZ(w * 16 + mlo, s * 4 + gg));
      bf16x8 fal = *(const bf16x8*)((const char*)Xl_t + SWZ(w * 16 + mlo, s * 4 + gg));
#pragma unroll
      for (int nf = 0; nf < 4; ++nf) {
        bf16x8 fbh = *(const bf16x8*)((const char*)BTh_t + SWZ(nf * 16 + mlo, s * 4 + gg));
        bf16x8 fbl = *(const bf16x8*)((const char*)BTl_t + SWZ(nf * 16 + mlo, s * 4 + gg));
        acc[nf] = __builtin_amdgcn_mfma_f32_16x16x32_bf16(fah, fbh, acc[nf], 0, 0, 0);
        acc[nf] = __builtin_amdgcn_mfma_f32_16x16x32_bf16(fah, fbl, acc[nf], 0, 0, 0);
        acc[nf] = __builtin_amdgcn_mfma_f32_16x16x32_bf16(fal, fbh, acc[nf], 0, 0, 0);
      }
    }
  }
  const size_t sb = ((size_t)(bc * NH + hh)) << 12;
#pragma unroll
  for (int nf = 0; nf < 4; ++nf)
#pragma unroll
    for (int reg = 0; reg < 4; ++reg) {
      int p = w * 16 + (lane >> 4) * 4 + reg;
      int n = nf * 16 + mlo;
      states[sb + (size_t)p * 64 + n] = acc[nf][reg];
    }
}

// ---------------- K6: inter-chunk scan ----------------
__global__ __launch_bounds__(256) void k_scanc(
    const float* __restrict__ states, const float* __restrict__ cdecay,
    float* __restrict__ prev)
{
  int tid = blockIdx.x * 256 + threadIdx.x;
  int pn  = tid & 4095;
  int rem = tid >> 12;
  int hh  = rem % NH;
  int b   = rem / NH;
  float carry = 0.f;
#pragma unroll
  for (int c = 0; c < 4; ++c) {
    size_t idx = ((size_t)((b * 4 + c) * NH + hh) << 12) + pn;
    prev[idx] = carry;
    carry = carry * cdecay[(b * 4 + c) * NH + hh] + states[idx];
  }
}

// ---------------- K7: y = intra + inter + D*x via MFMA (G recomputed on the fly) ----------------
__global__ __launch_bounds__(256) void k_y(
    const float* __restrict__ x,
    const u16* __restrict__ Chg, const u16* __restrict__ Clg,
    const u16* __restrict__ Bhg, const u16* __restrict__ Blg,
    const float* __restrict__ dtp, const float* __restrict__ dAcs,
    const float* __restrict__ prev, const float* __restrict__ Dp,
    float* __restrict__ y)
{
  __shared__ u16 Ch_t[4096], Cl_t[4096];
  __shared__ u16 Ph_t[4096], Pl_t[4096];   // prev tiles, then B tiles
  __shared__ u16 Xh_t[4096], Xl_t[4096];
  __shared__ u16 att_t[4096];
  __shared__ float xf[64 * 65];
  __shared__ float dAi_s[64], ei_s[64], dAj_s[64], dtj_s[64];
  const int bc = blockIdx.x;
  const int hh = blockIdx.y;
  const int it = blockIdx.z;
  const int t  = threadIdx.x;
  const int lane = t & 63, w = t >> 6;
  const int mlo = lane & 15, gg = lane >> 4;
  const int r = t >> 2, q = (t & 3) * 16;
  const int slot0 = q >> 3;
  const size_t base = (size_t)bc * 256;
  const int i0 = it * 64;
  // stage C (swizzled copy of hi/lo pair)
  {
    const u16* ch = &Chg[(size_t)(base + i0 + r) * DS + q];
    const u16* cl = &Clg[(size_t)(base + i0 + r) * DS + q];
    *(uint4*)((char*)Ch_t + SWZ(r, slot0))     = *(const uint4*)ch;
    *(uint4*)((char*)Ch_t + SWZ(r, slot0 + 1)) = *(const uint4*)(ch + 8);
    *(uint4*)((char*)Cl_t + SWZ(r, slot0))     = *(const uint4*)cl;
    *(uint4*)((char*)Cl_t + SWZ(r, slot0 + 1)) = *(const uint4*)(cl + 8);
  }
  // stage prev (fp32 -> split pair)
  {
    const float* pp = &prev[(((size_t)(bc * NH + hh)) << 12) + (size_t)r * 64 + q];
    U4 H0, H1, L0, L1;
#pragma unroll
    for (int k = 0; k < 16; ++k) {
      float v = pp[k];
      u16 h, l; bsplit(v, h, l);
      if (k < 8) { H0.s[k] = h; L0.s[k] = l; } else { H1.s[k - 8] = h; L1.s[k - 8] = l; }
    }
    *(uint4*)((char*)Ph_t + SWZ(r, slot0))     = H0.v;
    *(uint4*)((char*)Ph_t + SWZ(r, slot0 + 1)) = H1.v;
    *(uint4*)((char*)Pl_t + SWZ(r, slot0))     = L0.v;
    *(uint4*)((char*)Pl_t + SWZ(r, slot0 + 1)) = L1.v;
  }
  if (t < 64) {
    float da = dAcs[(base + i0 + t) * NH + hh];
    dAi_s[t] = da;
    ei_s[t] = expf(da);
  }
  __syncthreads();
  // cache C fragments (reused for inter + every G tile)
  bf16x8 fch[2], fcl[2];
#pragma unroll
  for (int s = 0; s < 2; ++s) {
    fch[s] = *(const bf16x8*)((const char*)Ch_t + SWZ(w * 16 + mlo, s * 4 + gg));
    fcl[s] = *(const bf16x8*)((const char*)Cl_t + SWZ(w * 16 + mlo, s * 4 + gg));
  }
  // inter: y = C . prev^T
  f32x4 accy[4];
#pragma unroll
  for (int i = 0; i < 4; ++i) accy[i] = (f32x4){0.f, 0.f, 0.f, 0.f};
#pragma unroll
  for (int s = 0; s < 2; ++s)
#pragma unroll
    for (int pf = 0; pf < 4; ++pf) {
      bf16x8 fph = *(const bf16x8*)((const char*)Ph_t + SWZ(pf * 16 + mlo, s * 4 + gg));
      bf16x8 fpl = *(const bf16x8*)((const char*)Pl_t + SWZ(pf * 16 + mlo, s * 4 + gg));
      accy[pf] = __builtin_amdgcn_mfma_f32_16x16x32_bf16(fch[s], fph, accy[pf], 0, 0, 0);
      accy[pf] = __builtin_amdgcn_mfma_f32_16x16x32_bf16(fch[s], fpl, accy[pf], 0, 0, 0);
      accy[pf] = __builtin_amdgcn_mfma_f32_16x16x32_bf16(fcl[s], fph, accy[pf], 0, 0, 0);
    }
  // scale by exp(dA_cs[i])
#pragma unroll
  for (int pf = 0; pf < 4; ++pf)
#pragma unroll
    for (int reg = 0; reg < 4; ++reg)
      accy[pf][reg] *= ei_s[w * 16 + (lane >> 4) * 4 + reg];

  for (int jt = 0; jt <= it; ++jt) {
    const int j0j = jt * 64;
    __syncthreads();
    // stage B tile (into P space) + x tile fp32 + per-j scalars
    {
      const u16* bh = &Bhg[(size_t)(base + j0j + r) * DS + q];
      const u16* bl = &Blg[(size_t)(base + j0j + r) * DS + q];
      *(uint4*)((char*)Ph_t + SWZ(r, slot0))     = *(const uint4*)bh;
      *(uint4*)((char*)Ph_t + SWZ(r, slot0 + 1)) = *(const uint4*)(bh + 8);
      *(uint4*)((char*)Pl_t + SWZ(r, slot0))     = *(const uint4*)bl;
      *(uint4*)((char*)Pl_t + SWZ(r, slot0 + 1)) = *(const uint4*)(bl + 8);
      const float* xp = &x[(size_t)(base + j0j + r) * DI + hh * HD + q];
#pragma unroll
      for (int k = 0; k < 4; ++k) {
        float4 v = *(const float4*)(xp + k * 4);
        xf[r * 65 + q + k * 4 + 0] = v.x; xf[r * 65 + q + k * 4 + 1] = v.y;
        xf[r * 65 + q + k * 4 + 2] = v.z; xf[r * 65 + q + k * 4 + 3] = v.w;
      }
    }
    if (t < 64) {
      dAj_s[t] = dAcs[(base + j0j + t) * NH + hh];
      dtj_s[t] = dtp[(base + j0j + t) * NH + hh];
    }
    __syncthreads();
    // G tile via MFMA
    f32x4 g[4];
#pragma unroll
    for (int i = 0; i < 4; ++i) g[i] = (f32x4){0.f, 0.f, 0.f, 0.f};
#pragma unroll
    for (int s = 0; s < 2; ++s)
#pragma unroll
      for (int jf = 0; jf < 4; ++jf) {
        bf16x8 fbh = *(const bf16x8*)((const char*)Ph_t + SWZ(jf * 16 + mlo, s * 4 + gg));
        bf16x8 fbl = *(const bf16x8*)((const char*)Pl_t + SWZ(jf * 16 + mlo, s * 4 + gg));
        g[jf] = __builtin_amdgcn_mfma_f32_16x16x32_bf16(fch[s], fbh, g[jf], 0, 0, 0);
        g[jf] = __builtin_amdgcn_mfma_f32_16x16x32_bf16(fch[s], fbl, g[jf], 0, 0, 0);
        g[jf] = __builtin_amdgcn_mfma_f32_16x16x32_bf16(fcl[s], fbh, g[jf], 0, 0, 0);
      }
    // transpose+split x -> [p][j] tiles
#pragma unroll
    for (int c = 0; c < 2; ++c) {
      U4 XH, XL;
#pragma unroll
      for (int jj = 0; jj < 8; ++jj) {
        int j = q + c * 8 + jj;
        u16 h, l; bsplit(xf[j * 65 + r], h, l);
        XH.s[jj] = h; XL.s[jj] = l;
      }
      *(uint4*)((char*)Xh_t + SWZ(r, slot0 + c)) = XH.v;
      *(uint4*)((char*)Xl_t + SWZ(r, slot0 + c)) = XL.v;
    }
    // att = G * exp(dAi - dAj) * dtj, causal mask, -> bf16 tile
#pragma unroll
    for (int jf = 0; jf < 4; ++jf)
#pragma unroll
      for (int reg = 0; reg < 4; ++reg) {
        int il = w * 16 + (lane >> 4) * 4 + reg;
        int jl = jf * 16 + mlo;
        bool ok = (jt < it) || (jl <= il);
        float av = ok ? g[jf][reg] * expf(dAi_s[il] - dAj_s[jl]) * dtj_s[jl] : 0.f;
        *(u16*)((char*)att_t + SWZ(il, jl >> 3) + (jl & 7) * 2) = f2b(av);
      }
    __syncthreads();
    // intra: y += att . xT
#pragma unroll
    for (int s = 0; s < 2; ++s) {
      bf16x8 fa = *(const bf16x8*)((const char*)att_t + SWZ(w * 16 + mlo, s * 4 + gg));
#pragma unroll
      for (int pf = 0; pf < 4; ++pf) {
        bf16x8 fxh = *(const bf16x8*)((const char*)Xh_t + SWZ(pf * 16 + mlo, s * 4 + gg));
        bf16x8 fxl = *(const bf16x8*)((const char*)Xl_t + SWZ(pf * 16 + mlo, s * 4 + gg));
        accy[pf] = __builtin_amdgcn_mfma_f32_16x16x32_bf16(fa, fxh, accy[pf], 0, 0, 0);
        accy[pf] = __builtin_amdgcn_mfma_f32_16x16x32_bf16(fa, fxl, accy[pf], 0, 0, 0);
      }
    }
  }
  // epilogue: + D*x, store y
  const float Dh = Dp[hh];
#pragma unroll
  for (int pf = 0; pf < 4; ++pf)
#pragma unroll
    for (int reg = 0; reg < 4; ++reg) {
      size_t row = base + i0 + w * 16 + (lane >> 4) * 4 + reg;
      int col = hh * HD + pf * 16 + mlo;
      y[row * DI + col] = accy[pf][reg] + Dh * x[row * DI + col];
    }
}

// ---------------- K8: LayerNorm * z -> bf16 hi/lo pair ----------------
__global__ __launch_bounds__(256) void k_norm(
    const float* __restrict__ z, const float* __restrict__ nw,
    const float* __restrict__ nb, const float* __restrict__ y,
    u16* __restrict__ yh, u16* __restrict__ yl)
{
  __shared__ float rs[4], rq[4];
  const size_t row = blockIdx.x;
  const int t = threadIdx.x;
  float v[3];
  float s = 0.f, sq = 0.f;
#pragma unroll
  for (int r = 0; r < 3; ++r) {
    v[r] = y[row * DI + r * 256 + t];
    s += v[r];
    sq = fmaf(v[r], v[r], sq);
  }
#pragma unroll
  for (int off = 32; off > 0; off >>= 1) {
    s  += __shfl_down(s, off, 64);
    sq += __shfl_down(sq, off, 64);
  }
  const int wid = t >> 6, lane = t & 63;
  if (lane == 0) { rs[wid] = s; rq[wid] = sq; }
  __syncthreads();
  if (t == 0) {
    rs[0] = rs[0] + rs[1] + rs[2] + rs[3];
    rq[0] = rq[0] + rq[1] + rq[2] + rq[3];
  }
  __syncthreads();
  const float mu   = rs[0] * (1.f / DI);
  const float var  = rq[0] * (1.f / DI) - mu * mu;
  const float rstd = 1.f / sqrtf(var + EPS_);
#pragma unroll
  for (int r = 0; r < 3; ++r) {
    int d = r * 256 + t;
    float o = (v[r] - mu) * rstd * nw[d] + nb[d];
    float p = o * z[row * DI + d];
    u16 h, l;
    bsplit(p, h, l);
    yh[row * DI + d] = h;
    yl[row * DI + d] = l;
  }
}

extern "C" void kernel_launch(void* const* d_in, const int* in_sizes, int n_in,
                              void* d_out, int out_size, void* d_ws, size_t ws_size,
                              hipStream_t stream)
{
  const float* u    = (const float*)d_in[0];
  const float* ipw  = (const float*)d_in[1];
  const float* cw   = (const float*)d_in[2];
  const float* cb   = (const float*)d_in[3];
  const float* dtb  = (const float*)d_in[4];
  const float* Alog = (const float*)d_in[5];
  const float* Dp   = (const float*)d_in[6];
  const float* nw   = (const float*)d_in[7];
  const float* nb   = (const float*)d_in[8];
  const float* opw  = (const float*)d_in[9];
  float* out = (float*)d_out;

  float* ws = (float*)d_ws;
  size_t off = 0;
  float* z_buf   = ws + off; off += (size_t)B_ * L_ * DI;
  float* xBC_buf = ws + off; off += (size_t)B_ * L_ * CONVD;
  float* y_buf   = xBC_buf;                       // alias: xBC dead after conv
  float* dt_buf  = ws + off; off += (size_t)B_ * L_ * NH;
  float* x_buf   = ws + off; off += (size_t)B_ * L_ * DI;
  u16*   Bh_buf  = (u16*)(ws + off); off += (size_t)B_ * L_ * DS / 2;
  u16*   Bl_buf  = (u16*)(ws + off); off += (size_t)B_ * L_ * DS / 2;
  u16*   Ch_buf  = (u16*)(ws + off); off += (size_t)B_ * L_ * DS / 2;
  u16*   Cl_buf  = (u16*)(ws + off); off += (size_t)B_ * L_ * DS / 2;
  float* dAcs    = ws + off; off += (size_t)B_ * L_ * NH;
  float* cdec    = ws + off; off += (size_t)B_ * NCH * NH;
  float* st_buf  = ws + off; off += (size_t)B_ * NCH * NH * HD * DS;
  float* pv_buf  = ws + off; off += (size_t)B_ * NCH * NH * HD * DS;
  u16*   Woh     = (u16*)(ws + off); off += (size_t)DM * DI / 2;
  u16*   Wol     = (u16*)(ws + off); off += (size_t)DM * DI / 2;

  // aliases inside x_buf (dead/live windows don't overlap)
  u16* Ah = (u16*)x_buf;
  u16* Al = Ah + (size_t)B_ * L_ * DM;
  u16* Wh = Al + (size_t)B_ * L_ * DM;
  u16* Wl = Wh + (size_t)NP1 * DM;
  u16* yh = (u16*)x_buf;
  u16* yl = yh + (size_t)B_ * L_ * DI;

  hipLaunchKernelGGL(k_cvtA, dim3(8, 12, 16), dim3(256), 0, stream, u, Ah, Al);
  hipLaunchKernelGGL(k_cvtW, dim3((NP1 * DM / 4 + 255) / 256), dim3(256), 0, stream,
                     ipw, Wh, Wl, DIP, DM, NP1 * DM / 4);
  hipLaunchKernelGGL(k_cvtW, dim3((DM * DI / 4 + 255) / 256), dim3(256), 0, stream,
                     opw, Woh, Wol, DM, DI, DM * DI / 4);
  hipLaunchKernelGGL(k_gemm1, dim3(128, 14), dim3(256), 0, stream,
                     Ah, Al, Wh, Wl, dtb, z_buf, xBC_buf, dt_buf);
  hipLaunchKernelGGL(k_conv,   dim3(56, 2, 16), dim3(256), 0, stream,
                     xBC_buf, cw, cb, x_buf, Bh_buf, Bl_buf, Ch_buf, Cl_buf);
  hipLaunchKernelGGL(k_dtcum,  dim3(64), dim3(256), 0, stream, dt_buf, Alog, dAcs, cdec);
  hipLaunchKernelGGL(k_states, dim3(64, 12), dim3(256), 0, stream,
                     x_buf, Bh_buf, Bl_buf, dt_buf, dAcs, st_buf);
  hipLaunchKernelGGL(k_scanc,  dim3(3072), dim3(256), 0, stream, st_buf, cdec, pv_buf);
  hipLaunchKernelGGL(k_y,      dim3(64, 12, 4), dim3(256), 0, stream,
                     x_buf, Ch_buf, Cl_buf, Bh_buf, Bl_buf, dt_buf, dAcs, pv_buf, Dp, y_buf);
  hipLaunchKernelGGL(k_norm,   dim3(16384), dim3(256), 0, stream, z_buf, nw, nb, y_buf, yh, yl);
  hipLaunchKernelGGL(k_gemm2,  dim3(128, 3), dim3(256), 0, stream, yh, yl, Woh, Wol, out);
}

// Round 5
// 311.694 us; speedup vs baseline: 3.2477x; 1.0646x over previous
//
#include <hip/hip_runtime.h>
#include <hip/hip_bf16.h>

#define B_    16
#define L_    1024
#define DM    384
#define DIP   1676
#define NP1   1792
#define DI    768
#define CONVD 896
#define NH    12
#define HD    64
#define DS    64
#define NCH   4
#define CH    256
#define EPS_  1e-5f

typedef unsigned short u16;
typedef unsigned int   u32;
typedef __attribute__((ext_vector_type(8))) short bf16x8;
typedef __attribute__((ext_vector_type(4))) float f32x4;

union U4 { uint4 v; u16 s[8]; };

// byte offset of 16B slot `slot` in row `row` of a [64][64]-bf16 LDS tile (128B rows, XOR swizzle)
#define SWZ(row, slot) (((row) << 7) + ((((slot) ^ ((row) & 7)) & 7) << 4))

// bf16 round-to-nearest-even split helpers
__device__ __forceinline__ u16 f2b(float v) {
  u32 u = __float_as_uint(v);
  u32 r = (u + 0x7FFFu + ((u >> 16) & 1u)) >> 16;
  return (u16)r;
}
__device__ __forceinline__ float b2f(u16 h) { return __uint_as_float(((u32)h) << 16); }
__device__ __forceinline__ void bsplit(float v, u16& h, u16& l) {
  u16 hh = f2b(v);
  l = f2b(v - b2f(hh));
  h = hh;
}

// ---------------- converters ----------------
__global__ __launch_bounds__(256) void k_cvtA(const float* __restrict__ u,
                                              u16* __restrict__ Ah, u16* __restrict__ Al)
{
  __shared__ float Ls[32][129];
  const int t  = threadIdx.x;
  const int l0 = blockIdx.x * 128;
  const int k0 = blockIdx.y * 32;
  const int b  = blockIdx.z;
#pragma unroll
  for (int r = 0; r < 4; ++r) {
    int idx = r * 256 + t;
    int kk = idx >> 5, q = idx & 31;
    float4 v = *(const float4*)&u[((size_t)(b * DM + k0 + kk)) * L_ + l0 + q * 4];
    Ls[kk][q * 4 + 0] = v.x; Ls[kk][q * 4 + 1] = v.y;
    Ls[kk][q * 4 + 2] = v.z; Ls[kk][q * 4 + 3] = v.w;
  }
  __syncthreads();
#pragma unroll
  for (int it = 0; it < 2; ++it) {
    int task = it * 256 + t;
    int l = task >> 2, kq = (task & 3) * 8;
    u32 hw[4], lw[4];
#pragma unroll
    for (int j = 0; j < 4; ++j) {
      u16 h0, l0v, h1, l1v;
      bsplit(Ls[kq + 2 * j + 0][l], h0, l0v);
      bsplit(Ls[kq + 2 * j + 1][l], h1, l1v);
      hw[j] = (u32)h0 | ((u32)h1 << 16);
      lw[j] = (u32)l0v | ((u32)l1v << 16);
    }
    size_t off = ((size_t)(b * L_ + l0 + l)) * DM + k0 + kq;
    *(uint4*)&Ah[off] = make_uint4(hw[0], hw[1], hw[2], hw[3]);
    *(uint4*)&Al[off] = make_uint4(lw[0], lw[1], lw[2], lw[3]);
  }
}

__global__ __launch_bounds__(256) void k_cvtW(const float* __restrict__ W,
    u16* __restrict__ Wh, u16* __restrict__ Wl, int nsrc, int K, int total4)
{
  int i = blockIdx.x * 256 + threadIdx.x;
  if (i >= total4) return;
  int e = i * 4;
  int row = e / K;
  float4 v = make_float4(0.f, 0.f, 0.f, 0.f);
  if (row < nsrc) v = *(const float4*)&W[e];
  u16 h[4], l[4];
  bsplit(v.x, h[0], l[0]); bsplit(v.y, h[1], l[1]);
  bsplit(v.z, h[2], l[2]); bsplit(v.w, h[3], l[3]);
  *(uint2*)&Wh[e] = make_uint2((u32)h[0] | ((u32)h[1] << 16), (u32)h[2] | ((u32)h[3] << 16));
  *(uint2*)&Wl[e] = make_uint2((u32)l[0] | ((u32)l[1] << 16), (u32)l[2] | ((u32)l[3] << 16));
}

// 4-stream staging of one 128x32 (u16) K-tile pair set into LDS buffer `bufbase` (u16 elems)
#define STAGE4(bufbase, k0, KS) do {                                                            \
  _Pragma("unroll")                                                                             \
  for (int i_ = 0; i_ < 2; ++i_) {                                                              \
    int S_ = i_ * 256 + t;                                                                      \
    int m_ = S_ >> 2;                                                                           \
    int g_ = (S_ ^ (m_ >> 1)) & 3;                                                              \
    size_t goff_ = (size_t)m_ * (KS) + (k0) + g_ * 8;                                           \
    __builtin_amdgcn_global_load_lds((const __attribute__((address_space(1))) u32*)(g0 + goff_),\
        (__attribute__((address_space(3))) u32*)(lds + (bufbase) + S_ * 8), 16, 0, 0);          \
    __builtin_amdgcn_global_load_lds((const __attribute__((address_space(1))) u32*)(g1 + goff_),\
        (__attribute__((address_space(3))) u32*)(lds + (bufbase) + 4096 + S_ * 8), 16, 0, 0);   \
    __builtin_amdgcn_global_load_lds((const __attribute__((address_space(1))) u32*)(g2 + goff_),\
        (__attribute__((address_space(3))) u32*)(lds + (bufbase) + 8192 + S_ * 8), 16, 0, 0);   \
    __builtin_amdgcn_global_load_lds((const __attribute__((address_space(1))) u32*)(g3 + goff_),\
        (__attribute__((address_space(3))) u32*)(lds + (bufbase) + 12288 + S_ * 8), 16, 0, 0);  \
  }                                                                                             \
} while (0)

// ---------------- bf16x3 MFMA GEMM: in_proj (double-buffered prefetch) ----------------
__global__ __launch_bounds__(256) void k_gemm1(
    const u16* __restrict__ Ah, const u16* __restrict__ Al,
    const u16* __restrict__ Bh, const u16* __restrict__ Bl,
    const float* __restrict__ dt_bias,
    float* __restrict__ z, float* __restrict__ xBC, float* __restrict__ dt)
{
  __shared__ u16 lds[32768];   // 2 x 32KB buffers
  const int t = threadIdx.x;
  const int lane = t & 63, wid = t >> 6;
  const int wr = wid >> 1, wc = wid & 1;
  const int gg = lane >> 4, mlo = lane & 15;
  const int m0 = blockIdx.x * 128, n0 = blockIdx.y * 128;
  f32x4 acc[4][4];
#pragma unroll
  for (int i = 0; i < 4; ++i)
#pragma unroll
    for (int j = 0; j < 4; ++j) acc[i][j] = (f32x4){0.f, 0.f, 0.f, 0.f};
  const u16* g0 = Ah + (size_t)m0 * DM;
  const u16* g1 = Al + (size_t)m0 * DM;
  const u16* g2 = Bh + (size_t)n0 * DM;
  const u16* g3 = Bl + (size_t)n0 * DM;
  STAGE4(0, 0, DM);
  __syncthreads();
  int cur = 0;
  for (int kt = 0; kt < DM / 32; ++kt) {
    if (kt + 1 < DM / 32) STAGE4((cur ^ 1) * 16384, (kt + 1) * 32, DM);
    const char* ldsb = (const char*)lds + cur * 32768;
    bf16x8 fa[4], fal[4], fb[4], fbl[4];
#pragma unroll
    for (int mf = 0; mf < 4; ++mf) {
      int m = wr * 64 + mf * 16 + mlo;
      int off = m * 64 + (((gg ^ (m >> 1)) & 3) << 4);
      fa[mf]  = *(const bf16x8*)(ldsb + off);
      fal[mf] = *(const bf16x8*)(ldsb + 8192 + off);
    }
#pragma unroll
    for (int nf = 0; nf < 4; ++nf) {
      int n = wc * 64 + nf * 16 + mlo;
      int off = n * 64 + (((gg ^ (n >> 1)) & 3) << 4);
      fb[nf]  = *(const bf16x8*)(ldsb + 16384 + off);
      fbl[nf] = *(const bf16x8*)(ldsb + 24576 + off);
    }
#pragma unroll
    for (int mf = 0; mf < 4; ++mf)
#pragma unroll
      for (int nf = 0; nf < 4; ++nf) {
        acc[mf][nf] = __builtin_amdgcn_mfma_f32_16x16x32_bf16(fa[mf],  fb[nf],  acc[mf][nf], 0, 0, 0);
        acc[mf][nf] = __builtin_amdgcn_mfma_f32_16x16x32_bf16(fa[mf],  fbl[nf], acc[mf][nf], 0, 0, 0);
        acc[mf][nf] = __builtin_amdgcn_mfma_f32_16x16x32_bf16(fal[mf], fb[nf],  acc[mf][nf], 0, 0, 0);
      }
    __syncthreads();   // drains prefetch (vmcnt 0) + syncs buffer swap
    cur ^= 1;
  }
  const int rb = m0 + wr * 64 + (lane >> 4) * 4;
  const int cb = n0 + wc * 64 + mlo;
#pragma unroll
  for (int mf = 0; mf < 4; ++mf)
#pragma unroll
    for (int nf = 0; nf < 4; ++nf) {
      int col = cb + nf * 16;
#pragma unroll
      for (int r = 0; r < 4; ++r) {
        int row = rb + mf * 16 + r;
        float v = acc[mf][nf][r];
        if (col < DI) z[(size_t)row * DI + col] = v;
        else if (col < DI + CONVD) xBC[(size_t)row * CONVD + (col - DI)] = v;
        else if (col < DIP) {
          int hh = col - (DI + CONVD);
          float xv = v + dt_bias[hh];
          dt[(size_t)row * NH + hh] = (xv > 20.f) ? xv : log1pf(expf(xv));
        }
      }
    }
}

// ---------------- bf16x3 MFMA GEMM: out_proj (double-buffered prefetch) ----------------
__global__ __launch_bounds__(256) void k_gemm2(
    const u16* __restrict__ Ah, const u16* __restrict__ Al,
    const u16* __restrict__ Bh, const u16* __restrict__ Bl,
    float* __restrict__ out)
{
  __shared__ u16 lds[32768];
  const int t = threadIdx.x;
  const int lane = t & 63, wid = t >> 6;
  const int wr = wid >> 1, wc = wid & 1;
  const int gg = lane >> 4, mlo = lane & 15;
  const int m0 = blockIdx.x * 128, n0 = blockIdx.y * 128;
  f32x4 acc[4][4];
#pragma unroll
  for (int i = 0; i < 4; ++i)
#pragma unroll
    for (int j = 0; j < 4; ++j) acc[i][j] = (f32x4){0.f, 0.f, 0.f, 0.f};
  const u16* g0 = Ah + (size_t)m0 * DI;
  const u16* g1 = Al + (size_t)m0 * DI;
  const u16* g2 = Bh + (size_t)n0 * DI;
  const u16* g3 = Bl + (size_t)n0 * DI;
  STAGE4(0, 0, DI);
  __syncthreads();
  int cur = 0;
  for (int kt = 0; kt < DI / 32; ++kt) {
    if (kt + 1 < DI / 32) STAGE4((cur ^ 1) * 16384, (kt + 1) * 32, DI);
    const char* ldsb = (const char*)lds + cur * 32768;
    bf16x8 fa[4], fal[4], fb[4], fbl[4];
#pragma unroll
    for (int mf = 0; mf < 4; ++mf) {
      int m = wr * 64 + mf * 16 + mlo;
      int off = m * 64 + (((gg ^ (m >> 1)) & 3) << 4);
      fa[mf]  = *(const bf16x8*)(ldsb + off);
      fal[mf] = *(const bf16x8*)(ldsb + 8192 + off);
    }
#pragma unroll
    for (int nf = 0; nf < 4; ++nf) {
      int n = wc * 64 + nf * 16 + mlo;
      int off = n * 64 + (((gg ^ (n >> 1)) & 3) << 4);
      fb[nf]  = *(const bf16x8*)(ldsb + 16384 + off);
      fbl[nf] = *(const bf16x8*)(ldsb + 24576 + off);
    }
#pragma unroll
    for (int mf = 0; mf < 4; ++mf)
#pragma unroll
      for (int nf = 0; nf < 4; ++nf) {
        acc[mf][nf] = __builtin_amdgcn_mfma_f32_16x16x32_bf16(fa[mf],  fb[nf],  acc[mf][nf], 0, 0, 0);
        acc[mf][nf] = __builtin_amdgcn_mfma_f32_16x16x32_bf16(fa[mf],  fbl[nf], acc[mf][nf], 0, 0, 0);
        acc[mf][nf] = __builtin_amdgcn_mfma_f32_16x16x32_bf16(fal[mf], fb[nf],  acc[mf][nf], 0, 0, 0);
      }
    __syncthreads();
    cur ^= 1;
  }
  const int rb = m0 + wr * 64 + (lane >> 4) * 4;
  const int cb = n0 + wc * 64 + mlo;
#pragma unroll
  for (int mf = 0; mf < 4; ++mf)
#pragma unroll
    for (int nf = 0; nf < 4; ++nf) {
      int col = cb + nf * 16;
#pragma unroll
      for (int r = 0; r < 4; ++r) {
        int row = rb + mf * 16 + r;
        int b = row >> 10, l = row & 1023;
        out[((size_t)(b * DM + col)) * L_ + l] = acc[mf][nf][r];
      }
    }
}

// ---------------- K2: LDS-tiled depthwise 3x3 conv + bias + SiLU + split ----------------
#define CC 16
__global__ __launch_bounds__(256) void k_conv(
    const float* __restrict__ xBC, const float* __restrict__ cw,
    const float* __restrict__ cb,
    float* __restrict__ x,
    u16* __restrict__ Bh, u16* __restrict__ Bl,
    u16* __restrict__ Chh, u16* __restrict__ Cll)
{
  __shared__ float Ls[18][32][CC];
  const int t  = threadIdx.x;
  const int c0 = blockIdx.x * CC;
  const int h0 = blockIdx.y * 16;
  const int b  = blockIdx.z;
#pragma unroll
  for (int k = 0; k < 9; ++k) {
    int f = k * 256 + t;
    int fc4 = f & 3, fw = (f >> 2) & 31, fr = f >> 7;
    int h = h0 + fr - 1;
    float4 v = make_float4(0.f, 0.f, 0.f, 0.f);
    if (h >= 0 && h < 32)
      v = *(const float4*)&xBC[((size_t)(b * 1024 + h * 32 + fw)) * CONVD + c0 + fc4 * 4];
    *(float4*)&Ls[fr][fw][fc4 * 4] = v;
  }
  const int c4 = t & 3;
  const int w  = (t >> 2) & 31;
  const int hb = t >> 7;
  float wt[4][9];
  float bias[4];
#pragma unroll
  for (int j = 0; j < 4; ++j) {
    int c = c0 + c4 * 4 + j;
    bias[j] = cb[c];
#pragma unroll
    for (int kb = 0; kb < 9; ++kb) wt[j][kb] = cw[c * 9 + kb];
  }
  __syncthreads();
#pragma unroll
  for (int k = 0; k < 8; ++k) {
    int h = hb * 8 + k;
    float acc[4] = {bias[0], bias[1], bias[2], bias[3]};
#pragma unroll
    for (int dh = 0; dh < 3; ++dh) {
#pragma unroll
      for (int dw = -1; dw <= 1; ++dw) {
        int ww = w + dw;
        if (ww < 0 || ww > 31) continue;
        const float* p = &Ls[h + dh][ww][c4 * 4];
        int kb = dh * 3 + (dw + 1);
#pragma unroll
        for (int j = 0; j < 4; ++j) acc[j] = fmaf(p[j], wt[j][kb], acc[j]);
      }
    }
    float s4[4];
#pragma unroll
    for (int j = 0; j < 4; ++j) { float v = acc[j]; s4[j] = v / (1.f + expf(-v)); }
    size_t row = (size_t)b * 1024 + (h0 + h) * 32 + w;
    int c = c0 + c4 * 4;
    if (c < DI) {
      *(float4*)&x[row * DI + c] = make_float4(s4[0], s4[1], s4[2], s4[3]);
    } else {
      u16 hv[4], lv[4];
#pragma unroll
      for (int j = 0; j < 4; ++j) bsplit(s4[j], hv[j], lv[j]);
      uint2 hp = make_uint2((u32)hv[0] | ((u32)hv[1] << 16), (u32)hv[2] | ((u32)hv[3] << 16));
      uint2 lp = make_uint2((u32)lv[0] | ((u32)lv[1] << 16), (u32)lv[2] | ((u32)lv[3] << 16));
      if (c < DI + DS) {
        *(uint2*)&Bh[row * DS + (c - DI)] = hp;
        *(uint2*)&Bl[row * DS + (c - DI)] = lp;
      } else {
        *(uint2*)&Chh[row * DS + (c - DI - DS)] = hp;
        *(uint2*)&Cll[row * DS + (c - DI - DS)] = lp;
      }
    }
  }
}

// ---------------- K3: dt*A cumsum per chunk (wave shuffle scan, one block per (bc,h)) ----------------
__global__ __launch_bounds__(256) void k_dtcum(
    const float* __restrict__ dt, const float* __restrict__ A_log,
    float* __restrict__ dAcs, float* __restrict__ cdecay)
{
  __shared__ float ws[4];
  const int bc = blockIdx.x;
  const int h  = blockIdx.y;
  const int t  = threadIdx.x;
  const int lane = t & 63, w = t >> 6;
  const size_t row = (size_t)bc * 256 + t;
  const float A = -expf(A_log[h]);
  float x = dt[row * NH + h] * A;
#pragma unroll
  for (int off = 1; off < 64; off <<= 1) {
    float y = __shfl_up(x, off, 64);
    if (lane >= off) x += y;
  }
  if (lane == 63) ws[w] = x;
  __syncthreads();
  float add = 0.f;
#pragma unroll
  for (int i = 0; i < 4; ++i) if (i < w) add += ws[i];
  x += add;
  dAcs[row * NH + h] = x;
  if (t == 255) cdecay[bc * NH + h] = expf(x);
}

// ---------------- K5: chunk states via MFMA (bf16x3) ----------------
__global__ __launch_bounds__(256) void k_states(
    const float* __restrict__ x,
    const u16* __restrict__ Bh, const u16* __restrict__ Bl,
    const float* __restrict__ dt, const float* __restrict__ dAcs,
    float* __restrict__ states)
{
  __shared__ float xf[64 * 65];
  __shared__ u32  bpack[64 * 65];
  __shared__ u16 BTh_t[4096], BTl_t[4096], Xh_t[4096], Xl_t[4096];
  __shared__ float wall[256];
  const int bc = blockIdx.x;
  const int hh = blockIdx.y;
  const int t  = threadIdx.x;
  const int lane = t & 63, w = t >> 6;
  const int mlo = lane & 15, gg = lane >> 4;
  const int r = t >> 2, q = (t & 3) * 16;
  const size_t base = (size_t)bc * 256;
  const float last = dAcs[(base + 255) * NH + hh];
  wall[t] = expf(last - dAcs[(base + t) * NH + hh]) * dt[(base + t) * NH + hh];
  f32x4 acc[4];
#pragma unroll
  for (int i = 0; i < 4; ++i) acc[i] = (f32x4){0.f, 0.f, 0.f, 0.f};
  for (int jt = 0; jt < 4; ++jt) {
    const int j0 = jt * 64;
    __syncthreads();
    {
      const float* xp = &x[(size_t)(base + j0 + r) * DI + hh * HD + q];
#pragma unroll
      for (int k = 0; k < 4; ++k) {
        float4 v = *(const float4*)(xp + k * 4);
        xf[r * 65 + q + k * 4 + 0] = v.x; xf[r * 65 + q + k * 4 + 1] = v.y;
        xf[r * 65 + q + k * 4 + 2] = v.z; xf[r * 65 + q + k * 4 + 3] = v.w;
      }
      const u16* bhp = &Bh[(size_t)(base + j0 + r) * DS + q];
      const u16* blp = &Bl[(size_t)(base + j0 + r) * DS + q];
      U4 H0, H1, L0, L1;
      H0.v = *(const uint4*)bhp; H1.v = *(const uint4*)(bhp + 8);
      L0.v = *(const uint4*)blp; L1.v = *(const uint4*)(blp + 8);
#pragma unroll
      for (int k = 0; k < 8; ++k) {
        bpack[r * 65 + q + k]     = ((u32)H0.s[k] << 16) | L0.s[k];
        bpack[r * 65 + q + 8 + k] = ((u32)H1.s[k] << 16) | L1.s[k];
      }
    }
    __syncthreads();
#pragma unroll
    for (int c = 0; c < 2; ++c) {
      U4 BH, BL, XH, XL;
#pragma unroll
      for (int jj = 0; jj < 8; ++jj) {
        int j = q + c * 8 + jj;
        u32 vv = bpack[j * 65 + r];
        BH.s[jj] = (u16)(vv >> 16); BL.s[jj] = (u16)(vv & 0xffff);
        float xv = xf[j * 65 + r] * wall[j0 + j];
        u16 h, l; bsplit(xv, h, l);
        XH.s[jj] = h; XL.s[jj] = l;
      }
      int slot = (q >> 3) + c;
      *(uint4*)((char*)BTh_t + SWZ(r, slot)) = BH.v;
      *(uint4*)((char*)BTl_t + SWZ(r, slot)) = BL.v;
      *(uint4*)((char*)Xh_t  + SWZ(r, slot)) = XH.v;
      *(uint4*)((char*)Xl_t  + SWZ(r, slot)) = XL.v;
    }
    __syncthreads();
#pragma unroll
    for (int s = 0; s < 2; ++s) {
      bf16x8 fah = *(const bf16x8*)((const char*)Xh_t + SWZ(w * 16 + mlo, s * 4 + gg));
      bf16x8 fal = *(const bf16x8*)((const char*)Xl_t + SWZ(w * 16 + mlo, s * 4 + gg));
#pragma unroll
      for (int nf = 0; nf < 4; ++nf) {
        bf16x8 fbh = *(const bf16x8*)((const char*)BTh_t + SWZ(nf * 16 + mlo, s * 4 + gg));
        bf16x8 fbl = *(const bf16x8*)((const char*)BTl_t + SWZ(nf * 16 + mlo, s * 4 + gg));
        acc[nf] = __builtin_amdgcn_mfma_f32_16x16x32_bf16(fah, fbh, acc[nf], 0, 0, 0);
        acc[nf] = __builtin_amdgcn_mfma_f32_16x16x32_bf16(fah, fbl, acc[nf], 0, 0, 0);
        acc[nf] = __builtin_amdgcn_mfma_f32_16x16x32_bf16(fal, fbh, acc[nf], 0, 0, 0);
      }
    }
  }
  const size_t sb = ((size_t)(bc * NH + hh)) << 12;
#pragma unroll
  for (int nf = 0; nf < 4; ++nf)
#pragma unroll
    for (int reg = 0; reg < 4; ++reg) {
      int p = w * 16 + (lane >> 4) * 4 + reg;
      int n = nf * 16 + mlo;
      states[sb + (size_t)p * 64 + n] = acc[nf][reg];
    }
}

// ---------------- K6: inter-chunk scan ----------------
__global__ __launch_bounds__(256) void k_scanc(
    const float* __restrict__ states, const float* __restrict__ cdecay,
    float* __restrict__ prev)
{
  int tid = blockIdx.x * 256 + threadIdx.x;
  int pn  = tid & 4095;
  int rem = tid >> 12;
  int hh  = rem % NH;
  int b   = rem / NH;
  float carry = 0.f;
#pragma unroll
  for (int c = 0; c < 4; ++c) {
    size_t idx = ((size_t)((b * 4 + c) * NH + hh) << 12) + pn;
    prev[idx] = carry;
    carry = carry * cdecay[(b * 4 + c) * NH + hh] + states[idx];
  }
}

// ---------------- K7: y = intra + inter + D*x via MFMA (G recomputed on the fly) ----------------
__global__ __launch_bounds__(256) void k_y(
    const float* __restrict__ x,
    const u16* __restrict__ Chg, const u16* __restrict__ Clg,
    const u16* __restrict__ Bhg, const u16* __restrict__ Blg,
    const float* __restrict__ dtp, const float* __restrict__ dAcs,
    const float* __restrict__ prev, const float* __restrict__ Dp,
    float* __restrict__ y)
{
  __shared__ u16 Ch_t[4096], Cl_t[4096];
  __shared__ u16 Ph_t[4096], Pl_t[4096];
  __shared__ u16 Xh_t[4096], Xl_t[4096];
  __shared__ u16 att_t[4096];
  __shared__ float xf[64 * 65];
  __shared__ float dAi_s[64], ei_s[64], dAj_s[64], dtj_s[64];
  const int bc = blockIdx.x;
  const int hh = blockIdx.y;
  const int it = blockIdx.z;
  const int t  = threadIdx.x;
  const int lane = t & 63, w = t >> 6;
  const int mlo = lane & 15, gg = lane >> 4;
  const int r = t >> 2, q = (t & 3) * 16;
  const int slot0 = q >> 3;
  const size_t base = (size_t)bc * 256;
  const int i0 = it * 64;
  {
    const u16* ch = &Chg[(size_t)(base + i0 + r) * DS + q];
    const u16* cl = &Clg[(size_t)(base + i0 + r) * DS + q];
    *(uint4*)((char*)Ch_t + SWZ(r, slot0))     = *(const uint4*)ch;
    *(uint4*)((char*)Ch_t + SWZ(r, slot0 + 1)) = *(const uint4*)(ch + 8);
    *(uint4*)((char*)Cl_t + SWZ(r, slot0))     = *(const uint4*)cl;
    *(uint4*)((char*)Cl_t + SWZ(r, slot0 + 1)) = *(const uint4*)(cl + 8);
  }
  {
    const float* pp = &prev[(((size_t)(bc * NH + hh)) << 12) + (size_t)r * 64 + q];
    U4 H0, H1, L0, L1;
#pragma unroll
    for (int k = 0; k < 16; ++k) {
      float v = pp[k];
      u16 h, l; bsplit(v, h, l);
      if (k < 8) { H0.s[k] = h; L0.s[k] = l; } else { H1.s[k - 8] = h; L1.s[k - 8] = l; }
    }
    *(uint4*)((char*)Ph_t + SWZ(r, slot0))     = H0.v;
    *(uint4*)((char*)Ph_t + SWZ(r, slot0 + 1)) = H1.v;
    *(uint4*)((char*)Pl_t + SWZ(r, slot0))     = L0.v;
    *(uint4*)((char*)Pl_t + SWZ(r, slot0 + 1)) = L1.v;
  }
  if (t < 64) {
    float da = dAcs[(base + i0 + t) * NH + hh];
    dAi_s[t] = da;
    ei_s[t] = expf(da);
  }
  __syncthreads();
  bf16x8 fch[2], fcl[2];
#pragma unroll
  for (int s = 0; s < 2; ++s) {
    fch[s] = *(const bf16x8*)((const char*)Ch_t + SWZ(w * 16 + mlo, s * 4 + gg));
    fcl[s] = *(const bf16x8*)((const char*)Cl_t + SWZ(w * 16 + mlo, s * 4 + gg));
  }
  f32x4 accy[4];
#pragma unroll
  for (int i = 0; i < 4; ++i) accy[i] = (f32x4){0.f, 0.f, 0.f, 0.f};
#pragma unroll
  for (int s = 0; s < 2; ++s)
#pragma unroll
    for (int pf = 0; pf < 4; ++pf) {
      bf16x8 fph = *(const bf16x8*)((const char*)Ph_t + SWZ(pf * 16 + mlo, s * 4 + gg));
      bf16x8 fpl = *(const bf16x8*)((const char*)Pl_t + SWZ(pf * 16 + mlo, s * 4 + gg));
      accy[pf] = __builtin_amdgcn_mfma_f32_16x16x32_bf16(fch[s], fph, accy[pf], 0, 0, 0);
      accy[pf] = __builtin_amdgcn_mfma_f32_16x16x32_bf16(fch[s], fpl, accy[pf], 0, 0, 0);
      accy[pf] = __builtin_amdgcn_mfma_f32_16x16x32_bf16(fcl[s], fph, accy[pf], 0, 0, 0);
    }
#pragma unroll
  for (int pf = 0; pf < 4; ++pf)
#pragma unroll
    for (int reg = 0; reg < 4; ++reg)
      accy[pf][reg] *= ei_s[w * 16 + (lane >> 4) * 4 + reg];

  for (int jt = 0; jt <= it; ++jt) {
    const int j0j = jt * 64;
    __syncthreads();
    {
      const u16* bh = &Bhg[(size_t)(base + j0j + r) * DS + q];
      const u16* bl = &Blg[(size_t)(base + j0j + r) * DS + q];
      *(uint4*)((char*)Ph_t + SWZ(r, slot0))     = *(const uint4*)bh;
      *(uint4*)((char*)Ph_t + SWZ(r, slot0 + 1)) = *(const uint4*)(bh + 8);
      *(uint4*)((char*)Pl_t + SWZ(r, slot0))     = *(const uint4*)bl;
      *(uint4*)((char*)Pl_t + SWZ(r, slot0 + 1)) = *(const uint4*)(bl + 8);
      const float* xp = &x[(size_t)(base + j0j + r) * DI + hh * HD + q];
#pragma unroll
      for (int k = 0; k < 4; ++k) {
        float4 v = *(const float4*)(xp + k * 4);
        xf[r * 65 + q + k * 4 + 0] = v.x; xf[r * 65 + q + k * 4 + 1] = v.y;
        xf[r * 65 + q + k * 4 + 2] = v.z; xf[r * 65 + q + k * 4 + 3] = v.w;
      }
    }
    if (t < 64) {
      dAj_s[t] = dAcs[(base + j0j + t) * NH + hh];
      dtj_s[t] = dtp[(base + j0j + t) * NH + hh];
    }
    __syncthreads();
    f32x4 g[4];
#pragma unroll
    for (int i = 0; i < 4; ++i) g[i] = (f32x4){0.f, 0.f, 0.f, 0.f};
#pragma unroll
    for (int s = 0; s < 2; ++s)
#pragma unroll
      for (int jf = 0; jf < 4; ++jf) {
        bf16x8 fbh = *(const bf16x8*)((const char*)Ph_t + SWZ(jf * 16 + mlo, s * 4 + gg));
        bf16x8 fbl = *(const bf16x8*)((const char*)Pl_t + SWZ(jf * 16 + mlo, s * 4 + gg));
        g[jf] = __builtin_amdgcn_mfma_f32_16x16x32_bf16(fch[s], fbh, g[jf], 0, 0, 0);
        g[jf] = __builtin_amdgcn_mfma_f32_16x16x32_bf16(fch[s], fbl, g[jf], 0, 0, 0);
        g[jf] = __builtin_amdgcn_mfma_f32_16x16x32_bf16(fcl[s], fbh, g[jf], 0, 0, 0);
      }
#pragma unroll
    for (int c = 0; c < 2; ++c) {
      U4 XH, XL;
#pragma unroll
      for (int jj = 0; jj < 8; ++jj) {
        int j = q + c * 8 + jj;
        u16 h, l; bsplit(xf[j * 65 + r], h, l);
        XH.s[jj] = h; XL.s[jj] = l;
      }
      *(uint4*)((char*)Xh_t + SWZ(r, slot0 + c)) = XH.v;
      *(uint4*)((char*)Xl_t + SWZ(r, slot0 + c)) = XL.v;
    }
#pragma unroll
    for (int jf = 0; jf < 4; ++jf)
#pragma unroll
      for (int reg = 0; reg < 4; ++reg) {
        int il = w * 16 + (lane >> 4) * 4 + reg;
        int jl = jf * 16 + mlo;
        bool ok = (jt < it) || (jl <= il);
        float av = ok ? g[jf][reg] * expf(dAi_s[il] - dAj_s[jl]) * dtj_s[jl] : 0.f;
        *(u16*)((char*)att_t + SWZ(il, jl >> 3) + (jl & 7) * 2) = f2b(av);
      }
    __syncthreads();
#pragma unroll
    for (int s = 0; s < 2; ++s) {
      bf16x8 fa = *(const bf16x8*)((const char*)att_t + SWZ(w * 16 + mlo, s * 4 + gg));
#pragma unroll
      for (int pf = 0; pf < 4; ++pf) {
        bf16x8 fxh = *(const bf16x8*)((const char*)Xh_t + SWZ(pf * 16 + mlo, s * 4 + gg));
        bf16x8 fxl = *(const bf16x8*)((const char*)Xl_t + SWZ(pf * 16 + mlo, s * 4 + gg));
        accy[pf] = __builtin_amdgcn_mfma_f32_16x16x32_bf16(fa, fxh, accy[pf], 0, 0, 0);
        accy[pf] = __builtin_amdgcn_mfma_f32_16x16x32_bf16(fa, fxl, accy[pf], 0, 0, 0);
      }
    }
  }
  const float Dh = Dp[hh];
#pragma unroll
  for (int pf = 0; pf < 4; ++pf)
#pragma unroll
    for (int reg = 0; reg < 4; ++reg) {
      size_t row = base + i0 + w * 16 + (lane >> 4) * 4 + reg;
      int col = hh * HD + pf * 16 + mlo;
      y[row * DI + col] = accy[pf][reg] + Dh * x[row * DI + col];
    }
}

// ---------------- K8: LayerNorm * z -> bf16 hi/lo pair ----------------
__global__ __launch_bounds__(256) void k_norm(
    const float* __restrict__ z, const float* __restrict__ nw,
    const float* __restrict__ nb, const float* __restrict__ y,
    u16* __restrict__ yh, u16* __restrict__ yl)
{
  __shared__ float rs[4], rq[4];
  const size_t row = blockIdx.x;
  const int t = threadIdx.x;
  float v[3];
  float s = 0.f, sq = 0.f;
#pragma unroll
  for (int r = 0; r < 3; ++r) {
    v[r] = y[row * DI + r * 256 + t];
    s += v[r];
    sq = fmaf(v[r], v[r], sq);
  }
#pragma unroll
  for (int off = 32; off > 0; off >>= 1) {
    s  += __shfl_down(s, off, 64);
    sq += __shfl_down(sq, off, 64);
  }
  const int wid = t >> 6, lane = t & 63;
  if (lane == 0) { rs[wid] = s; rq[wid] = sq; }
  __syncthreads();
  if (t == 0) {
    rs[0] = rs[0] + rs[1] + rs[2] + rs[3];
    rq[0] = rq[0] + rq[1] + rq[2] + rq[3];
  }
  __syncthreads();
  const float mu   = rs[0] * (1.f / DI);
  const float var  = rq[0] * (1.f / DI) - mu * mu;
  const float rstd = 1.f / sqrtf(var + EPS_);
#pragma unroll
  for (int r = 0; r < 3; ++r) {
    int d = r * 256 + t;
    float o = (v[r] - mu) * rstd * nw[d] + nb[d];
    float p = o * z[row * DI + d];
    u16 h, l;
    bsplit(p, h, l);
    yh[row * DI + d] = h;
    yl[row * DI + d] = l;
  }
}

extern "C" void kernel_launch(void* const* d_in, const int* in_sizes, int n_in,
                              void* d_out, int out_size, void* d_ws, size_t ws_size,
                              hipStream_t stream)
{
  const float* u    = (const float*)d_in[0];
  const float* ipw  = (const float*)d_in[1];
  const float* cw   = (const float*)d_in[2];
  const float* cb   = (const float*)d_in[3];
  const float* dtb  = (const float*)d_in[4];
  const float* Alog = (const float*)d_in[5];
  const float* Dp   = (const float*)d_in[6];
  const float* nw   = (const float*)d_in[7];
  const float* nb   = (const float*)d_in[8];
  const float* opw  = (const float*)d_in[9];
  float* out = (float*)d_out;

  float* ws = (float*)d_ws;
  size_t off = 0;
  float* z_buf   = ws + off; off += (size_t)B_ * L_ * DI;
  float* xBC_buf = ws + off; off += (size_t)B_ * L_ * CONVD;
  float* y_buf   = xBC_buf;                       // alias: xBC dead after conv
  float* dt_buf  = ws + off; off += (size_t)B_ * L_ * NH;
  float* x_buf   = ws + off; off += (size_t)B_ * L_ * DI;
  u16*   Bh_buf  = (u16*)(ws + off); off += (size_t)B_ * L_ * DS / 2;
  u16*   Bl_buf  = (u16*)(ws + off); off += (size_t)B_ * L_ * DS / 2;
  u16*   Ch_buf  = (u16*)(ws + off); off += (size_t)B_ * L_ * DS / 2;
  u16*   Cl_buf  = (u16*)(ws + off); off += (size_t)B_ * L_ * DS / 2;
  float* dAcs    = ws + off; off += (size_t)B_ * L_ * NH;
  float* cdec    = ws + off; off += (size_t)B_ * NCH * NH;
  float* st_buf  = ws + off; off += (size_t)B_ * NCH * NH * HD * DS;
  float* pv_buf  = ws + off; off += (size_t)B_ * NCH * NH * HD * DS;
  u16*   Woh     = (u16*)(ws + off); off += (size_t)DM * DI / 2;
  u16*   Wol     = (u16*)(ws + off); off += (size_t)DM * DI / 2;

  u16* Ah = (u16*)x_buf;
  u16* Al = Ah + (size_t)B_ * L_ * DM;
  u16* Wh = Al + (size_t)B_ * L_ * DM;
  u16* Wl = Wh + (size_t)NP1 * DM;
  u16* yh = (u16*)x_buf;
  u16* yl = yh + (size_t)B_ * L_ * DI;

  hipLaunchKernelGGL(k_cvtA, dim3(8, 12, 16), dim3(256), 0, stream, u, Ah, Al);
  hipLaunchKernelGGL(k_cvtW, dim3((NP1 * DM / 4 + 255) / 256), dim3(256), 0, stream,
                     ipw, Wh, Wl, DIP, DM, NP1 * DM / 4);
  hipLaunchKernelGGL(k_cvtW, dim3((DM * DI / 4 + 255) / 256), dim3(256), 0, stream,
                     opw, Woh, Wol, DM, DI, DM * DI / 4);
  hipLaunchKernelGGL(k_gemm1, dim3(128, 14), dim3(256), 0, stream,
                     Ah, Al, Wh, Wl, dtb, z_buf, xBC_buf, dt_buf);
  hipLaunchKernelGGL(k_conv,   dim3(56, 2, 16), dim3(256), 0, stream,
                     xBC_buf, cw, cb, x_buf, Bh_buf, Bl_buf, Ch_buf, Cl_buf);
  hipLaunchKernelGGL(k_dtcum,  dim3(64, 12), dim3(256), 0, stream, dt_buf, Alog, dAcs, cdec);
  hipLaunchKernelGGL(k_states, dim3(64, 12), dim3(256), 0, stream,
                     x_buf, Bh_buf, Bl_buf, dt_buf, dAcs, st_buf);
  hipLaunchKernelGGL(k_scanc,  dim3(3072), dim3(256), 0, stream, st_buf, cdec, pv_buf);
  hipLaunchKernelGGL(k_y,      dim3(64, 12, 4), dim3(256), 0, stream,
                     x_buf, Ch_buf, Cl_buf, Bh_buf, Bl_buf, dt_buf, dAcs, pv_buf, Dp, y_buf);
  hipLaunchKernelGGL(k_norm,   dim3(16384), dim3(256), 0, stream, z_buf, nw, nb, y_buf, yh, yl);
  hipLaunchKernelGGL(k_gemm2,  dim3(128, 3), dim3(256), 0, stream, yh, yl, Woh, Wol, out);
}

// Round 6
// 295.256 us; speedup vs baseline: 3.4286x; 1.0557x over previous
//
#include <hip/hip_runtime.h>
#include <hip/hip_bf16.h>

#define B_    16
#define L_    1024
#define DM    384
#define DIP   1676
#define NIP   1664
#define DI    768
#define CONVD 896
#define NH    12
#define HD    64
#define DS    64
#define NCH   4
#define CH    256
#define EPS_  1e-5f

typedef unsigned short u16;
typedef unsigned int   u32;
typedef __attribute__((ext_vector_type(8))) short bf16x8;
typedef __attribute__((ext_vector_type(8))) _Float16 f16x8;
typedef __attribute__((ext_vector_type(4))) float f32x4;

union U4 { uint4 v; u16 s[8]; };

// byte offset of 16B slot `slot` in row `row` of a [64][64]-16bit LDS tile (128B rows, XOR swizzle)
#define SWZ(row, slot) (((row) << 7) + ((((slot) ^ ((row) & 7)) & 7) << 4))

// ---- bf16 split helpers (kept for out_proj path) ----
__device__ __forceinline__ u16 f2b(float v) {
  u32 u = __float_as_uint(v);
  u32 r = (u + 0x7FFFu + ((u >> 16) & 1u)) >> 16;
  return (u16)r;
}
__device__ __forceinline__ float b2f(u16 h) { return __uint_as_float(((u32)h) << 16); }
__device__ __forceinline__ void bsplit(float v, u16& h, u16& l) {
  u16 hh = f2b(v);
  l = f2b(v - b2f(hh));
  h = hh;
}
// ---- fp16 split helpers ----
__device__ __forceinline__ u16 f2h(float v) { return __builtin_bit_cast(u16, (_Float16)v); }
__device__ __forceinline__ void hsplit(float v, u16& h, u16& l) {
  _Float16 hh = (_Float16)v;
  _Float16 ll = (_Float16)(v - (float)hh);
  h = __builtin_bit_cast(u16, hh);
  l = __builtin_bit_cast(u16, ll);
}

// ---------------- converters ----------------
// u[b,k,l] -> fp16 hi/lo pair, transposed to [m][k]
__global__ __launch_bounds__(256) void k_cvtA(const float* __restrict__ u,
                                              u16* __restrict__ Ah, u16* __restrict__ Al)
{
  __shared__ float Ls[32][129];
  const int t  = threadIdx.x;
  const int l0 = blockIdx.x * 128;
  const int k0 = blockIdx.y * 32;
  const int b  = blockIdx.z;
#pragma unroll
  for (int r = 0; r < 4; ++r) {
    int idx = r * 256 + t;
    int kk = idx >> 5, q = idx & 31;
    float4 v = *(const float4*)&u[((size_t)(b * DM + k0 + kk)) * L_ + l0 + q * 4];
    Ls[kk][q * 4 + 0] = v.x; Ls[kk][q * 4 + 1] = v.y;
    Ls[kk][q * 4 + 2] = v.z; Ls[kk][q * 4 + 3] = v.w;
  }
  __syncthreads();
#pragma unroll
  for (int it = 0; it < 2; ++it) {
    int task = it * 256 + t;
    int l = task >> 2, kq = (task & 3) * 8;
    u32 hw[4], lw[4];
#pragma unroll
    for (int j = 0; j < 4; ++j) {
      u16 h0, l0v, h1, l1v;
      hsplit(Ls[kq + 2 * j + 0][l], h0, l0v);
      hsplit(Ls[kq + 2 * j + 1][l], h1, l1v);
      hw[j] = (u32)h0 | ((u32)h1 << 16);
      lw[j] = (u32)l0v | ((u32)l1v << 16);
    }
    size_t off = ((size_t)(b * L_ + l0 + l)) * DM + k0 + kq;
    *(uint4*)&Ah[off] = make_uint4(hw[0], hw[1], hw[2], hw[3]);
    *(uint4*)&Al[off] = make_uint4(lw[0], lw[1], lw[2], lw[3]);
  }
}

// in_proj weights rows [0,1664) -> single fp16
__global__ __launch_bounds__(256) void k_cvtWh(const float* __restrict__ W,
                                               u16* __restrict__ Wh, int total4)
{
  int i = blockIdx.x * 256 + threadIdx.x;
  if (i >= total4) return;
  int e = i * 4;
  float4 v = *(const float4*)&W[e];
  u16 h[4] = {f2h(v.x), f2h(v.y), f2h(v.z), f2h(v.w)};
  *(uint2*)&Wh[e] = make_uint2((u32)h[0] | ((u32)h[1] << 16), (u32)h[2] | ((u32)h[3] << 16));
}

// out_proj weights -> bf16 hi/lo pair (unchanged path)
__global__ __launch_bounds__(256) void k_cvtW(const float* __restrict__ W,
    u16* __restrict__ Wh, u16* __restrict__ Wl, int nsrc, int K, int total4)
{
  int i = blockIdx.x * 256 + threadIdx.x;
  if (i >= total4) return;
  int e = i * 4;
  int row = e / K;
  float4 v = make_float4(0.f, 0.f, 0.f, 0.f);
  if (row < nsrc) v = *(const float4*)&W[e];
  u16 h[4], l[4];
  bsplit(v.x, h[0], l[0]); bsplit(v.y, h[1], l[1]);
  bsplit(v.z, h[2], l[2]); bsplit(v.w, h[3], l[3]);
  *(uint2*)&Wh[e] = make_uint2((u32)h[0] | ((u32)h[1] << 16), (u32)h[2] | ((u32)h[3] << 16));
  *(uint2*)&Wl[e] = make_uint2((u32)l[0] | ((u32)l[1] << 16), (u32)l[2] | ((u32)l[3] << 16));
}

// ---------------- K_dtp: dt logits from u (fp32) + softplus + chunk cumsum ----------------
__global__ __launch_bounds__(256) void k_dtp(
    const float* __restrict__ u, const float* __restrict__ ipw,
    const float* __restrict__ dtb, const float* __restrict__ A_log,
    float* __restrict__ dt, float* __restrict__ dAcs, float* __restrict__ cdecay)
{
  __shared__ float Ls[64][256];
  __shared__ float wdt[NH * DM];
  __shared__ float ws4[4];
  const int bc = blockIdx.x;            // b*4 + c
  const int b  = bc >> 2, l0 = (bc & 3) * 256;
  const int t  = threadIdx.x;
  const int lane = t & 63, w = t >> 6;
#pragma unroll
  for (int i = 0; i < 18; ++i) wdt[i * 256 + t] = ipw[(size_t)NIP * DM + i * 256 + t];
  float acc[NH] = {};
  for (int k0 = 0; k0 < DM; k0 += 64) {
    __syncthreads();
#pragma unroll
    for (int it = 0; it < 16; ++it) {
      int idx = it * 256 + t;
      int kk = idx >> 6, q4 = (idx & 63) * 4;
      *(float4*)&Ls[kk][q4] = *(const float4*)&u[((size_t)(b * DM + k0 + kk)) * L_ + l0 + q4];
    }
    __syncthreads();
    for (int k = 0; k < 64; ++k) {
      float uv = Ls[k][t];
#pragma unroll
      for (int h = 0; h < NH; ++h)
        acc[h] = fmaf(uv, wdt[h * DM + k0 + k], acc[h]);
    }
  }
  const size_t row = (size_t)bc * 256 + t;
#pragma unroll
  for (int h = 0; h < NH; ++h) {
    float logit = acc[h] + dtb[h];
    float dtv = (logit > 20.f) ? logit : log1pf(expf(logit));
    dt[row * NH + h] = dtv;
    float xv = dtv * (-expf(A_log[h]));
#pragma unroll
    for (int off = 1; off < 64; off <<= 1) {
      float y = __shfl_up(xv, off, 64);
      if (lane >= off) xv += y;
    }
    __syncthreads();
    if (lane == 63) ws4[w] = xv;
    __syncthreads();
    float add = 0.f;
#pragma unroll
    for (int i = 0; i < 4; ++i) if (i < w) add += ws4[i];
    xv += add;
    dAcs[row * NH + h] = xv;
    if (t == 255) cdecay[bc * NH + h] = expf(xv);
  }
}

// 3-stream staging (A-hi, A-lo, W) of one 128x32 u16 K-tile set
#define STAGE3(bufbase, k0) do {                                                                \
  _Pragma("unroll")                                                                             \
  for (int i_ = 0; i_ < 2; ++i_) {                                                              \
    int S_ = i_ * 256 + t;                                                                      \
    int m_ = S_ >> 2;                                                                           \
    int g_ = (S_ ^ (m_ >> 1)) & 3;                                                              \
    size_t goff_ = (size_t)m_ * DM + (k0) + g_ * 8;                                             \
    __builtin_amdgcn_global_load_lds((const __attribute__((address_space(1))) u32*)(g0 + goff_),\
        (__attribute__((address_space(3))) u32*)(lds + (bufbase) + S_ * 8), 16, 0, 0);          \
    __builtin_amdgcn_global_load_lds((const __attribute__((address_space(1))) u32*)(g1 + goff_),\
        (__attribute__((address_space(3))) u32*)(lds + (bufbase) + 4096 + S_ * 8), 16, 0, 0);   \
    __builtin_amdgcn_global_load_lds((const __attribute__((address_space(1))) u32*)(g2 + goff_),\
        (__attribute__((address_space(3))) u32*)(lds + (bufbase) + 8192 + S_ * 8), 16, 0, 0);   \
  }                                                                                             \
} while (0)

// ---------------- fp16x2 MFMA GEMM: in_proj (N=1664, no dt) ----------------
__global__ __launch_bounds__(256) void k_gemm1(
    const u16* __restrict__ Ah, const u16* __restrict__ Al,
    const u16* __restrict__ Wh,
    float* __restrict__ z, float* __restrict__ xBC)
{
  __shared__ u16 lds[24576];   // 2 x 24KB buffers (3 streams x 8KB)
  const int t = threadIdx.x;
  const int lane = t & 63, wid = t >> 6;
  const int wr = wid >> 1, wc = wid & 1;
  const int gg = lane >> 4, mlo = lane & 15;
  const int m0 = blockIdx.x * 128, n0 = blockIdx.y * 128;
  f32x4 acc[4][4];
#pragma unroll
  for (int i = 0; i < 4; ++i)
#pragma unroll
    for (int j = 0; j < 4; ++j) acc[i][j] = (f32x4){0.f, 0.f, 0.f, 0.f};
  const u16* g0 = Ah + (size_t)m0 * DM;
  const u16* g1 = Al + (size_t)m0 * DM;
  const u16* g2 = Wh + (size_t)n0 * DM;
  STAGE3(0, 0);
  __syncthreads();
  int cur = 0;
  for (int kt = 0; kt < DM / 32; ++kt) {
    if (kt + 1 < DM / 32) STAGE3((cur ^ 1) * 12288, (kt + 1) * 32);
    const char* ldsb = (const char*)lds + cur * 24576;
    f16x8 fa[4], fal[4], fb[4];
#pragma unroll
    for (int mf = 0; mf < 4; ++mf) {
      int m = wr * 64 + mf * 16 + mlo;
      int off = m * 64 + (((gg ^ (m >> 1)) & 3) << 4);
      fa[mf]  = *(const f16x8*)(ldsb + off);
      fal[mf] = *(const f16x8*)(ldsb + 8192 + off);
    }
#pragma unroll
    for (int nf = 0; nf < 4; ++nf) {
      int n = wc * 64 + nf * 16 + mlo;
      int off = n * 64 + (((gg ^ (n >> 1)) & 3) << 4);
      fb[nf]  = *(const f16x8*)(ldsb + 16384 + off);
    }
#pragma unroll
    for (int mf = 0; mf < 4; ++mf)
#pragma unroll
      for (int nf = 0; nf < 4; ++nf) {
        acc[mf][nf] = __builtin_amdgcn_mfma_f32_16x16x32_f16(fa[mf],  fb[nf], acc[mf][nf], 0, 0, 0);
        acc[mf][nf] = __builtin_amdgcn_mfma_f32_16x16x32_f16(fal[mf], fb[nf], acc[mf][nf], 0, 0, 0);
      }
    __syncthreads();
    cur ^= 1;
  }
  const int rb = m0 + wr * 64 + (lane >> 4) * 4;
  const int cb = n0 + wc * 64 + mlo;
#pragma unroll
  for (int mf = 0; mf < 4; ++mf)
#pragma unroll
    for (int nf = 0; nf < 4; ++nf) {
      int col = cb + nf * 16;
#pragma unroll
      for (int r = 0; r < 4; ++r) {
        int row = rb + mf * 16 + r;
        float v = acc[mf][nf][r];
        if (col < DI) z[(size_t)row * DI + col] = v;
        else xBC[(size_t)row * CONVD + (col - DI)] = v;
      }
    }
}

// 4-stream bf16 staging for gemm2 (unchanged)
#define STAGE4(bufbase, k0, KS) do {                                                            \
  _Pragma("unroll")                                                                             \
  for (int i_ = 0; i_ < 2; ++i_) {                                                              \
    int S_ = i_ * 256 + t;                                                                      \
    int m_ = S_ >> 2;                                                                           \
    int g_ = (S_ ^ (m_ >> 1)) & 3;                                                              \
    size_t goff_ = (size_t)m_ * (KS) + (k0) + g_ * 8;                                           \
    __builtin_amdgcn_global_load_lds((const __attribute__((address_space(1))) u32*)(g0 + goff_),\
        (__attribute__((address_space(3))) u32*)(lds + (bufbase) + S_ * 8), 16, 0, 0);          \
    __builtin_amdgcn_global_load_lds((const __attribute__((address_space(1))) u32*)(g1 + goff_),\
        (__attribute__((address_space(3))) u32*)(lds + (bufbase) + 4096 + S_ * 8), 16, 0, 0);   \
    __builtin_amdgcn_global_load_lds((const __attribute__((address_space(1))) u32*)(g2 + goff_),\
        (__attribute__((address_space(3))) u32*)(lds + (bufbase) + 8192 + S_ * 8), 16, 0, 0);   \
    __builtin_amdgcn_global_load_lds((const __attribute__((address_space(1))) u32*)(g3 + goff_),\
        (__attribute__((address_space(3))) u32*)(lds + (bufbase) + 12288 + S_ * 8), 16, 0, 0);  \
  }                                                                                             \
} while (0)

// ---------------- bf16x3 MFMA GEMM: out_proj ----------------
__global__ __launch_bounds__(256) void k_gemm2(
    const u16* __restrict__ Ah, const u16* __restrict__ Al,
    const u16* __restrict__ Bh, const u16* __restrict__ Bl,
    float* __restrict__ out)
{
  __shared__ u16 lds[32768];
  const int t = threadIdx.x;
  const int lane = t & 63, wid = t >> 6;
  const int wr = wid >> 1, wc = wid & 1;
  const int gg = lane >> 4, mlo = lane & 15;
  const int m0 = blockIdx.x * 128, n0 = blockIdx.y * 128;
  f32x4 acc[4][4];
#pragma unroll
  for (int i = 0; i < 4; ++i)
#pragma unroll
    for (int j = 0; j < 4; ++j) acc[i][j] = (f32x4){0.f, 0.f, 0.f, 0.f};
  const u16* g0 = Ah + (size_t)m0 * DI;
  const u16* g1 = Al + (size_t)m0 * DI;
  const u16* g2 = Bh + (size_t)n0 * DI;
  const u16* g3 = Bl + (size_t)n0 * DI;
  STAGE4(0, 0, DI);
  __syncthreads();
  int cur = 0;
  for (int kt = 0; kt < DI / 32; ++kt) {
    if (kt + 1 < DI / 32) STAGE4((cur ^ 1) * 16384, (kt + 1) * 32, DI);
    const char* ldsb = (const char*)lds + cur * 32768;
    bf16x8 fa[4], fal[4], fb[4], fbl[4];
#pragma unroll
    for (int mf = 0; mf < 4; ++mf) {
      int m = wr * 64 + mf * 16 + mlo;
      int off = m * 64 + (((gg ^ (m >> 1)) & 3) << 4);
      fa[mf]  = *(const bf16x8*)(ldsb + off);
      fal[mf] = *(const bf16x8*)(ldsb + 8192 + off);
    }
#pragma unroll
    for (int nf = 0; nf < 4; ++nf) {
      int n = wc * 64 + nf * 16 + mlo;
      int off = n * 64 + (((gg ^ (n >> 1)) & 3) << 4);
      fb[nf]  = *(const bf16x8*)(ldsb + 16384 + off);
      fbl[nf] = *(const bf16x8*)(ldsb + 24576 + off);
    }
#pragma unroll
    for (int mf = 0; mf < 4; ++mf)
#pragma unroll
      for (int nf = 0; nf < 4; ++nf) {
        acc[mf][nf] = __builtin_amdgcn_mfma_f32_16x16x32_bf16(fa[mf],  fb[nf],  acc[mf][nf], 0, 0, 0);
        acc[mf][nf] = __builtin_amdgcn_mfma_f32_16x16x32_bf16(fa[mf],  fbl[nf], acc[mf][nf], 0, 0, 0);
        acc[mf][nf] = __builtin_amdgcn_mfma_f32_16x16x32_bf16(fal[mf], fb[nf],  acc[mf][nf], 0, 0, 0);
      }
    __syncthreads();
    cur ^= 1;
  }
  const int rb = m0 + wr * 64 + (lane >> 4) * 4;
  const int cb = n0 + wc * 64 + mlo;
#pragma unroll
  for (int mf = 0; mf < 4; ++mf)
#pragma unroll
    for (int nf = 0; nf < 4; ++nf) {
      int col = cb + nf * 16;
#pragma unroll
      for (int r = 0; r < 4; ++r) {
        int row = rb + mf * 16 + r;
        int b = row >> 10, l = row & 1023;
        out[((size_t)(b * DM + col)) * L_ + l] = acc[mf][nf][r];
      }
    }
}

// ---------------- K2: LDS-tiled depthwise conv; x fp32, B single fp16, C fp16 pair ----------------
#define CC 16
__global__ __launch_bounds__(256) void k_conv(
    const float* __restrict__ xBC, const float* __restrict__ cw,
    const float* __restrict__ cb,
    float* __restrict__ x,
    u16* __restrict__ Bh,
    u16* __restrict__ Chh, u16* __restrict__ Cll)
{
  __shared__ float Ls[18][32][CC];
  const int t  = threadIdx.x;
  const int c0 = blockIdx.x * CC;
  const int h0 = blockIdx.y * 16;
  const int b  = blockIdx.z;
#pragma unroll
  for (int k = 0; k < 9; ++k) {
    int f = k * 256 + t;
    int fc4 = f & 3, fw = (f >> 2) & 31, fr = f >> 7;
    int h = h0 + fr - 1;
    float4 v = make_float4(0.f, 0.f, 0.f, 0.f);
    if (h >= 0 && h < 32)
      v = *(const float4*)&xBC[((size_t)(b * 1024 + h * 32 + fw)) * CONVD + c0 + fc4 * 4];
    *(float4*)&Ls[fr][fw][fc4 * 4] = v;
  }
  const int c4 = t & 3;
  const int w  = (t >> 2) & 31;
  const int hb = t >> 7;
  float wt[4][9];
  float bias[4];
#pragma unroll
  for (int j = 0; j < 4; ++j) {
    int c = c0 + c4 * 4 + j;
    bias[j] = cb[c];
#pragma unroll
    for (int kb = 0; kb < 9; ++kb) wt[j][kb] = cw[c * 9 + kb];
  }
  __syncthreads();
#pragma unroll
  for (int k = 0; k < 8; ++k) {
    int h = hb * 8 + k;
    float acc[4] = {bias[0], bias[1], bias[2], bias[3]};
#pragma unroll
    for (int dh = 0; dh < 3; ++dh) {
#pragma unroll
      for (int dw = -1; dw <= 1; ++dw) {
        int ww = w + dw;
        if (ww < 0 || ww > 31) continue;
        const float* p = &Ls[h + dh][ww][c4 * 4];
        int kb = dh * 3 + (dw + 1);
#pragma unroll
        for (int j = 0; j < 4; ++j) acc[j] = fmaf(p[j], wt[j][kb], acc[j]);
      }
    }
    float s4[4];
#pragma unroll
    for (int j = 0; j < 4; ++j) { float v = acc[j]; s4[j] = v / (1.f + expf(-v)); }
    size_t row = (size_t)b * 1024 + (h0 + h) * 32 + w;
    int c = c0 + c4 * 4;
    if (c < DI) {
      *(float4*)&x[row * DI + c] = make_float4(s4[0], s4[1], s4[2], s4[3]);
    } else if (c < DI + DS) {
      u16 hv[4] = {f2h(s4[0]), f2h(s4[1]), f2h(s4[2]), f2h(s4[3])};
      *(uint2*)&Bh[row * DS + (c - DI)] =
          make_uint2((u32)hv[0] | ((u32)hv[1] << 16), (u32)hv[2] | ((u32)hv[3] << 16));
    } else {
      u16 hv[4], lv[4];
#pragma unroll
      for (int j = 0; j < 4; ++j) hsplit(s4[j], hv[j], lv[j]);
      *(uint2*)&Chh[row * DS + (c - DI - DS)] =
          make_uint2((u32)hv[0] | ((u32)hv[1] << 16), (u32)hv[2] | ((u32)hv[3] << 16));
      *(uint2*)&Cll[row * DS + (c - DI - DS)] =
          make_uint2((u32)lv[0] | ((u32)lv[1] << 16), (u32)lv[2] | ((u32)lv[3] << 16));
    }
  }
}

// ---------------- K5: chunk states via MFMA (fp16: X pair x B single = 2 MFMA) ----------------
__global__ __launch_bounds__(256) void k_states(
    const float* __restrict__ x,
    const u16* __restrict__ Bh,
    const float* __restrict__ dt, const float* __restrict__ dAcs,
    float* __restrict__ states)
{
  __shared__ float xf[64 * 65];
  __shared__ u32  bpack[64 * 65];
  __shared__ u16 BTh_t[4096], Xh_t[4096], Xl_t[4096];
  __shared__ float wall[256];
  const int bc = blockIdx.x;
  const int hh = blockIdx.y;
  const int t  = threadIdx.x;
  const int lane = t & 63, w = t >> 6;
  const int mlo = lane & 15, gg = lane >> 4;
  const int r = t >> 2, q = (t & 3) * 16;
  const size_t base = (size_t)bc * 256;
  const float last = dAcs[(base + 255) * NH + hh];
  wall[t] = expf(last - dAcs[(base + t) * NH + hh]) * dt[(base + t) * NH + hh];
  f32x4 acc[4];
#pragma unroll
  for (int i = 0; i < 4; ++i) acc[i] = (f32x4){0.f, 0.f, 0.f, 0.f};
  for (int jt = 0; jt < 4; ++jt) {
    const int j0 = jt * 64;
    __syncthreads();
    {
      const float* xp = &x[(size_t)(base + j0 + r) * DI + hh * HD + q];
#pragma unroll
      for (int k = 0; k < 4; ++k) {
        float4 v = *(const float4*)(xp + k * 4);
        xf[r * 65 + q + k * 4 + 0] = v.x; xf[r * 65 + q + k * 4 + 1] = v.y;
        xf[r * 65 + q + k * 4 + 2] = v.z; xf[r * 65 + q + k * 4 + 3] = v.w;
      }
      const u16* bhp = &Bh[(size_t)(base + j0 + r) * DS + q];
      U4 H0, H1;
      H0.v = *(const uint4*)bhp; H1.v = *(const uint4*)(bhp + 8);
#pragma unroll
      for (int k = 0; k < 8; ++k) {
        bpack[r * 65 + q + k]     = H0.s[k];
        bpack[r * 65 + q + 8 + k] = H1.s[k];
      }
    }
    __syncthreads();
#pragma unroll
    for (int c = 0; c < 2; ++c) {
      U4 BH, XH, XL;
#pragma unroll
      for (int jj = 0; jj < 8; ++jj) {
        int j = q + c * 8 + jj;
        BH.s[jj] = (u16)bpack[j * 65 + r];
        float xv = xf[j * 65 + r] * wall[j0 + j];
        u16 h, l; hsplit(xv, h, l);
        XH.s[jj] = h; XL.s[jj] = l;
      }
      int slot = (q >> 3) + c;
      *(uint4*)((char*)BTh_t + SWZ(r, slot)) = BH.v;
      *(uint4*)((char*)Xh_t  + SWZ(r, slot)) = XH.v;
      *(uint4*)((char*)Xl_t  + SWZ(r, slot)) = XL.v;
    }
    __syncthreads();
#pragma unroll
    for (int s = 0; s < 2; ++s) {
      f16x8 fah = *(const f16x8*)((const char*)Xh_t + SWZ(w * 16 + mlo, s * 4 + gg));
      f16x8 fal = *(const f16x8*)((const char*)Xl_t + SWZ(w * 16 + mlo, s * 4 + gg));
#pragma unroll
      for (int nf = 0; nf < 4; ++nf) {
        f16x8 fbh = *(const f16x8*)((const char*)BTh_t + SWZ(nf * 16 + mlo, s * 4 + gg));
        acc[nf] = __builtin_amdgcn_mfma_f32_16x16x32_f16(fah, fbh, acc[nf], 0, 0, 0);
        acc[nf] = __builtin_amdgcn_mfma_f32_16x16x32_f16(fal, fbh, acc[nf], 0, 0, 0);
      }
    }
  }
  const size_t sb = ((size_t)(bc * NH + hh)) << 12;
#pragma unroll
  for (int nf = 0; nf < 4; ++nf)
#pragma unroll
    for (int reg = 0; reg < 4; ++reg) {
      int p = w * 16 + (lane >> 4) * 4 + reg;
      int n = nf * 16 + mlo;
      states[sb + (size_t)p * 64 + n] = acc[nf][reg];
    }
}

// ---------------- K6: inter-chunk scan ----------------
__global__ __launch_bounds__(256) void k_scanc(
    const float* __restrict__ states, const float* __restrict__ cdecay,
    float* __restrict__ prev)
{
  int tid = blockIdx.x * 256 + threadIdx.x;
  int pn  = tid & 4095;
  int rem = tid >> 12;
  int hh  = rem % NH;
  int b   = rem / NH;
  float carry = 0.f;
#pragma unroll
  for (int c = 0; c < 4; ++c) {
    size_t idx = ((size_t)((b * 4 + c) * NH + hh) << 12) + pn;
    prev[idx] = carry;
    carry = carry * cdecay[(b * 4 + c) * NH + hh] + states[idx];
  }
}

// ---------------- K7: y via MFMA; C pair, B/prev/att single fp16, x pair ----------------
__global__ __launch_bounds__(256) void k_y(
    const float* __restrict__ x,
    const u16* __restrict__ Chg, const u16* __restrict__ Clg,
    const u16* __restrict__ Bhg,
    const float* __restrict__ dtp, const float* __restrict__ dAcs,
    const float* __restrict__ prev, const float* __restrict__ Dp,
    float* __restrict__ y)
{
  __shared__ u16 Ch_t[4096], Cl_t[4096];
  __shared__ u16 Pb_t[4096];              // prev tile, then B tiles
  __shared__ u16 Xh_t[4096], Xl_t[4096];
  __shared__ u16 att_t[4096];
  __shared__ float xf[64 * 65];
  __shared__ float dAi_s[64], ei_s[64], dAj_s[64], dtj_s[64];
  const int bc = blockIdx.x;
  const int hh = blockIdx.y;
  const int it = blockIdx.z;
  const int t  = threadIdx.x;
  const int lane = t & 63, w = t >> 6;
  const int mlo = lane & 15, gg = lane >> 4;
  const int r = t >> 2, q = (t & 3) * 16;
  const int slot0 = q >> 3;
  const size_t base = (size_t)bc * 256;
  const int i0 = it * 64;
  {
    const u16* ch = &Chg[(size_t)(base + i0 + r) * DS + q];
    const u16* cl = &Clg[(size_t)(base + i0 + r) * DS + q];
    *(uint4*)((char*)Ch_t + SWZ(r, slot0))     = *(const uint4*)ch;
    *(uint4*)((char*)Ch_t + SWZ(r, slot0 + 1)) = *(const uint4*)(ch + 8);
    *(uint4*)((char*)Cl_t + SWZ(r, slot0))     = *(const uint4*)cl;
    *(uint4*)((char*)Cl_t + SWZ(r, slot0 + 1)) = *(const uint4*)(cl + 8);
  }
  {
    const float* pp = &prev[(((size_t)(bc * NH + hh)) << 12) + (size_t)r * 64 + q];
    U4 H0, H1;
#pragma unroll
    for (int k = 0; k < 16; ++k) {
      u16 h = f2h(pp[k]);
      if (k < 8) H0.s[k] = h; else H1.s[k - 8] = h;
    }
    *(uint4*)((char*)Pb_t + SWZ(r, slot0))     = H0.v;
    *(uint4*)((char*)Pb_t + SWZ(r, slot0 + 1)) = H1.v;
  }
  if (t < 64) {
    float da = dAcs[(base + i0 + t) * NH + hh];
    dAi_s[t] = da;
    ei_s[t] = expf(da);
  }
  __syncthreads();
  f16x8 fch[2], fcl[2];
#pragma unroll
  for (int s = 0; s < 2; ++s) {
    fch[s] = *(const f16x8*)((const char*)Ch_t + SWZ(w * 16 + mlo, s * 4 + gg));
    fcl[s] = *(const f16x8*)((const char*)Cl_t + SWZ(w * 16 + mlo, s * 4 + gg));
  }
  f32x4 accy[4];
#pragma unroll
  for (int i = 0; i < 4; ++i) accy[i] = (f32x4){0.f, 0.f, 0.f, 0.f};
#pragma unroll
  for (int s = 0; s < 2; ++s)
#pragma unroll
    for (int pf = 0; pf < 4; ++pf) {
      f16x8 fph = *(const f16x8*)((const char*)Pb_t + SWZ(pf * 16 + mlo, s * 4 + gg));
      accy[pf] = __builtin_amdgcn_mfma_f32_16x16x32_f16(fch[s], fph, accy[pf], 0, 0, 0);
      accy[pf] = __builtin_amdgcn_mfma_f32_16x16x32_f16(fcl[s], fph, accy[pf], 0, 0, 0);
    }
#pragma unroll
  for (int pf = 0; pf < 4; ++pf)
#pragma unroll
    for (int reg = 0; reg < 4; ++reg)
      accy[pf][reg] *= ei_s[w * 16 + (lane >> 4) * 4 + reg];

  for (int jt = 0; jt <= it; ++jt) {
    const int j0j = jt * 64;
    __syncthreads();
    {
      const u16* bh = &Bhg[(size_t)(base + j0j + r) * DS + q];
      *(uint4*)((char*)Pb_t + SWZ(r, slot0))     = *(const uint4*)bh;
      *(uint4*)((char*)Pb_t + SWZ(r, slot0 + 1)) = *(const uint4*)(bh + 8);
      const float* xp = &x[(size_t)(base + j0j + r) * DI + hh * HD + q];
#pragma unroll
      for (int k = 0; k < 4; ++k) {
        float4 v = *(const float4*)(xp + k * 4);
        xf[r * 65 + q + k * 4 + 0] = v.x; xf[r * 65 + q + k * 4 + 1] = v.y;
        xf[r * 65 + q + k * 4 + 2] = v.z; xf[r * 65 + q + k * 4 + 3] = v.w;
      }
    }
    if (t < 64) {
      dAj_s[t] = dAcs[(base + j0j + t) * NH + hh];
      dtj_s[t] = dtp[(base + j0j + t) * NH + hh];
    }
    __syncthreads();
    f32x4 g[4];
#pragma unroll
    for (int i = 0; i < 4; ++i) g[i] = (f32x4){0.f, 0.f, 0.f, 0.f};
#pragma unroll
    for (int s = 0; s < 2; ++s)
#pragma unroll
      for (int jf = 0; jf < 4; ++jf) {
        f16x8 fbh = *(const f16x8*)((const char*)Pb_t + SWZ(jf * 16 + mlo, s * 4 + gg));
        g[jf] = __builtin_amdgcn_mfma_f32_16x16x32_f16(fch[s], fbh, g[jf], 0, 0, 0);
        g[jf] = __builtin_amdgcn_mfma_f32_16x16x32_f16(fcl[s], fbh, g[jf], 0, 0, 0);
      }
#pragma unroll
    for (int c = 0; c < 2; ++c) {
      U4 XH, XL;
#pragma unroll
      for (int jj = 0; jj < 8; ++jj) {
        int j = q + c * 8 + jj;
        u16 h, l; hsplit(xf[j * 65 + r], h, l);
        XH.s[jj] = h; XL.s[jj] = l;
      }
      *(uint4*)((char*)Xh_t + SWZ(r, slot0 + c)) = XH.v;
      *(uint4*)((char*)Xl_t + SWZ(r, slot0 + c)) = XL.v;
    }
#pragma unroll
    for (int jf = 0; jf < 4; ++jf)
#pragma unroll
      for (int reg = 0; reg < 4; ++reg) {
        int il = w * 16 + (lane >> 4) * 4 + reg;
        int jl = jf * 16 + mlo;
        bool ok = (jt < it) || (jl <= il);
        float av = ok ? g[jf][reg] * expf(dAi_s[il] - dAj_s[jl]) * dtj_s[jl] : 0.f;
        *(u16*)((char*)att_t + SWZ(il, jl >> 3) + (jl & 7) * 2) = f2h(av);
      }
    __syncthreads();
#pragma unroll
    for (int s = 0; s < 2; ++s) {
      f16x8 fa = *(const f16x8*)((const char*)att_t + SWZ(w * 16 + mlo, s * 4 + gg));
#pragma unroll
      for (int pf = 0; pf < 4; ++pf) {
        f16x8 fxh = *(const f16x8*)((const char*)Xh_t + SWZ(pf * 16 + mlo, s * 4 + gg));
        f16x8 fxl = *(const f16x8*)((const char*)Xl_t + SWZ(pf * 16 + mlo, s * 4 + gg));
        accy[pf] = __builtin_amdgcn_mfma_f32_16x16x32_f16(fa, fxh, accy[pf], 0, 0, 0);
        accy[pf] = __builtin_amdgcn_mfma_f32_16x16x32_f16(fa, fxl, accy[pf], 0, 0, 0);
      }
    }
  }
  const float Dh = Dp[hh];
#pragma unroll
  for (int pf = 0; pf < 4; ++pf)
#pragma unroll
    for (int reg = 0; reg < 4; ++reg) {
      size_t row = base + i0 + w * 16 + (lane >> 4) * 4 + reg;
      int col = hh * HD + pf * 16 + mlo;
      y[row * DI + col] = accy[pf][reg] + Dh * x[row * DI + col];
    }
}

// ---------------- K8: LayerNorm * z -> bf16 hi/lo pair ----------------
__global__ __launch_bounds__(256) void k_norm(
    const float* __restrict__ z, const float* __restrict__ nw,
    const float* __restrict__ nb, const float* __restrict__ y,
    u16* __restrict__ yh, u16* __restrict__ yl)
{
  __shared__ float rs[4], rq[4];
  const size_t row = blockIdx.x;
  const int t = threadIdx.x;
  float v[3];
  float s = 0.f, sq = 0.f;
#pragma unroll
  for (int r = 0; r < 3; ++r) {
    v[r] = y[row * DI + r * 256 + t];
    s += v[r];
    sq = fmaf(v[r], v[r], sq);
  }
#pragma unroll
  for (int off = 32; off > 0; off >>= 1) {
    s  += __shfl_down(s, off, 64);
    sq += __shfl_down(sq, off, 64);
  }
  const int wid = t >> 6, lane = t & 63;
  if (lane == 0) { rs[wid] = s; rq[wid] = sq; }
  __syncthreads();
  if (t == 0) {
    rs[0] = rs[0] + rs[1] + rs[2] + rs[3];
    rq[0] = rq[0] + rq[1] + rq[2] + rq[3];
  }
  __syncthreads();
  const float mu   = rs[0] * (1.f / DI);
  const float var  = rq[0] * (1.f / DI) - mu * mu;
  const float rstd = 1.f / sqrtf(var + EPS_);
#pragma unroll
  for (int r = 0; r < 3; ++r) {
    int d = r * 256 + t;
    float o = (v[r] - mu) * rstd * nw[d] + nb[d];
    float p = o * z[row * DI + d];
    u16 h, l;
    bsplit(p, h, l);
    yh[row * DI + d] = h;
    yl[row * DI + d] = l;
  }
}

extern "C" void kernel_launch(void* const* d_in, const int* in_sizes, int n_in,
                              void* d_out, int out_size, void* d_ws, size_t ws_size,
                              hipStream_t stream)
{
  const float* u    = (const float*)d_in[0];
  const float* ipw  = (const float*)d_in[1];
  const float* cw   = (const float*)d_in[2];
  const float* cb   = (const float*)d_in[3];
  const float* dtb  = (const float*)d_in[4];
  const float* Alog = (const float*)d_in[5];
  const float* Dp   = (const float*)d_in[6];
  const float* nw   = (const float*)d_in[7];
  const float* nb   = (const float*)d_in[8];
  const float* opw  = (const float*)d_in[9];
  float* out = (float*)d_out;

  float* ws = (float*)d_ws;
  size_t off = 0;
  float* z_buf   = ws + off; off += (size_t)B_ * L_ * DI;
  float* xBC_buf = ws + off; off += (size_t)B_ * L_ * CONVD;
  float* y_buf   = xBC_buf;                       // alias: xBC dead after conv
  float* dt_buf  = ws + off; off += (size_t)B_ * L_ * NH;
  float* x_buf   = ws + off; off += (size_t)B_ * L_ * DI;
  u16*   Bh_buf  = (u16*)(ws + off); off += (size_t)B_ * L_ * DS / 2;
  u16*   Ch_buf  = (u16*)(ws + off); off += (size_t)B_ * L_ * DS / 2;
  u16*   Cl_buf  = (u16*)(ws + off); off += (size_t)B_ * L_ * DS / 2;
  float* dAcs    = ws + off; off += (size_t)B_ * L_ * NH;
  float* cdec    = ws + off; off += (size_t)B_ * NCH * NH;
  float* st_buf  = ws + off; off += (size_t)B_ * NCH * NH * HD * DS;
  float* pv_buf  = ws + off; off += (size_t)B_ * NCH * NH * HD * DS;
  u16*   Woh     = (u16*)(ws + off); off += (size_t)DM * DI / 2;
  u16*   Wol     = (u16*)(ws + off); off += (size_t)DM * DI / 2;

  // aliases inside x_buf (dead/live windows don't overlap)
  u16* Ah = (u16*)x_buf;                         // 16384*384 fp16
  u16* Al = Ah + (size_t)B_ * L_ * DM;
  u16* Whip = Al + (size_t)B_ * L_ * DM;         // 1664*384 fp16 single
  u16* yh = (u16*)x_buf;                         // 16384*768 bf16 pair
  u16* yl = yh + (size_t)B_ * L_ * DI;

  hipLaunchKernelGGL(k_cvtA, dim3(8, 12, 16), dim3(256), 0, stream, u, Ah, Al);
  hipLaunchKernelGGL(k_cvtWh, dim3((NIP * DM / 4 + 255) / 256), dim3(256), 0, stream,
                     ipw, Whip, NIP * DM / 4);
  hipLaunchKernelGGL(k_cvtW, dim3((DM * DI / 4 + 255) / 256), dim3(256), 0, stream,
                     opw, Woh, Wol, DM, DI, DM * DI / 4);
  hipLaunchKernelGGL(k_dtp, dim3(64), dim3(256), 0, stream,
                     u, ipw, dtb, Alog, dt_buf, dAcs, cdec);
  hipLaunchKernelGGL(k_gemm1, dim3(128, 13), dim3(256), 0, stream,
                     Ah, Al, Whip, z_buf, xBC_buf);
  hipLaunchKernelGGL(k_conv, dim3(56, 2, 16), dim3(256), 0, stream,
                     xBC_buf, cw, cb, x_buf, Bh_buf, Ch_buf, Cl_buf);
  hipLaunchKernelGGL(k_states, dim3(64, 12), dim3(256), 0, stream,
                     x_buf, Bh_buf, dt_buf, dAcs, st_buf);
  hipLaunchKernelGGL(k_scanc, dim3(3072), dim3(256), 0, stream, st_buf, cdec, pv_buf);
  hipLaunchKernelGGL(k_y, dim3(64, 12, 4), dim3(256), 0, stream,
                     x_buf, Ch_buf, Cl_buf, Bh_buf, dt_buf, dAcs, pv_buf, Dp, y_buf);
  hipLaunchKernelGGL(k_norm, dim3(16384), dim3(256), 0, stream, z_buf, nw, nb, y_buf, yh, yl);
  hipLaunchKernelGGL(k_gemm2, dim3(128, 3), dim3(256), 0, stream, yh, yl, Woh, Wol, out);
}